// Round 12
// baseline (228.730 us; speedup 1.0000x reference)
//
#include <hip/hip_runtime.h>
#include <math.h>

// ---------------------------------------------------------------------------
// Bidirectional Mamba block, MI355X. Round 12:
//  - scan v5: p1/p3 process 2 d's per thread (128 d/block). The per-step
//    sB/sC ds_read_b128 is reused for both d-rows: LDS instrs per (d,t)
//    drop 40% (p3 was LDS-throughput-bound: 10 b128/4-step @ ~12cy).
//    sD/sU [128][68] (stride 68 -> <=2-way bank aliasing = free).
//  - everything else byte-identical to round 11 (verified).
// ws layout (f32 elements):
//   xz    [b][4096][1024]   8,388,608  (b0 x-half: hinit after conv)
//   u     [dirb][2048][1024] 8,388,608 (head: H16/Win16 before conv)
//   xdbl  [dirb][96][1024]     393,216
//   delta [dirb][2048][1024] 8,388,608 (head: x_proj partials; GT after scan)
//   y     [dirb][2048][1024] 8,388,608 (head: weights scratch -> hend@0,
//                                       aprod@2M during scan -> y by p3)
// ---------------------------------------------------------------------------

typedef _Float16 f16x8 __attribute__((ext_vector_type(8)));
typedef _Float16 f16x4 __attribute__((ext_vector_type(4)));
typedef float    f32x4 __attribute__((ext_vector_type(4)));

#define SCH 16    // scan chunks
#define SCL 64    // chunk length

__device__ __forceinline__ void gload_lds16(const void* g, void* l) {
    __builtin_amdgcn_global_load_lds(
        (const __attribute__((address_space(1))) void*)g,
        (__attribute__((address_space(3))) void*)l, 16, 0, 0);
}

__device__ __forceinline__ float softplus_f(float x) {
    float e = __builtin_amdgcn_exp2f(-fabsf(x) * 1.44269504f);
    return fmaxf(x, 0.f) + __builtin_amdgcn_logf(1.f + e) * 0.69314718f;
}

template<int CTRL>
__device__ __forceinline__ float dpp_add(float x) {
    int s = __builtin_amdgcn_update_dpp(0, __builtin_bit_cast(int, x),
                                        CTRL, 0xF, 0xF, true);
    return x + __builtin_bit_cast(float, s);
}

// ---------------------------------------------------------------------------
// fp16 NT MFMA GEMM (in_proj / out_proj)
// ---------------------------------------------------------------------------
template<int WMW, int WNW, int FM, int FN>
__global__ __launch_bounds__(256)
void gemm_nt_f16(const _Float16* __restrict__ A, const _Float16* __restrict__ B,
                 float* __restrict__ C, int K, int ldc, long sA, long sC)
{
    constexpr int BM = WMW * FM * 16, BN = WNW * FN * 16;
    constexpr int ACH = BM / 8, NCH = (BM + BN) / 8;
    __shared__ __align__(16) _Float16 lds[(BM + BN) * 64];
    A += (long)blockIdx.z * sA;
    C += (long)blockIdx.z * sC;
    const int m0 = blockIdx.y * BM, n0 = blockIdx.x * BN;
    const int t = threadIdx.x, wid = t >> 6, lane = t & 63;
    const int wm = wid / WNW, wn = wid % WNW;
    const int srow = lane >> 3;
    const int skk  = ((lane & 7) ^ srow) * 8;

    f32x4 acc[FM][FN];
#pragma unroll
    for (int i = 0; i < FM; ++i)
#pragma unroll
        for (int j = 0; j < FN; ++j) acc[i][j] = (f32x4){0.f, 0.f, 0.f, 0.f};

    for (int k0 = 0; k0 < K; k0 += 64) {
#pragma unroll
        for (int c = wid; c < NCH; c += 4) {
            const _Float16* gp = (c < ACH)
                ? A + (long)(m0 + c * 8 + srow) * K + k0 + skk
                : B + (long)(n0 + (c - ACH) * 8 + srow) * K + k0 + skk;
            gload_lds16(gp, lds + c * 512);
        }
        __syncthreads();
#pragma unroll
        for (int kw = 0; kw < 2; ++kw) {
            f16x8 af[FM], bf[FN];
#pragma unroll
            for (int i = 0; i < FM; ++i) {
                int r = wm * FM * 16 + i * 16 + (lane & 15);
                af[i] = *(const f16x8*)(lds + r * 64 +
                        (((kw * 4 + (lane >> 4)) ^ (r & 7)) * 8));
            }
#pragma unroll
            for (int j = 0; j < FN; ++j) {
                int r = wn * FN * 16 + j * 16 + (lane & 15);
                bf[j] = *(const f16x8*)(lds + BM * 64 + r * 64 +
                        (((kw * 4 + (lane >> 4)) ^ (r & 7)) * 8));
            }
#pragma unroll
            for (int i = 0; i < FM; ++i)
#pragma unroll
                for (int j = 0; j < FN; ++j)
                    acc[i][j] = __builtin_amdgcn_mfma_f32_16x16x32_f16(
                        af[i], bf[j], acc[i][j], 0, 0, 0);
        }
        __syncthreads();
    }
#pragma unroll
    for (int i = 0; i < FM; ++i)
#pragma unroll
        for (int j = 0; j < FN; ++j) {
            int n = n0 + wn * FN * 16 + j * 16 + (lane & 15);
            int m = m0 + wm * FM * 16 + i * 16 + (lane >> 4) * 4;
            *(f32x4*)&C[(long)n * ldc + m] = acc[i][j];
        }
}

// ---------------------------------------------------------------------------
// x_proj fp16 MFMA, split-K (verified r8)
// ---------------------------------------------------------------------------
#define XP_SK 8
__global__ __launch_bounds__(256)
void xproj_f16_kernel(const float* __restrict__ u, const _Float16* __restrict__ xw16,
                      float* __restrict__ pb)
{
    __shared__ __align__(16) _Float16 Asw[128 * 64];
    __shared__ __align__(16) _Float16 Bsw[96 * 64];
    const int t = threadIdx.x, wid = t >> 6, lane = t & 63;
    const int wm = wid >> 1, wn = wid & 1;
    const int m0 = blockIdx.x * 128;
    const int sk = blockIdx.y, dirb = blockIdx.z;
    const float* ub = u + (long)dirb * 2048 * 1024;
    const _Float16* Bw = xw16 + (long)(dirb >> 1) * 96 * 2048;
    const int srow = lane >> 3;
    const int skk  = ((lane & 7) ^ srow) * 8;
    const int lloc = (t & 31) * 4;
    const int kslt = t >> 5;

    f32x4 acc[4][3];
#pragma unroll
    for (int i = 0; i < 4; ++i)
#pragma unroll
        for (int j = 0; j < 3; ++j) acc[i][j] = (f32x4){0.f, 0.f, 0.f, 0.f};

    for (int ks = 0; ks < 2048 / XP_SK; ks += 64) {
        const int k0 = sk * (2048 / XP_SK) + ks;
#pragma unroll
        for (int c = wid; c < 12; c += 4)
            gload_lds16(Bw + (long)(c * 8 + srow) * 2048 + k0 + skk, Bsw + c * 512);
        float av[8][4];
#pragma unroll
        for (int kk = 0; kk < 8; ++kk) {
            f32x4 v = *(const f32x4*)&ub[(long)(k0 + kslt * 8 + kk) * 1024 + m0 + lloc];
            av[kk][0] = v.x; av[kk][1] = v.y; av[kk][2] = v.z; av[kk][3] = v.w;
        }
#pragma unroll
        for (int q = 0; q < 4; ++q) {
            int l = lloc + q;
            f16x8 h = {(_Float16)av[0][q], (_Float16)av[1][q], (_Float16)av[2][q],
                       (_Float16)av[3][q], (_Float16)av[4][q], (_Float16)av[5][q],
                       (_Float16)av[6][q], (_Float16)av[7][q]};
            *(f16x8*)(Asw + l * 64 + ((kslt ^ (l & 7)) * 8)) = h;
        }
        __syncthreads();
#pragma unroll
        for (int kw = 0; kw < 2; ++kw) {
            f16x8 af[4], bf[3];
#pragma unroll
            for (int i = 0; i < 4; ++i) {
                int r = wm * 64 + i * 16 + (lane & 15);
                af[i] = *(const f16x8*)(Asw + r * 64 +
                        (((kw * 4 + (lane >> 4)) ^ (r & 7)) * 8));
            }
#pragma unroll
            for (int j = 0; j < 3; ++j) {
                int r = wn * 48 + j * 16 + (lane & 15);
                bf[j] = *(const f16x8*)(Bsw + r * 64 +
                        (((kw * 4 + (lane >> 4)) ^ (r & 7)) * 8));
            }
#pragma unroll
            for (int i = 0; i < 4; ++i)
#pragma unroll
                for (int j = 0; j < 3; ++j)
                    acc[i][j] = __builtin_amdgcn_mfma_f32_16x16x32_f16(
                        af[i], bf[j], acc[i][j], 0, 0, 0);
        }
        __syncthreads();
    }
    float* Cp = pb + ((long)sk * 4 + dirb) * 96 * 1024;
#pragma unroll
    for (int i = 0; i < 4; ++i)
#pragma unroll
        for (int j = 0; j < 3; ++j) {
            int n = wn * 48 + j * 16 + (lane & 15);
            int m = m0 + wm * 64 + i * 16 + (lane >> 4) * 4;
            *(f32x4*)&Cp[(long)n * 1024 + m] = acc[i][j];
        }
}

__global__ __launch_bounds__(256)
void xreduce_kernel(const float* __restrict__ pb, float* __restrict__ xdbl)
{
    int f = (blockIdx.x * 256 + threadIdx.x) * 4;
    f32x4 s = (f32x4){0.f, 0.f, 0.f, 0.f};
#pragma unroll
    for (int sk = 0; sk < XP_SK; ++sk)
        s += *(const f32x4*)(pb + (long)sk * 393216 + f);
    *(f32x4*)(xdbl + f) = s;
}

// ---------------------------------------------------------------------------
// dt_proj fp16 MFMA + softplus epilogue (verified r9)
// ---------------------------------------------------------------------------
__global__ __launch_bounds__(256)
void dtproj_f16_kernel(const float* __restrict__ xdbl, const _Float16* __restrict__ dw16,
                       const float* __restrict__ bcat, float* __restrict__ delta)
{
    __shared__ __align__(16) _Float16 Asw[128 * 64];
    __shared__ __align__(16) _Float16 Bsw[128 * 64];
    const int t = threadIdx.x, wid = t >> 6, lane = t & 63;
    const int wm = wid >> 1, wn = wid & 1;
    const int n0 = blockIdx.x * 128, m0 = blockIdx.y * 128;
    const int dirb = blockIdx.z, dir = dirb >> 1;
    const float* Xb = xdbl + (long)dirb * 96 * 1024;
    const _Float16* Bw = dw16 + (long)dir * 2048 * 64;
    const int srow = lane >> 3, skk = ((lane & 7) ^ srow) * 8;
    const int lloc = (t & 31) * 4, kslt = t >> 5;

#pragma unroll
    for (int c = wid; c < 16; c += 4)
        gload_lds16(Bw + (long)(n0 + c * 8 + srow) * 64 + skk, Bsw + c * 512);
    float av[8][4];
#pragma unroll
    for (int kk = 0; kk < 8; ++kk) {
        f32x4 v = *(const f32x4*)&Xb[(long)(kslt * 8 + kk) * 1024 + m0 + lloc];
        av[kk][0] = v.x; av[kk][1] = v.y; av[kk][2] = v.z; av[kk][3] = v.w;
    }
#pragma unroll
    for (int q = 0; q < 4; ++q) {
        int l = lloc + q;
        f16x8 h = {(_Float16)av[0][q], (_Float16)av[1][q], (_Float16)av[2][q],
                   (_Float16)av[3][q], (_Float16)av[4][q], (_Float16)av[5][q],
                   (_Float16)av[6][q], (_Float16)av[7][q]};
        *(f16x8*)(Asw + l * 64 + ((kslt ^ (l & 7)) * 8)) = h;
    }
    __syncthreads();

    f32x4 acc[4][4];
#pragma unroll
    for (int i = 0; i < 4; ++i)
#pragma unroll
        for (int j = 0; j < 4; ++j) acc[i][j] = (f32x4){0.f, 0.f, 0.f, 0.f};
#pragma unroll
    for (int kw = 0; kw < 2; ++kw) {
        f16x8 af[4], bf[4];
#pragma unroll
        for (int i = 0; i < 4; ++i) {
            int r = wm * 64 + i * 16 + (lane & 15);
            af[i] = *(const f16x8*)(Asw + r * 64 +
                    (((kw * 4 + (lane >> 4)) ^ (r & 7)) * 8));
        }
#pragma unroll
        for (int j = 0; j < 4; ++j) {
            int r = wn * 64 + j * 16 + (lane & 15);
            bf[j] = *(const f16x8*)(Bsw + r * 64 +
                    (((kw * 4 + (lane >> 4)) ^ (r & 7)) * 8));
        }
#pragma unroll
        for (int i = 0; i < 4; ++i)
#pragma unroll
            for (int j = 0; j < 4; ++j)
                acc[i][j] = __builtin_amdgcn_mfma_f32_16x16x32_f16(
                    af[i], bf[j], acc[i][j], 0, 0, 0);
    }
    float* Dp = delta + (long)dirb * 2048 * 1024;
#pragma unroll
    for (int j = 0; j < 4; ++j) {
        int dd = n0 + wn * 64 + j * 16 + (lane & 15);
        float bm = bcat[dir * 2048 + dd];
#pragma unroll
        for (int i = 0; i < 4; ++i) {
            int m = m0 + wm * 64 + i * 16 + (lane >> 4) * 4;
            f32x4 v = acc[i][j];
            f32x4 o = {softplus_f(v.x + bm), softplus_f(v.y + bm),
                       softplus_f(v.z + bm), softplus_f(v.w + bm)};
            *(f32x4*)&Dp[(long)dd * 1024 + m] = o;
        }
    }
}

// f32 -> fp16 elementwise
__global__ __launch_bounds__(256)
void cvt_f16_kernel(const float* __restrict__ in, _Float16* __restrict__ out, int n)
{
    int i = (blockIdx.x * 256 + threadIdx.x) * 4;
    if (i + 3 < n) {
        float4 v = *(const float4*)(in + i);
        f16x4 h = {(_Float16)v.x, (_Float16)v.y, (_Float16)v.z, (_Float16)v.w};
        *(f16x4*)(out + i) = h;
    }
}

__global__ __launch_bounds__(256)
void concat_weights(const float* __restrict__ xwf, const float* __restrict__ xwb,
                    const float* __restrict__ dwf, const float* __restrict__ dwb,
                    const float* __restrict__ bf,  const float* __restrict__ bb,
                    _Float16* __restrict__ xw16, _Float16* __restrict__ dw16,
                    float* __restrict__ bcat)
{
    int i = blockIdx.x * 256 + threadIdx.x;
    if (i < 196608) { xw16[i] = (_Float16)xwf[i]; xw16[196608 + i] = (_Float16)xwb[i]; }
    if (i < 131072) { dw16[i] = (_Float16)dwf[i]; dw16[131072 + i] = (_Float16)dwb[i]; }
    if (i < 2048)   { bcat[i]  = bf[i];  bcat[2048 + i] = bb[i]; }
}

// Depthwise causal conv (k=4) + SiLU, both directions (bwd in reversed coords).
__global__ __launch_bounds__(256)
void conv_silu_kernel(const float* __restrict__ xz,
                      const float* __restrict__ wf, const float* __restrict__ bf,
                      const float* __restrict__ wb, const float* __restrict__ bbk,
                      float* __restrict__ u)
{
    long idx = (long)blockIdx.x * 256 + threadIdx.x;
    int l = (int)(idx & 1023);
    long r = idx >> 10;
    int d = (int)(r & 2047);
    int b = (int)((r >> 11) & 1);
    int dir = (int)(r >> 12);
    const float* x = xz + ((long)b * 4096 + d) * 1024;
    const float* w = dir ? wb : wf;
    float s = dir ? bbk[d] : bf[d];
    if (dir == 0) {
#pragma unroll
        for (int j = 0; j < 4; ++j) {
            int p = l - 3 + j;
            if (p >= 0) s = fmaf(w[d * 4 + j], x[p], s);
        }
    } else {
#pragma unroll
        for (int j = 0; j < 4; ++j) {
            int src = l - 3 + j;
            if (src >= 0) s = fmaf(w[d * 4 + j], x[1023 - src], s);
        }
    }
    u[idx] = s / (1.f + __builtin_amdgcn_exp2f(-s * 1.44269504f));
}

// ---------------------------------------------------------------------------
// scan v5 pass 1: per-chunk local scan, 2 d's per thread (128 d/block).
// sB reads amortize over both d's. Outputs h_end, aprod.
// ---------------------------------------------------------------------------
__global__ __launch_bounds__(256)
void scan_p1_kernel(const float* __restrict__ u, const float* __restrict__ delta,
                    const float* __restrict__ xdbl,
                    const float* __restrict__ Alf, const float* __restrict__ Alb,
                    float* __restrict__ hend, float* __restrict__ aprod)
{
    __shared__ float sD[128][68], sU[128][68], sB[64][20];
    const int t = threadIdx.x, wid = t >> 6, lane = t & 63;
    const int nl = lane & 3;
    const int da = wid * 32 + (lane >> 2);      // first d (local)
    const int db = da + 16;                     // second d (local)
    const int dblk = blockIdx.x, chunk = blockIdx.y, dirb = blockIdx.z;
    const int dir = dirb >> 1;
    const int T0 = chunk * SCL;
    const float* Al = (dir ? Alb : Alf) + (long)dblk * 128 * 16;
    f32x4 Ava = *(const f32x4*)(Al + da * 16 + nl * 4);
    f32x4 Avb = *(const f32x4*)(Al + db * 16 + nl * 4);
    float Aa[4] = {-expf(Ava.x) * 1.44269504f, -expf(Ava.y) * 1.44269504f,
                   -expf(Ava.z) * 1.44269504f, -expf(Ava.w) * 1.44269504f};
    float Ab[4] = {-expf(Avb.x) * 1.44269504f, -expf(Avb.y) * 1.44269504f,
                   -expf(Avb.z) * 1.44269504f, -expf(Avb.w) * 1.44269504f};
    const float* dp = delta + ((long)dirb * 2048 + dblk * 128) * 1024;
    const float* up = u     + ((long)dirb * 2048 + dblk * 128) * 1024;
    const float* Bp = xdbl  + ((long)dirb * 96 + 64) * 1024;

#pragma unroll
    for (int rep = 0; rep < 8; ++rep) {
        int ii = rep * 256 + t;
        int dd = ii >> 4, q = ii & 15;
        *(f32x4*)&sD[dd][q * 4] = *(const f32x4*)&dp[(long)dd * 1024 + T0 + q * 4];
        *(f32x4*)&sU[dd][q * 4] = *(const f32x4*)&up[(long)dd * 1024 + T0 + q * 4];
    }
#pragma unroll
    for (int rep = 0; rep < 4; ++rep) {
        int ii = rep * 256 + t;
        int n = ii >> 6, tt = ii & 63;
        sB[tt][n] = Bp[(long)n * 1024 + T0 + tt];
    }
    __syncthreads();

    float ha[4] = {0.f, 0.f, 0.f, 0.f}, hb[4] = {0.f, 0.f, 0.f, 0.f};
    float Sa = 0.f, Sb = 0.f;
#pragma unroll 4
    for (int g = 0; g < 16; ++g) {
        f32x4 dla = *(const f32x4*)&sD[da][g * 4];
        f32x4 uua = *(const f32x4*)&sU[da][g * 4];
        f32x4 dlb = *(const f32x4*)&sD[db][g * 4];
        f32x4 uub = *(const f32x4*)&sU[db][g * 4];
        float dlsa[4] = {dla.x, dla.y, dla.z, dla.w};
        float uusa[4] = {uua.x, uua.y, uua.z, uua.w};
        float dlsb[4] = {dlb.x, dlb.y, dlb.z, dlb.w};
        float uusb[4] = {uub.x, uub.y, uub.z, uub.w};
#pragma unroll
        for (int r4 = 0; r4 < 4; ++r4) {
            f32x4 Bv = *(const f32x4*)&sB[g * 4 + r4][nl * 4];
            float Bs[4] = {Bv.x, Bv.y, Bv.z, Bv.w};
            float d1 = dlsa[r4], t1 = d1 * uusa[r4];
            float d2 = dlsb[r4], t2 = d2 * uusb[r4];
            Sa += d1; Sb += d2;
#pragma unroll
            for (int r = 0; r < 4; ++r) {
                ha[r] = fmaf(__builtin_amdgcn_exp2f(d1 * Aa[r]), ha[r], t1 * Bs[r]);
                hb[r] = fmaf(__builtin_amdgcn_exp2f(d2 * Ab[r]), hb[r], t2 * Bs[r]);
            }
        }
    }
    long cba = (((long)dirb * SCH + chunk) * 2048 + dblk * 128 + da) * 16 + nl * 4;
    long cbb = (((long)dirb * SCH + chunk) * 2048 + dblk * 128 + db) * 16 + nl * 4;
    *(f32x4*)&hend[cba]  = (f32x4){ha[0], ha[1], ha[2], ha[3]};
    *(f32x4*)&hend[cbb]  = (f32x4){hb[0], hb[1], hb[2], hb[3]};
    *(f32x4*)&aprod[cba] = (f32x4){__builtin_amdgcn_exp2f(Sa * Aa[0]),
                                   __builtin_amdgcn_exp2f(Sa * Aa[1]),
                                   __builtin_amdgcn_exp2f(Sa * Aa[2]),
                                   __builtin_amdgcn_exp2f(Sa * Aa[3])};
    *(f32x4*)&aprod[cbb] = (f32x4){__builtin_amdgcn_exp2f(Sb * Ab[0]),
                                   __builtin_amdgcn_exp2f(Sb * Ab[1]),
                                   __builtin_amdgcn_exp2f(Sb * Ab[2]),
                                   __builtin_amdgcn_exp2f(Sb * Ab[3])};
}

// scan v5 pass 2: sequential carry combine across SCH chunks.
__global__ __launch_bounds__(256)
void scan_carry_kernel(const float* __restrict__ hend, const float* __restrict__ aprod,
                       float* __restrict__ hinit)
{
    int f = blockIdx.x * 256 + threadIdx.x;   // (dirb, d*16+n)
    int dn = f & 32767;
    int dirb = f >> 15;
    long base = (long)dirb * SCH * 32768 + dn;
    float hcur = 0.f;
#pragma unroll
    for (int c = 0; c < SCH; ++c) {
        hinit[base + (long)c * 32768] = hcur;
        hcur = hend[base + (long)c * 32768]
             + aprod[base + (long)c * 32768] * hcur;
    }
}

// scan v5 pass 3: rescan chunk from hinit, emit y. 2 d's per thread.
__global__ __launch_bounds__(256)
void scan_p3_kernel(const float* __restrict__ u, const float* __restrict__ delta,
                    const float* __restrict__ xdbl,
                    const float* __restrict__ Alf, const float* __restrict__ Alb,
                    const float* __restrict__ Df, const float* __restrict__ Db,
                    const float* __restrict__ hinit, float* __restrict__ y)
{
    __shared__ float sD[128][68], sU[128][68], sB[64][20], sC[64][20];
    const int t = threadIdx.x, wid = t >> 6, lane = t & 63;
    const int nl = lane & 3;
    const int da = wid * 32 + (lane >> 2);
    const int db = da + 16;
    const int dblk = blockIdx.x, chunk = blockIdx.y, dirb = blockIdx.z;
    const int dir = dirb >> 1;
    const int T0 = chunk * SCL;
    const float* Al = (dir ? Alb : Alf) + (long)dblk * 128 * 16;
    f32x4 Ava = *(const f32x4*)(Al + da * 16 + nl * 4);
    f32x4 Avb = *(const f32x4*)(Al + db * 16 + nl * 4);
    float Aa[4] = {-expf(Ava.x) * 1.44269504f, -expf(Ava.y) * 1.44269504f,
                   -expf(Ava.z) * 1.44269504f, -expf(Ava.w) * 1.44269504f};
    float Ab[4] = {-expf(Avb.x) * 1.44269504f, -expf(Avb.y) * 1.44269504f,
                   -expf(Avb.z) * 1.44269504f, -expf(Avb.w) * 1.44269504f};
    const float Dda = (dir ? Db : Df)[dblk * 128 + da];
    const float Ddb = (dir ? Db : Df)[dblk * 128 + db];
    const float* dp = delta + ((long)dirb * 2048 + dblk * 128) * 1024;
    const float* up = u     + ((long)dirb * 2048 + dblk * 128) * 1024;
    const float* Bp = xdbl  + ((long)dirb * 96 + 64) * 1024;
    const float* Cp = xdbl  + ((long)dirb * 96 + 80) * 1024;
    float* yra = y + ((long)dirb * 2048 + dblk * 128 + da) * 1024;
    float* yrb = y + ((long)dirb * 2048 + dblk * 128 + db) * 1024;

#pragma unroll
    for (int rep = 0; rep < 8; ++rep) {
        int ii = rep * 256 + t;
        int dd = ii >> 4, q = ii & 15;
        *(f32x4*)&sD[dd][q * 4] = *(const f32x4*)&dp[(long)dd * 1024 + T0 + q * 4];
        *(f32x4*)&sU[dd][q * 4] = *(const f32x4*)&up[(long)dd * 1024 + T0 + q * 4];
    }
#pragma unroll
    for (int rep = 0; rep < 4; ++rep) {
        int ii = rep * 256 + t;
        int n = ii >> 6, tt = ii & 63;
        sB[tt][n] = Bp[(long)n * 1024 + T0 + tt];
        sC[tt][n] = Cp[(long)n * 1024 + T0 + tt];
    }
    long cba = (((long)dirb * SCH + chunk) * 2048 + dblk * 128 + da) * 16 + nl * 4;
    long cbb = (((long)dirb * SCH + chunk) * 2048 + dblk * 128 + db) * 16 + nl * 4;
    f32x4 h0a = *(const f32x4*)&hinit[cba];
    f32x4 h0b = *(const f32x4*)&hinit[cbb];
    float ha[4] = {h0a.x, h0a.y, h0a.z, h0a.w};
    float hb[4] = {h0b.x, h0b.y, h0b.z, h0b.w};
    const bool m[4] = {nl == 0, nl == 1, nl == 2, nl == 3};
    __syncthreads();

#pragma unroll 4
    for (int g = 0; g < 16; ++g) {
        f32x4 dla = *(const f32x4*)&sD[da][g * 4];
        f32x4 uua = *(const f32x4*)&sU[da][g * 4];
        f32x4 dlb = *(const f32x4*)&sD[db][g * 4];
        f32x4 uub = *(const f32x4*)&sU[db][g * 4];
        float dlsa[4] = {dla.x, dla.y, dla.z, dla.w};
        float uusa[4] = {uua.x, uua.y, uua.z, uua.w};
        float dlsb[4] = {dlb.x, dlb.y, dlb.z, dlb.w};
        float uusb[4] = {uub.x, uub.y, uub.z, uub.w};
        float keepa = 0.f, keepb = 0.f;
#pragma unroll
        for (int r4 = 0; r4 < 4; ++r4) {
            f32x4 Bv = *(const f32x4*)&sB[g * 4 + r4][nl * 4];
            f32x4 Cv = *(const f32x4*)&sC[g * 4 + r4][nl * 4];
            float Bs[4] = {Bv.x, Bv.y, Bv.z, Bv.w};
            float Cs[4] = {Cv.x, Cv.y, Cv.z, Cv.w};
            float d1 = dlsa[r4], u1 = uusa[r4], t1 = d1 * u1;
            float d2 = dlsb[r4], u2 = uusb[r4], t2 = d2 * u2;
#pragma unroll
            for (int r = 0; r < 4; ++r) {
                ha[r] = fmaf(__builtin_amdgcn_exp2f(d1 * Aa[r]), ha[r], t1 * Bs[r]);
                hb[r] = fmaf(__builtin_amdgcn_exp2f(d2 * Ab[r]), hb[r], t2 * Bs[r]);
            }
            float pa = ha[0] * Cs[0];
            pa = fmaf(ha[1], Cs[1], pa);
            pa = fmaf(ha[2], Cs[2], pa);
            pa = fmaf(ha[3], Cs[3], pa);
            float pb2 = hb[0] * Cs[0];
            pb2 = fmaf(hb[1], Cs[1], pb2);
            pb2 = fmaf(hb[2], Cs[2], pb2);
            pb2 = fmaf(hb[3], Cs[3], pb2);
            pa  = dpp_add<0xB1>(pa);
            pa  = dpp_add<0x4E>(pa);
            pb2 = dpp_add<0xB1>(pb2);
            pb2 = dpp_add<0x4E>(pb2);
            float fya = fmaf(Dda, u1, pa);
            float fyb = fmaf(Ddb, u2, pb2);
            keepa = m[r4] ? fya : keepa;
            keepb = m[r4] ? fyb : keepb;
        }
        yra[T0 + g * 4 + nl] = keepa;
        yrb[T0 + g * 4 + nl] = keepb;
    }
}

// G = silu(z) * (y_f + rev y_b), written TRANSPOSED as fp16 GT[b][l][d].
__global__ __launch_bounds__(256)
void combine_T_kernel(const float* __restrict__ xz, const float* __restrict__ y,
                      _Float16* __restrict__ GT)
{
    __shared__ float Ls[64][65];
    const int d0 = blockIdx.x * 64, l0 = blockIdx.y * 64, b = blockIdx.z;
    const int t = threadIdx.x;
#pragma unroll
    for (int rep = 0; rep < 4; ++rep) {
        int i = rep * 256 + t;
        int dl = i >> 4;
        int lq = (i & 15) * 4;
        const float* zp  = xz + ((long)b * 4096 + 2048 + d0 + dl) * 1024 + l0 + lq;
        const float* yfp = y  + ((long)(b)     * 2048 + d0 + dl) * 1024 + l0 + lq;
        const float* ybp = y  + ((long)(2 + b) * 2048 + d0 + dl) * 1024 + (1020 - l0 - lq);
        float4 vz = *(const float4*)zp;
        float4 vf = *(const float4*)yfp;
        float4 vb = *(const float4*)ybp;
        float zz[4]  = {vz.x, vz.y, vz.z, vz.w};
        float ff[4]  = {vf.x, vf.y, vf.z, vf.w};
        float bbv[4] = {vb.w, vb.z, vb.y, vb.x};
#pragma unroll
        for (int qq = 0; qq < 4; ++qq) {
            float z = zz[qq];
            float sz = z / (1.f + __builtin_amdgcn_exp2f(-z * 1.44269504f));
            Ls[dl][lq + qq] = sz * (ff[qq] + bbv[qq]);
        }
    }
    __syncthreads();
#pragma unroll
    for (int rep = 0; rep < 4; ++rep) {
        int i = rep * 256 + t;
        int ll = i >> 4;
        int dq = (i & 15) * 4;
        f16x4 h = {(_Float16)Ls[dq][ll], (_Float16)Ls[dq + 1][ll],
                   (_Float16)Ls[dq + 2][ll], (_Float16)Ls[dq + 3][ll]};
        *(f16x4*)(GT + ((long)(b * 1024 + l0 + ll)) * 2048 + d0 + dq) = h;
    }
}

extern "C" void kernel_launch(void* const* d_in, const int* in_sizes, int n_in,
                              void* d_out, int out_size, void* d_ws, size_t ws_size,
                              hipStream_t stream)
{
    const float* hidden   = (const float*)d_in[0];
    const float* inproj_w = (const float*)d_in[1];
    const float* conv_w   = (const float*)d_in[2];
    const float* conv_b   = (const float*)d_in[3];
    const float* xproj_w  = (const float*)d_in[4];
    const float* dtproj_w = (const float*)d_in[5];
    const float* dt_bias  = (const float*)d_in[6];
    const float* A_log    = (const float*)d_in[7];
    const float* D_skip   = (const float*)d_in[8];
    const float* convb_w  = (const float*)d_in[9];
    const float* convb_b  = (const float*)d_in[10];
    const float* xprojb_w = (const float*)d_in[11];
    const float* dtprojb_w= (const float*)d_in[12];
    const float* dtb_bias = (const float*)d_in[13];
    const float* Ab_log   = (const float*)d_in[14];
    const float* Db_skip  = (const float*)d_in[15];
    const float* outproj_w= (const float*)d_in[16];
    float* out = (float*)d_out;

    float* ws    = (float*)d_ws;
    float* xz    = ws;
    float* u     = ws + 8388608;
    float* xdbl  = ws + 16777216;
    float* delta = ws + 17170432;
    float* y     = ws + 25559040;
    // fp16 / scratch aliases in temporally-dead regions:
    _Float16* H16    = (_Float16*)u;
    _Float16* Win16  = (_Float16*)(u + 1048576);
    float*    xpb    = delta;                       // x_proj partials
    _Float16* GT     = (_Float16*)delta;            // after scan
    _Float16* Wout16 = (_Float16*)y;                // after combine
    _Float16* dw16   = (_Float16*)y;                // pre-scan scratch
    float*    bcat   = y + 131072;
    _Float16* xw16   = (_Float16*)(y + 135168);
    // scan carry buffers (SCH=16 -> 2M f32 each):
    float* hend  = y;               // y dead until p3 writes it
    float* aprod = y + 2097152;
    float* hinit = xz;              // b0 x-half dead after conv

    // 0) f32 -> fp16 conversions
    hipLaunchKernelGGL(cvt_f16_kernel, dim3(2048), dim3(256), 0, stream,
        hidden, H16, 2097152);
    hipLaunchKernelGGL(cvt_f16_kernel, dim3(4096), dim3(256), 0, stream,
        inproj_w, Win16, 4194304);

    // 0b) weight concat/convert
    hipLaunchKernelGGL(concat_weights, dim3(768), dim3(256), 0, stream,
        xproj_w, xprojb_w, dtproj_w, dtprojb_w, dt_bias, dtb_bias,
        xw16, dw16, bcat);

    // 1) in_proj MFMA
    hipLaunchKernelGGL((gemm_nt_f16<2, 2, 4, 4>),
        dim3(32, 8, 2), dim3(256), 0, stream,
        H16, Win16, xz, 1024, 1024, 1048576L, 4194304L);

    // 2) conv + silu
    hipLaunchKernelGGL(conv_silu_kernel, dim3(32768), dim3(256), 0, stream,
        xz, conv_w, conv_b, convb_w, convb_b, u);

    // 3) x_proj MFMA split-K + reduce
    hipLaunchKernelGGL(xproj_f16_kernel, dim3(8, XP_SK, 4), dim3(256), 0, stream,
        u, xw16, xpb);
    hipLaunchKernelGGL(xreduce_kernel, dim3(384), dim3(256), 0, stream,
        xpb, xdbl);

    // 4) dt_proj fp16 MFMA + softplus
    hipLaunchKernelGGL(dtproj_f16_kernel, dim3(16, 8, 4), dim3(256), 0, stream,
        xdbl, dw16, bcat, delta);

    // 5) scan v5: p1 (local, 128d/blk) -> carry -> p3 (emit y, 128d/blk)
    hipLaunchKernelGGL(scan_p1_kernel, dim3(16, SCH, 4), dim3(256), 0, stream,
        u, delta, xdbl, A_log, Ab_log, hend, aprod);
    hipLaunchKernelGGL(scan_carry_kernel, dim3(512), dim3(256), 0, stream,
        hend, aprod, hinit);
    hipLaunchKernelGGL(scan_p3_kernel, dim3(16, SCH, 4), dim3(256), 0, stream,
        u, delta, xdbl, A_log, Ab_log, D_skip, Db_skip, hinit, y);

    // 6) combine -> GT fp16
    hipLaunchKernelGGL(combine_T_kernel, dim3(32, 16, 2), dim3(256), 0, stream,
        xz, y, GT);

    // 7) W_out -> fp16
    hipLaunchKernelGGL(cvt_f16_kernel, dim3(2048), dim3(256), 0, stream,
        outproj_w, Wout16, 2097152);

    // 8) out_proj MFMA
    hipLaunchKernelGGL((gemm_nt_f16<4, 1, 2, 4>),
        dim3(32, 8, 1), dim3(256), 0, stream,
        Wout16, GT, out, 2048, 1024, 0L, 0L);
}

// Round 13
// 199.840 us; speedup vs baseline: 1.1446x; 1.1446x over previous
//
#include <hip/hip_runtime.h>
#include <math.h>

// ---------------------------------------------------------------------------
// Bidirectional Mamba block, MI355X. Round 13:
//  - scan v6: revert r12's 2d/thread (regressed: 80KB LDS -> 2 blk/CU).
//    Back to r11 geometry (64 d/blk, 1 d/thread) with SCH=32 chunks of
//    SCL=32: 4096 blocks/pass, 21-24KB LDS -> ~6 blk/CU, 2x parallelism.
//    hend/aprod fill dead y region exactly; hinit split across the two
//    dead xz x-halves.
//  - all other kernels byte-identical to r11 (verified).
// ws layout (f32 elements):
//   xz    [b][4096][1024]   8,388,608  (x-halves: hinit during scan)
//   u     [dirb][2048][1024] 8,388,608 (head: H16/Win16 before conv)
//   xdbl  [dirb][96][1024]     393,216
//   delta [dirb][2048][1024] 8,388,608 (head: x_proj partials; GT after scan)
//   y     [dirb][2048][1024] 8,388,608 (hend@0 + aprod@4.2M during scan ->
//                                       y by p3 -> Wout16 after combine)
// ---------------------------------------------------------------------------

typedef _Float16 f16x8 __attribute__((ext_vector_type(8)));
typedef _Float16 f16x4 __attribute__((ext_vector_type(4)));
typedef float    f32x4 __attribute__((ext_vector_type(4)));

#define SCH 32    // scan chunks
#define SCL 32    // chunk length

__device__ __forceinline__ void gload_lds16(const void* g, void* l) {
    __builtin_amdgcn_global_load_lds(
        (const __attribute__((address_space(1))) void*)g,
        (__attribute__((address_space(3))) void*)l, 16, 0, 0);
}

__device__ __forceinline__ float softplus_f(float x) {
    float e = __builtin_amdgcn_exp2f(-fabsf(x) * 1.44269504f);
    return fmaxf(x, 0.f) + __builtin_amdgcn_logf(1.f + e) * 0.69314718f;
}

template<int CTRL>
__device__ __forceinline__ float dpp_add(float x) {
    int s = __builtin_amdgcn_update_dpp(0, __builtin_bit_cast(int, x),
                                        CTRL, 0xF, 0xF, true);
    return x + __builtin_bit_cast(float, s);
}

// ---------------------------------------------------------------------------
// fp16 NT MFMA GEMM (in_proj / out_proj)
// ---------------------------------------------------------------------------
template<int WMW, int WNW, int FM, int FN>
__global__ __launch_bounds__(256)
void gemm_nt_f16(const _Float16* __restrict__ A, const _Float16* __restrict__ B,
                 float* __restrict__ C, int K, int ldc, long sA, long sC)
{
    constexpr int BM = WMW * FM * 16, BN = WNW * FN * 16;
    constexpr int ACH = BM / 8, NCH = (BM + BN) / 8;
    __shared__ __align__(16) _Float16 lds[(BM + BN) * 64];
    A += (long)blockIdx.z * sA;
    C += (long)blockIdx.z * sC;
    const int m0 = blockIdx.y * BM, n0 = blockIdx.x * BN;
    const int t = threadIdx.x, wid = t >> 6, lane = t & 63;
    const int wm = wid / WNW, wn = wid % WNW;
    const int srow = lane >> 3;
    const int skk  = ((lane & 7) ^ srow) * 8;

    f32x4 acc[FM][FN];
#pragma unroll
    for (int i = 0; i < FM; ++i)
#pragma unroll
        for (int j = 0; j < FN; ++j) acc[i][j] = (f32x4){0.f, 0.f, 0.f, 0.f};

    for (int k0 = 0; k0 < K; k0 += 64) {
#pragma unroll
        for (int c = wid; c < NCH; c += 4) {
            const _Float16* gp = (c < ACH)
                ? A + (long)(m0 + c * 8 + srow) * K + k0 + skk
                : B + (long)(n0 + (c - ACH) * 8 + srow) * K + k0 + skk;
            gload_lds16(gp, lds + c * 512);
        }
        __syncthreads();
#pragma unroll
        for (int kw = 0; kw < 2; ++kw) {
            f16x8 af[FM], bf[FN];
#pragma unroll
            for (int i = 0; i < FM; ++i) {
                int r = wm * FM * 16 + i * 16 + (lane & 15);
                af[i] = *(const f16x8*)(lds + r * 64 +
                        (((kw * 4 + (lane >> 4)) ^ (r & 7)) * 8));
            }
#pragma unroll
            for (int j = 0; j < FN; ++j) {
                int r = wn * FN * 16 + j * 16 + (lane & 15);
                bf[j] = *(const f16x8*)(lds + BM * 64 + r * 64 +
                        (((kw * 4 + (lane >> 4)) ^ (r & 7)) * 8));
            }
#pragma unroll
            for (int i = 0; i < FM; ++i)
#pragma unroll
                for (int j = 0; j < FN; ++j)
                    acc[i][j] = __builtin_amdgcn_mfma_f32_16x16x32_f16(
                        af[i], bf[j], acc[i][j], 0, 0, 0);
        }
        __syncthreads();
    }
#pragma unroll
    for (int i = 0; i < FM; ++i)
#pragma unroll
        for (int j = 0; j < FN; ++j) {
            int n = n0 + wn * FN * 16 + j * 16 + (lane & 15);
            int m = m0 + wm * FM * 16 + i * 16 + (lane >> 4) * 4;
            *(f32x4*)&C[(long)n * ldc + m] = acc[i][j];
        }
}

// ---------------------------------------------------------------------------
// x_proj fp16 MFMA, split-K (verified r8)
// ---------------------------------------------------------------------------
#define XP_SK 8
__global__ __launch_bounds__(256)
void xproj_f16_kernel(const float* __restrict__ u, const _Float16* __restrict__ xw16,
                      float* __restrict__ pb)
{
    __shared__ __align__(16) _Float16 Asw[128 * 64];
    __shared__ __align__(16) _Float16 Bsw[96 * 64];
    const int t = threadIdx.x, wid = t >> 6, lane = t & 63;
    const int wm = wid >> 1, wn = wid & 1;
    const int m0 = blockIdx.x * 128;
    const int sk = blockIdx.y, dirb = blockIdx.z;
    const float* ub = u + (long)dirb * 2048 * 1024;
    const _Float16* Bw = xw16 + (long)(dirb >> 1) * 96 * 2048;
    const int srow = lane >> 3;
    const int skk  = ((lane & 7) ^ srow) * 8;
    const int lloc = (t & 31) * 4;
    const int kslt = t >> 5;

    f32x4 acc[4][3];
#pragma unroll
    for (int i = 0; i < 4; ++i)
#pragma unroll
        for (int j = 0; j < 3; ++j) acc[i][j] = (f32x4){0.f, 0.f, 0.f, 0.f};

    for (int ks = 0; ks < 2048 / XP_SK; ks += 64) {
        const int k0 = sk * (2048 / XP_SK) + ks;
#pragma unroll
        for (int c = wid; c < 12; c += 4)
            gload_lds16(Bw + (long)(c * 8 + srow) * 2048 + k0 + skk, Bsw + c * 512);
        float av[8][4];
#pragma unroll
        for (int kk = 0; kk < 8; ++kk) {
            f32x4 v = *(const f32x4*)&ub[(long)(k0 + kslt * 8 + kk) * 1024 + m0 + lloc];
            av[kk][0] = v.x; av[kk][1] = v.y; av[kk][2] = v.z; av[kk][3] = v.w;
        }
#pragma unroll
        for (int q = 0; q < 4; ++q) {
            int l = lloc + q;
            f16x8 h = {(_Float16)av[0][q], (_Float16)av[1][q], (_Float16)av[2][q],
                       (_Float16)av[3][q], (_Float16)av[4][q], (_Float16)av[5][q],
                       (_Float16)av[6][q], (_Float16)av[7][q]};
            *(f16x8*)(Asw + l * 64 + ((kslt ^ (l & 7)) * 8)) = h;
        }
        __syncthreads();
#pragma unroll
        for (int kw = 0; kw < 2; ++kw) {
            f16x8 af[4], bf[3];
#pragma unroll
            for (int i = 0; i < 4; ++i) {
                int r = wm * 64 + i * 16 + (lane & 15);
                af[i] = *(const f16x8*)(Asw + r * 64 +
                        (((kw * 4 + (lane >> 4)) ^ (r & 7)) * 8));
            }
#pragma unroll
            for (int j = 0; j < 3; ++j) {
                int r = wn * 48 + j * 16 + (lane & 15);
                bf[j] = *(const f16x8*)(Bsw + r * 64 +
                        (((kw * 4 + (lane >> 4)) ^ (r & 7)) * 8));
            }
#pragma unroll
            for (int i = 0; i < 4; ++i)
#pragma unroll
                for (int j = 0; j < 3; ++j)
                    acc[i][j] = __builtin_amdgcn_mfma_f32_16x16x32_f16(
                        af[i], bf[j], acc[i][j], 0, 0, 0);
        }
        __syncthreads();
    }
    float* Cp = pb + ((long)sk * 4 + dirb) * 96 * 1024;
#pragma unroll
    for (int i = 0; i < 4; ++i)
#pragma unroll
        for (int j = 0; j < 3; ++j) {
            int n = wn * 48 + j * 16 + (lane & 15);
            int m = m0 + wm * 64 + i * 16 + (lane >> 4) * 4;
            *(f32x4*)&Cp[(long)n * 1024 + m] = acc[i][j];
        }
}

__global__ __launch_bounds__(256)
void xreduce_kernel(const float* __restrict__ pb, float* __restrict__ xdbl)
{
    int f = (blockIdx.x * 256 + threadIdx.x) * 4;
    f32x4 s = (f32x4){0.f, 0.f, 0.f, 0.f};
#pragma unroll
    for (int sk = 0; sk < XP_SK; ++sk)
        s += *(const f32x4*)(pb + (long)sk * 393216 + f);
    *(f32x4*)(xdbl + f) = s;
}

// ---------------------------------------------------------------------------
// dt_proj fp16 MFMA + softplus epilogue (verified r9)
// ---------------------------------------------------------------------------
__global__ __launch_bounds__(256)
void dtproj_f16_kernel(const float* __restrict__ xdbl, const _Float16* __restrict__ dw16,
                       const float* __restrict__ bcat, float* __restrict__ delta)
{
    __shared__ __align__(16) _Float16 Asw[128 * 64];
    __shared__ __align__(16) _Float16 Bsw[128 * 64];
    const int t = threadIdx.x, wid = t >> 6, lane = t & 63;
    const int wm = wid >> 1, wn = wid & 1;
    const int n0 = blockIdx.x * 128, m0 = blockIdx.y * 128;
    const int dirb = blockIdx.z, dir = dirb >> 1;
    const float* Xb = xdbl + (long)dirb * 96 * 1024;
    const _Float16* Bw = dw16 + (long)dir * 2048 * 64;
    const int srow = lane >> 3, skk = ((lane & 7) ^ srow) * 8;
    const int lloc = (t & 31) * 4, kslt = t >> 5;

#pragma unroll
    for (int c = wid; c < 16; c += 4)
        gload_lds16(Bw + (long)(n0 + c * 8 + srow) * 64 + skk, Bsw + c * 512);
    float av[8][4];
#pragma unroll
    for (int kk = 0; kk < 8; ++kk) {
        f32x4 v = *(const f32x4*)&Xb[(long)(kslt * 8 + kk) * 1024 + m0 + lloc];
        av[kk][0] = v.x; av[kk][1] = v.y; av[kk][2] = v.z; av[kk][3] = v.w;
    }
#pragma unroll
    for (int q = 0; q < 4; ++q) {
        int l = lloc + q;
        f16x8 h = {(_Float16)av[0][q], (_Float16)av[1][q], (_Float16)av[2][q],
                   (_Float16)av[3][q], (_Float16)av[4][q], (_Float16)av[5][q],
                   (_Float16)av[6][q], (_Float16)av[7][q]};
        *(f16x8*)(Asw + l * 64 + ((kslt ^ (l & 7)) * 8)) = h;
    }
    __syncthreads();

    f32x4 acc[4][4];
#pragma unroll
    for (int i = 0; i < 4; ++i)
#pragma unroll
        for (int j = 0; j < 4; ++j) acc[i][j] = (f32x4){0.f, 0.f, 0.f, 0.f};
#pragma unroll
    for (int kw = 0; kw < 2; ++kw) {
        f16x8 af[4], bf[4];
#pragma unroll
        for (int i = 0; i < 4; ++i) {
            int r = wm * 64 + i * 16 + (lane & 15);
            af[i] = *(const f16x8*)(Asw + r * 64 +
                    (((kw * 4 + (lane >> 4)) ^ (r & 7)) * 8));
        }
#pragma unroll
        for (int j = 0; j < 4; ++j) {
            int r = wn * 64 + j * 16 + (lane & 15);
            bf[j] = *(const f16x8*)(Bsw + r * 64 +
                    (((kw * 4 + (lane >> 4)) ^ (r & 7)) * 8));
        }
#pragma unroll
        for (int i = 0; i < 4; ++i)
#pragma unroll
            for (int j = 0; j < 4; ++j)
                acc[i][j] = __builtin_amdgcn_mfma_f32_16x16x32_f16(
                    af[i], bf[j], acc[i][j], 0, 0, 0);
    }
    float* Dp = delta + (long)dirb * 2048 * 1024;
#pragma unroll
    for (int j = 0; j < 4; ++j) {
        int dd = n0 + wn * 64 + j * 16 + (lane & 15);
        float bm = bcat[dir * 2048 + dd];
#pragma unroll
        for (int i = 0; i < 4; ++i) {
            int m = m0 + wm * 64 + i * 16 + (lane >> 4) * 4;
            f32x4 v = acc[i][j];
            f32x4 o = {softplus_f(v.x + bm), softplus_f(v.y + bm),
                       softplus_f(v.z + bm), softplus_f(v.w + bm)};
            *(f32x4*)&Dp[(long)dd * 1024 + m] = o;
        }
    }
}

// f32 -> fp16 elementwise
__global__ __launch_bounds__(256)
void cvt_f16_kernel(const float* __restrict__ in, _Float16* __restrict__ out, int n)
{
    int i = (blockIdx.x * 256 + threadIdx.x) * 4;
    if (i + 3 < n) {
        float4 v = *(const float4*)(in + i);
        f16x4 h = {(_Float16)v.x, (_Float16)v.y, (_Float16)v.z, (_Float16)v.w};
        *(f16x4*)(out + i) = h;
    }
}

__global__ __launch_bounds__(256)
void concat_weights(const float* __restrict__ xwf, const float* __restrict__ xwb,
                    const float* __restrict__ dwf, const float* __restrict__ dwb,
                    const float* __restrict__ bf,  const float* __restrict__ bb,
                    _Float16* __restrict__ xw16, _Float16* __restrict__ dw16,
                    float* __restrict__ bcat)
{
    int i = blockIdx.x * 256 + threadIdx.x;
    if (i < 196608) { xw16[i] = (_Float16)xwf[i]; xw16[196608 + i] = (_Float16)xwb[i]; }
    if (i < 131072) { dw16[i] = (_Float16)dwf[i]; dw16[131072 + i] = (_Float16)dwb[i]; }
    if (i < 2048)   { bcat[i]  = bf[i];  bcat[2048 + i] = bb[i]; }
}

// Depthwise causal conv (k=4) + SiLU, both directions (bwd in reversed coords).
__global__ __launch_bounds__(256)
void conv_silu_kernel(const float* __restrict__ xz,
                      const float* __restrict__ wf, const float* __restrict__ bf,
                      const float* __restrict__ wb, const float* __restrict__ bbk,
                      float* __restrict__ u)
{
    long idx = (long)blockIdx.x * 256 + threadIdx.x;
    int l = (int)(idx & 1023);
    long r = idx >> 10;
    int d = (int)(r & 2047);
    int b = (int)((r >> 11) & 1);
    int dir = (int)(r >> 12);
    const float* x = xz + ((long)b * 4096 + d) * 1024;
    const float* w = dir ? wb : wf;
    float s = dir ? bbk[d] : bf[d];
    if (dir == 0) {
#pragma unroll
        for (int j = 0; j < 4; ++j) {
            int p = l - 3 + j;
            if (p >= 0) s = fmaf(w[d * 4 + j], x[p], s);
        }
    } else {
#pragma unroll
        for (int j = 0; j < 4; ++j) {
            int src = l - 3 + j;
            if (src >= 0) s = fmaf(w[d * 4 + j], x[1023 - src], s);
        }
    }
    u[idx] = s / (1.f + __builtin_amdgcn_exp2f(-s * 1.44269504f));
}

// ---------------------------------------------------------------------------
// scan v6 pass 1: per-chunk local scan. 64 d/block, 1 d/thread (16d x 4nl
// per wave, 4 states/lane). SCL=32 staged whole-chunk, 1 barrier.
// ---------------------------------------------------------------------------
__global__ __launch_bounds__(256)
void scan_p1_kernel(const float* __restrict__ u, const float* __restrict__ delta,
                    const float* __restrict__ xdbl,
                    const float* __restrict__ Alf, const float* __restrict__ Alb,
                    float* __restrict__ hend, float* __restrict__ aprod)
{
    __shared__ float sD[64][36], sU[64][36], sB[32][20];
    const int t = threadIdx.x, wid = t >> 6, lane = t & 63;
    const int nl = lane & 3;
    const int dloc = wid * 16 + (lane >> 2);
    const int dblk = blockIdx.x, chunk = blockIdx.y, dirb = blockIdx.z;
    const int d = dblk * 64 + dloc, dir = dirb >> 1;
    const int T0 = chunk * SCL;
    f32x4 Av = *(const f32x4*)((dir ? Alb : Alf) + d * 16 + nl * 4);
    float An2[4] = {-expf(Av.x) * 1.44269504f, -expf(Av.y) * 1.44269504f,
                    -expf(Av.z) * 1.44269504f, -expf(Av.w) * 1.44269504f};
    const float* dp = delta + ((long)dirb * 2048 + dblk * 64) * 1024;
    const float* up = u     + ((long)dirb * 2048 + dblk * 64) * 1024;
    const float* Bp = xdbl  + ((long)dirb * 96 + 64) * 1024;

#pragma unroll
    for (int rep = 0; rep < 2; ++rep) {
        int ii = rep * 256 + t;
        int dd = ii >> 3, q = ii & 7;
        *(f32x4*)&sD[dd][q * 4] = *(const f32x4*)&dp[(long)dd * 1024 + T0 + q * 4];
        *(f32x4*)&sU[dd][q * 4] = *(const f32x4*)&up[(long)dd * 1024 + T0 + q * 4];
    }
#pragma unroll
    for (int rep = 0; rep < 2; ++rep) {
        int ii = rep * 256 + t;
        int n = ii >> 5, tt = ii & 31;
        sB[tt][n] = Bp[(long)n * 1024 + T0 + tt];
    }
    __syncthreads();

    float h[4] = {0.f, 0.f, 0.f, 0.f};
    float S = 0.f;
#pragma unroll 4
    for (int g = 0; g < 8; ++g) {
        f32x4 dlv = *(const f32x4*)&sD[dloc][g * 4];
        f32x4 uuv = *(const f32x4*)&sU[dloc][g * 4];
        float dls[4] = {dlv.x, dlv.y, dlv.z, dlv.w};
        float uus[4] = {uuv.x, uuv.y, uuv.z, uuv.w};
#pragma unroll
        for (int r4 = 0; r4 < 4; ++r4) {
            f32x4 Bv = *(const f32x4*)&sB[g * 4 + r4][nl * 4];
            float Bs[4] = {Bv.x, Bv.y, Bv.z, Bv.w};
            float dl = dls[r4], t1 = dl * uus[r4];
            S += dl;
#pragma unroll
            for (int r = 0; r < 4; ++r)
                h[r] = fmaf(__builtin_amdgcn_exp2f(dl * An2[r]), h[r], t1 * Bs[r]);
        }
    }
    long cb = (((long)dirb * SCH + chunk) * 2048 + d) * 16 + nl * 4;
    *(f32x4*)&hend[cb]  = (f32x4){h[0], h[1], h[2], h[3]};
    *(f32x4*)&aprod[cb] = (f32x4){__builtin_amdgcn_exp2f(S * An2[0]),
                                  __builtin_amdgcn_exp2f(S * An2[1]),
                                  __builtin_amdgcn_exp2f(S * An2[2]),
                                  __builtin_amdgcn_exp2f(S * An2[3])};
}

// scan v6 pass 2: sequential carry combine. hinit split across xz x-halves:
// region (dirb>>1)*4194304 + (dirb&1)*1048576.
__global__ __launch_bounds__(256)
void scan_carry_kernel(const float* __restrict__ hend, const float* __restrict__ aprod,
                       float* __restrict__ hinit)
{
    int f = blockIdx.x * 256 + threadIdx.x;   // (dirb, d*16+n)
    int dn = f & 32767;
    int dirb = f >> 15;
    long src = (long)dirb * SCH * 32768 + dn;
    long dst = (long)(dirb >> 1) * 4194304 + (long)(dirb & 1) * 1048576 + dn;
    float hcur = 0.f;
#pragma unroll
    for (int c = 0; c < SCH; ++c) {
        hinit[dst + (long)c * 32768] = hcur;
        hcur = hend[src + (long)c * 32768]
             + aprod[src + (long)c * 32768] * hcur;
    }
}

// scan v6 pass 3: rescan chunk from hinit, emit y.
__global__ __launch_bounds__(256)
void scan_p3_kernel(const float* __restrict__ u, const float* __restrict__ delta,
                    const float* __restrict__ xdbl,
                    const float* __restrict__ Alf, const float* __restrict__ Alb,
                    const float* __restrict__ Df, const float* __restrict__ Db,
                    const float* __restrict__ hinit, float* __restrict__ y)
{
    __shared__ float sD[64][36], sU[64][36], sB[32][20], sC[32][20];
    const int t = threadIdx.x, wid = t >> 6, lane = t & 63;
    const int nl = lane & 3;
    const int dloc = wid * 16 + (lane >> 2);
    const int dblk = blockIdx.x, chunk = blockIdx.y, dirb = blockIdx.z;
    const int d = dblk * 64 + dloc, dir = dirb >> 1;
    const int T0 = chunk * SCL;
    f32x4 Av = *(const f32x4*)((dir ? Alb : Alf) + d * 16 + nl * 4);
    float An2[4] = {-expf(Av.x) * 1.44269504f, -expf(Av.y) * 1.44269504f,
                    -expf(Av.z) * 1.44269504f, -expf(Av.w) * 1.44269504f};
    const float Dd = (dir ? Db : Df)[d];
    const float* dp = delta + ((long)dirb * 2048 + dblk * 64) * 1024;
    const float* up = u     + ((long)dirb * 2048 + dblk * 64) * 1024;
    const float* Bp = xdbl  + ((long)dirb * 96 + 64) * 1024;
    const float* Cp = xdbl  + ((long)dirb * 96 + 80) * 1024;
    float* yrow = y + ((long)dirb * 2048 + d) * 1024;

#pragma unroll
    for (int rep = 0; rep < 2; ++rep) {
        int ii = rep * 256 + t;
        int dd = ii >> 3, q = ii & 7;
        *(f32x4*)&sD[dd][q * 4] = *(const f32x4*)&dp[(long)dd * 1024 + T0 + q * 4];
        *(f32x4*)&sU[dd][q * 4] = *(const f32x4*)&up[(long)dd * 1024 + T0 + q * 4];
    }
#pragma unroll
    for (int rep = 0; rep < 2; ++rep) {
        int ii = rep * 256 + t;
        int n = ii >> 5, tt = ii & 31;
        sB[tt][n] = Bp[(long)n * 1024 + T0 + tt];
        sC[tt][n] = Cp[(long)n * 1024 + T0 + tt];
    }
    long cb = (long)(dirb >> 1) * 4194304 + (long)(dirb & 1) * 1048576
            + (long)chunk * 32768 + (long)d * 16 + nl * 4;
    f32x4 h0v = *(const f32x4*)&hinit[cb];
    float h[4] = {h0v.x, h0v.y, h0v.z, h0v.w};
    const bool m[4] = {nl == 0, nl == 1, nl == 2, nl == 3};
    __syncthreads();

#pragma unroll 4
    for (int g = 0; g < 8; ++g) {
        f32x4 dlv = *(const f32x4*)&sD[dloc][g * 4];
        f32x4 uuv = *(const f32x4*)&sU[dloc][g * 4];
        float dls[4] = {dlv.x, dlv.y, dlv.z, dlv.w};
        float uus[4] = {uuv.x, uuv.y, uuv.z, uuv.w};
        float keep = 0.f;
#pragma unroll
        for (int r4 = 0; r4 < 4; ++r4) {
            f32x4 Bv = *(const f32x4*)&sB[g * 4 + r4][nl * 4];
            f32x4 Cv = *(const f32x4*)&sC[g * 4 + r4][nl * 4];
            float Bs[4] = {Bv.x, Bv.y, Bv.z, Bv.w};
            float Cs[4] = {Cv.x, Cv.y, Cv.z, Cv.w};
            float dl = dls[r4], uu = uus[r4];
            float t1 = dl * uu;
#pragma unroll
            for (int r = 0; r < 4; ++r)
                h[r] = fmaf(__builtin_amdgcn_exp2f(dl * An2[r]), h[r], t1 * Bs[r]);
            float p = h[0] * Cs[0];
            p = fmaf(h[1], Cs[1], p);
            p = fmaf(h[2], Cs[2], p);
            p = fmaf(h[3], Cs[3], p);
            p = dpp_add<0xB1>(p);      // quad xor1
            p = dpp_add<0x4E>(p);      // quad xor2 -> full 16-n sum in all 4 lanes
            float fy = fmaf(Dd, uu, p);
            keep = m[r4] ? fy : keep;
        }
        yrow[T0 + g * 4 + nl] = keep;
    }
}

// G = silu(z) * (y_f + rev y_b), written TRANSPOSED as fp16 GT[b][l][d].
__global__ __launch_bounds__(256)
void combine_T_kernel(const float* __restrict__ xz, const float* __restrict__ y,
                      _Float16* __restrict__ GT)
{
    __shared__ float Ls[64][65];
    const int d0 = blockIdx.x * 64, l0 = blockIdx.y * 64, b = blockIdx.z;
    const int t = threadIdx.x;
#pragma unroll
    for (int rep = 0; rep < 4; ++rep) {
        int i = rep * 256 + t;
        int dl = i >> 4;
        int lq = (i & 15) * 4;
        const float* zp  = xz + ((long)b * 4096 + 2048 + d0 + dl) * 1024 + l0 + lq;
        const float* yfp = y  + ((long)(b)     * 2048 + d0 + dl) * 1024 + l0 + lq;
        const float* ybp = y  + ((long)(2 + b) * 2048 + d0 + dl) * 1024 + (1020 - l0 - lq);
        float4 vz = *(const float4*)zp;
        float4 vf = *(const float4*)yfp;
        float4 vb = *(const float4*)ybp;
        float zz[4]  = {vz.x, vz.y, vz.z, vz.w};
        float ff[4]  = {vf.x, vf.y, vf.z, vf.w};
        float bbv[4] = {vb.w, vb.z, vb.y, vb.x};
#pragma unroll
        for (int qq = 0; qq < 4; ++qq) {
            float z = zz[qq];
            float sz = z / (1.f + __builtin_amdgcn_exp2f(-z * 1.44269504f));
            Ls[dl][lq + qq] = sz * (ff[qq] + bbv[qq]);
        }
    }
    __syncthreads();
#pragma unroll
    for (int rep = 0; rep < 4; ++rep) {
        int i = rep * 256 + t;
        int ll = i >> 4;
        int dq = (i & 15) * 4;
        f16x4 h = {(_Float16)Ls[dq][ll], (_Float16)Ls[dq + 1][ll],
                   (_Float16)Ls[dq + 2][ll], (_Float16)Ls[dq + 3][ll]};
        *(f16x4*)(GT + ((long)(b * 1024 + l0 + ll)) * 2048 + d0 + dq) = h;
    }
}

extern "C" void kernel_launch(void* const* d_in, const int* in_sizes, int n_in,
                              void* d_out, int out_size, void* d_ws, size_t ws_size,
                              hipStream_t stream)
{
    const float* hidden   = (const float*)d_in[0];
    const float* inproj_w = (const float*)d_in[1];
    const float* conv_w   = (const float*)d_in[2];
    const float* conv_b   = (const float*)d_in[3];
    const float* xproj_w  = (const float*)d_in[4];
    const float* dtproj_w = (const float*)d_in[5];
    const float* dt_bias  = (const float*)d_in[6];
    const float* A_log    = (const float*)d_in[7];
    const float* D_skip   = (const float*)d_in[8];
    const float* convb_w  = (const float*)d_in[9];
    const float* convb_b  = (const float*)d_in[10];
    const float* xprojb_w = (const float*)d_in[11];
    const float* dtprojb_w= (const float*)d_in[12];
    const float* dtb_bias = (const float*)d_in[13];
    const float* Ab_log   = (const float*)d_in[14];
    const float* Db_skip  = (const float*)d_in[15];
    const float* outproj_w= (const float*)d_in[16];
    float* out = (float*)d_out;

    float* ws    = (float*)d_ws;
    float* xz    = ws;
    float* u     = ws + 8388608;
    float* xdbl  = ws + 16777216;
    float* delta = ws + 17170432;
    float* y     = ws + 25559040;
    // fp16 / scratch aliases in temporally-dead regions:
    _Float16* H16    = (_Float16*)u;
    _Float16* Win16  = (_Float16*)(u + 1048576);
    float*    xpb    = delta;                       // x_proj partials
    _Float16* GT     = (_Float16*)delta;            // after scan
    _Float16* Wout16 = (_Float16*)y;                // after combine
    _Float16* dw16   = (_Float16*)y;                // pre-scan scratch
    float*    bcat   = y + 131072;
    _Float16* xw16   = (_Float16*)(y + 135168);
    // scan carry buffers (SCH=32 -> 4,194,304 f32 each):
    float* hend  = y;               // y dead until p3 writes it
    float* aprod = y + 4194304;
    float* hinit = xz;              // split across both xz x-halves

    // 0) f32 -> fp16 conversions
    hipLaunchKernelGGL(cvt_f16_kernel, dim3(2048), dim3(256), 0, stream,
        hidden, H16, 2097152);
    hipLaunchKernelGGL(cvt_f16_kernel, dim3(4096), dim3(256), 0, stream,
        inproj_w, Win16, 4194304);

    // 0b) weight concat/convert
    hipLaunchKernelGGL(concat_weights, dim3(768), dim3(256), 0, stream,
        xproj_w, xprojb_w, dtproj_w, dtprojb_w, dt_bias, dtb_bias,
        xw16, dw16, bcat);

    // 1) in_proj MFMA
    hipLaunchKernelGGL((gemm_nt_f16<2, 2, 4, 4>),
        dim3(32, 8, 2), dim3(256), 0, stream,
        H16, Win16, xz, 1024, 1024, 1048576L, 4194304L);

    // 2) conv + silu
    hipLaunchKernelGGL(conv_silu_kernel, dim3(32768), dim3(256), 0, stream,
        xz, conv_w, conv_b, convb_w, convb_b, u);

    // 3) x_proj MFMA split-K + reduce
    hipLaunchKernelGGL(xproj_f16_kernel, dim3(8, XP_SK, 4), dim3(256), 0, stream,
        u, xw16, xpb);
    hipLaunchKernelGGL(xreduce_kernel, dim3(384), dim3(256), 0, stream,
        xpb, xdbl);

    // 4) dt_proj fp16 MFMA + softplus
    hipLaunchKernelGGL(dtproj_f16_kernel, dim3(16, 8, 4), dim3(256), 0, stream,
        xdbl, dw16, bcat, delta);

    // 5) scan v6: p1 (local) -> carry -> p3 (emit y)
    hipLaunchKernelGGL(scan_p1_kernel, dim3(32, SCH, 4), dim3(256), 0, stream,
        u, delta, xdbl, A_log, Ab_log, hend, aprod);
    hipLaunchKernelGGL(scan_carry_kernel, dim3(512), dim3(256), 0, stream,
        hend, aprod, hinit);
    hipLaunchKernelGGL(scan_p3_kernel, dim3(32, SCH, 4), dim3(256), 0, stream,
        u, delta, xdbl, A_log, Ab_log, D_skip, Db_skip, hinit, y);

    // 6) combine -> GT fp16
    hipLaunchKernelGGL(combine_T_kernel, dim3(32, 16, 2), dim3(256), 0, stream,
        xz, y, GT);

    // 7) W_out -> fp16
    hipLaunchKernelGGL(cvt_f16_kernel, dim3(2048), dim3(256), 0, stream,
        outproj_w, Wout16, 2097152);

    // 8) out_proj MFMA
    hipLaunchKernelGGL((gemm_nt_f16<4, 1, 2, 4>),
        dim3(32, 8, 1), dim3(256), 0, stream,
        Wout16, GT, out, 2048, 1024, 0L, 0L);
}

// Round 14
// 180.807 us; speedup vs baseline: 1.2651x; 1.1053x over previous
//
#include <hip/hip_runtime.h>
#include <math.h>

// ---------------------------------------------------------------------------
// Bidirectional Mamba block, MI355X. Round 14:
//  - fp16 intermediates end-to-end: conv->u16, dt_proj->delta16, scan p3->y16.
//    scan p1/p3 stage fp16 ([64][40] LDS, conflict-free), cvt in-register.
//    x_proj A-staging reads u16 directly (cvt removed). combine reads y16.
//    ~100MB less L3/HBM traffic.
//  - setup merged into ONE kernel (H16/Win16/Wout16/xw16/dw16/bcat): 11 launches.
//  - scan geometry unchanged from r13 (SCH=32, SCL=32, 64 d/blk — verified).
// ws layout (f32 elements):
//   xz    [b][4096][1024] 8,388,608  (x-halves: hinit during scan; z-half live)
//   u     region:  [0,1M) H16 | [1M,3M) Win16 | [3M,7M) u16 | [7M,8M) Wout16
//   xdbl  [dirb][96][1024]  393,216 (f32)
//   delta region:  [0,4.2M) delta16 (later GT) | [4.2M,7.3M) xpb partials
//   y     region:  [0,4.2M) hend -> y16 | [4.2M,8.4M) aprod
//                  (xw16/dw16/bcat in head pre-scan, dead before hend)
// ---------------------------------------------------------------------------

typedef _Float16 f16x8 __attribute__((ext_vector_type(8)));
typedef _Float16 f16x4 __attribute__((ext_vector_type(4)));
typedef float    f32x4 __attribute__((ext_vector_type(4)));

#define SCH 32    // scan chunks
#define SCL 32    // chunk length

__device__ __forceinline__ void gload_lds16(const void* g, void* l) {
    __builtin_amdgcn_global_load_lds(
        (const __attribute__((address_space(1))) void*)g,
        (__attribute__((address_space(3))) void*)l, 16, 0, 0);
}

__device__ __forceinline__ float softplus_f(float x) {
    float e = __builtin_amdgcn_exp2f(-fabsf(x) * 1.44269504f);
    return fmaxf(x, 0.f) + __builtin_amdgcn_logf(1.f + e) * 0.69314718f;
}

template<int CTRL>
__device__ __forceinline__ float dpp_add(float x) {
    int s = __builtin_amdgcn_update_dpp(0, __builtin_bit_cast(int, x),
                                        CTRL, 0xF, 0xF, true);
    return x + __builtin_bit_cast(float, s);
}

// ---------------------------------------------------------------------------
// fp16 NT MFMA GEMM (in_proj / out_proj) — verified r7.
// ---------------------------------------------------------------------------
template<int WMW, int WNW, int FM, int FN>
__global__ __launch_bounds__(256)
void gemm_nt_f16(const _Float16* __restrict__ A, const _Float16* __restrict__ B,
                 float* __restrict__ C, int K, int ldc, long sA, long sC)
{
    constexpr int BM = WMW * FM * 16, BN = WNW * FN * 16;
    constexpr int ACH = BM / 8, NCH = (BM + BN) / 8;
    __shared__ __align__(16) _Float16 lds[(BM + BN) * 64];
    A += (long)blockIdx.z * sA;
    C += (long)blockIdx.z * sC;
    const int m0 = blockIdx.y * BM, n0 = blockIdx.x * BN;
    const int t = threadIdx.x, wid = t >> 6, lane = t & 63;
    const int wm = wid / WNW, wn = wid % WNW;
    const int srow = lane >> 3;
    const int skk  = ((lane & 7) ^ srow) * 8;

    f32x4 acc[FM][FN];
#pragma unroll
    for (int i = 0; i < FM; ++i)
#pragma unroll
        for (int j = 0; j < FN; ++j) acc[i][j] = (f32x4){0.f, 0.f, 0.f, 0.f};

    for (int k0 = 0; k0 < K; k0 += 64) {
#pragma unroll
        for (int c = wid; c < NCH; c += 4) {
            const _Float16* gp = (c < ACH)
                ? A + (long)(m0 + c * 8 + srow) * K + k0 + skk
                : B + (long)(n0 + (c - ACH) * 8 + srow) * K + k0 + skk;
            gload_lds16(gp, lds + c * 512);
        }
        __syncthreads();
#pragma unroll
        for (int kw = 0; kw < 2; ++kw) {
            f16x8 af[FM], bf[FN];
#pragma unroll
            for (int i = 0; i < FM; ++i) {
                int r = wm * FM * 16 + i * 16 + (lane & 15);
                af[i] = *(const f16x8*)(lds + r * 64 +
                        (((kw * 4 + (lane >> 4)) ^ (r & 7)) * 8));
            }
#pragma unroll
            for (int j = 0; j < FN; ++j) {
                int r = wn * FN * 16 + j * 16 + (lane & 15);
                bf[j] = *(const f16x8*)(lds + BM * 64 + r * 64 +
                        (((kw * 4 + (lane >> 4)) ^ (r & 7)) * 8));
            }
#pragma unroll
            for (int i = 0; i < FM; ++i)
#pragma unroll
                for (int j = 0; j < FN; ++j)
                    acc[i][j] = __builtin_amdgcn_mfma_f32_16x16x32_f16(
                        af[i], bf[j], acc[i][j], 0, 0, 0);
        }
        __syncthreads();
    }
#pragma unroll
    for (int i = 0; i < FM; ++i)
#pragma unroll
        for (int j = 0; j < FN; ++j) {
            int n = n0 + wn * FN * 16 + j * 16 + (lane & 15);
            int m = m0 + wm * FM * 16 + i * 16 + (lane >> 4) * 4;
            *(f32x4*)&C[(long)n * ldc + m] = acc[i][j];
        }
}

// ---------------------------------------------------------------------------
// x_proj fp16 MFMA, split-K (verified r8). A now read directly from u16.
// ---------------------------------------------------------------------------
#define XP_SK 8
__global__ __launch_bounds__(256)
void xproj_f16_kernel(const _Float16* __restrict__ u16, const _Float16* __restrict__ xw16,
                      float* __restrict__ pb)
{
    __shared__ __align__(16) _Float16 Asw[128 * 64];
    __shared__ __align__(16) _Float16 Bsw[96 * 64];
    const int t = threadIdx.x, wid = t >> 6, lane = t & 63;
    const int wm = wid >> 1, wn = wid & 1;
    const int m0 = blockIdx.x * 128;
    const int sk = blockIdx.y, dirb = blockIdx.z;
    const _Float16* ub = u16 + (long)dirb * 2048 * 1024;
    const _Float16* Bw = xw16 + (long)(dirb >> 1) * 96 * 2048;
    const int srow = lane >> 3;
    const int skk  = ((lane & 7) ^ srow) * 8;
    const int lloc = (t & 31) * 4;
    const int kslt = t >> 5;

    f32x4 acc[4][3];
#pragma unroll
    for (int i = 0; i < 4; ++i)
#pragma unroll
        for (int j = 0; j < 3; ++j) acc[i][j] = (f32x4){0.f, 0.f, 0.f, 0.f};

    for (int ks = 0; ks < 2048 / XP_SK; ks += 64) {
        const int k0 = sk * (2048 / XP_SK) + ks;
#pragma unroll
        for (int c = wid; c < 12; c += 4)
            gload_lds16(Bw + (long)(c * 8 + srow) * 2048 + k0 + skk, Bsw + c * 512);
        _Float16 av[8][4];
#pragma unroll
        for (int kk = 0; kk < 8; ++kk) {
            f16x4 v = *(const f16x4*)&ub[(long)(k0 + kslt * 8 + kk) * 1024 + m0 + lloc];
            av[kk][0] = v[0]; av[kk][1] = v[1]; av[kk][2] = v[2]; av[kk][3] = v[3];
        }
#pragma unroll
        for (int q = 0; q < 4; ++q) {
            int l = lloc + q;
            f16x8 h = {av[0][q], av[1][q], av[2][q], av[3][q],
                       av[4][q], av[5][q], av[6][q], av[7][q]};
            *(f16x8*)(Asw + l * 64 + ((kslt ^ (l & 7)) * 8)) = h;
        }
        __syncthreads();
#pragma unroll
        for (int kw = 0; kw < 2; ++kw) {
            f16x8 af[4], bf[3];
#pragma unroll
            for (int i = 0; i < 4; ++i) {
                int r = wm * 64 + i * 16 + (lane & 15);
                af[i] = *(const f16x8*)(Asw + r * 64 +
                        (((kw * 4 + (lane >> 4)) ^ (r & 7)) * 8));
            }
#pragma unroll
            for (int j = 0; j < 3; ++j) {
                int r = wn * 48 + j * 16 + (lane & 15);
                bf[j] = *(const f16x8*)(Bsw + r * 64 +
                        (((kw * 4 + (lane >> 4)) ^ (r & 7)) * 8));
            }
#pragma unroll
            for (int i = 0; i < 4; ++i)
#pragma unroll
                for (int j = 0; j < 3; ++j)
                    acc[i][j] = __builtin_amdgcn_mfma_f32_16x16x32_f16(
                        af[i], bf[j], acc[i][j], 0, 0, 0);
        }
        __syncthreads();
    }
    float* Cp = pb + ((long)sk * 4 + dirb) * 96 * 1024;
#pragma unroll
    for (int i = 0; i < 4; ++i)
#pragma unroll
        for (int j = 0; j < 3; ++j) {
            int n = wn * 48 + j * 16 + (lane & 15);
            int m = m0 + wm * 64 + i * 16 + (lane >> 4) * 4;
            *(f32x4*)&Cp[(long)n * 1024 + m] = acc[i][j];
        }
}

__global__ __launch_bounds__(256)
void xreduce_kernel(const float* __restrict__ pb, float* __restrict__ xdbl)
{
    int f = (blockIdx.x * 256 + threadIdx.x) * 4;
    f32x4 s = (f32x4){0.f, 0.f, 0.f, 0.f};
#pragma unroll
    for (int sk = 0; sk < XP_SK; ++sk)
        s += *(const f32x4*)(pb + (long)sk * 393216 + f);
    *(f32x4*)(xdbl + f) = s;
}

// ---------------------------------------------------------------------------
// dt_proj fp16 MFMA + softplus epilogue -> delta16 (fp16)
// ---------------------------------------------------------------------------
__global__ __launch_bounds__(256)
void dtproj_f16_kernel(const float* __restrict__ xdbl, const _Float16* __restrict__ dw16,
                       const float* __restrict__ bcat, _Float16* __restrict__ delta16)
{
    __shared__ __align__(16) _Float16 Asw[128 * 64];
    __shared__ __align__(16) _Float16 Bsw[128 * 64];
    const int t = threadIdx.x, wid = t >> 6, lane = t & 63;
    const int wm = wid >> 1, wn = wid & 1;
    const int n0 = blockIdx.x * 128, m0 = blockIdx.y * 128;
    const int dirb = blockIdx.z, dir = dirb >> 1;
    const float* Xb = xdbl + (long)dirb * 96 * 1024;
    const _Float16* Bw = dw16 + (long)dir * 2048 * 64;
    const int srow = lane >> 3, skk = ((lane & 7) ^ srow) * 8;
    const int lloc = (t & 31) * 4, kslt = t >> 5;

#pragma unroll
    for (int c = wid; c < 16; c += 4)
        gload_lds16(Bw + (long)(n0 + c * 8 + srow) * 64 + skk, Bsw + c * 512);
    float av[8][4];
#pragma unroll
    for (int kk = 0; kk < 8; ++kk) {
        f32x4 v = *(const f32x4*)&Xb[(long)(kslt * 8 + kk) * 1024 + m0 + lloc];
        av[kk][0] = v.x; av[kk][1] = v.y; av[kk][2] = v.z; av[kk][3] = v.w;
    }
#pragma unroll
    for (int q = 0; q < 4; ++q) {
        int l = lloc + q;
        f16x8 h = {(_Float16)av[0][q], (_Float16)av[1][q], (_Float16)av[2][q],
                   (_Float16)av[3][q], (_Float16)av[4][q], (_Float16)av[5][q],
                   (_Float16)av[6][q], (_Float16)av[7][q]};
        *(f16x8*)(Asw + l * 64 + ((kslt ^ (l & 7)) * 8)) = h;
    }
    __syncthreads();

    f32x4 acc[4][4];
#pragma unroll
    for (int i = 0; i < 4; ++i)
#pragma unroll
        for (int j = 0; j < 4; ++j) acc[i][j] = (f32x4){0.f, 0.f, 0.f, 0.f};
#pragma unroll
    for (int kw = 0; kw < 2; ++kw) {
        f16x8 af[4], bf[4];
#pragma unroll
        for (int i = 0; i < 4; ++i) {
            int r = wm * 64 + i * 16 + (lane & 15);
            af[i] = *(const f16x8*)(Asw + r * 64 +
                    (((kw * 4 + (lane >> 4)) ^ (r & 7)) * 8));
        }
#pragma unroll
        for (int j = 0; j < 4; ++j) {
            int r = wn * 64 + j * 16 + (lane & 15);
            bf[j] = *(const f16x8*)(Bsw + r * 64 +
                    (((kw * 4 + (lane >> 4)) ^ (r & 7)) * 8));
        }
#pragma unroll
        for (int i = 0; i < 4; ++i)
#pragma unroll
            for (int j = 0; j < 4; ++j)
                acc[i][j] = __builtin_amdgcn_mfma_f32_16x16x32_f16(
                    af[i], bf[j], acc[i][j], 0, 0, 0);
    }
    _Float16* Dp = delta16 + (long)dirb * 2048 * 1024;
#pragma unroll
    for (int j = 0; j < 4; ++j) {
        int dd = n0 + wn * 64 + j * 16 + (lane & 15);
        float bm = bcat[dir * 2048 + dd];
#pragma unroll
        for (int i = 0; i < 4; ++i) {
            int m = m0 + wm * 64 + i * 16 + (lane >> 4) * 4;
            f32x4 v = acc[i][j];
            f16x4 o = {(_Float16)softplus_f(v.x + bm), (_Float16)softplus_f(v.y + bm),
                       (_Float16)softplus_f(v.z + bm), (_Float16)softplus_f(v.w + bm)};
            *(f16x4*)&Dp[(long)dd * 1024 + m] = o;
        }
    }
}

// ---------------------------------------------------------------------------
// Merged setup: H16, Win16, Wout16 (fp16 cvt) + xw16/dw16 concat + bcat.
// ---------------------------------------------------------------------------
__global__ __launch_bounds__(256)
void setup_kernel(const float* __restrict__ hidden, const float* __restrict__ winp,
                  const float* __restrict__ woutp,
                  const float* __restrict__ xwf, const float* __restrict__ xwb,
                  const float* __restrict__ dwf, const float* __restrict__ dwb,
                  const float* __restrict__ bf,  const float* __restrict__ bb,
                  _Float16* __restrict__ H16, _Float16* __restrict__ Win16,
                  _Float16* __restrict__ Wout16,
                  _Float16* __restrict__ xw16, _Float16* __restrict__ dw16,
                  float* __restrict__ bcat)
{
    long i4 = ((long)blockIdx.x * 256 + threadIdx.x) * 4;
    auto cvt4 = [](const float* s) -> f16x4 {
        float4 v = *(const float4*)s;
        return (f16x4){(_Float16)v.x, (_Float16)v.y, (_Float16)v.z, (_Float16)v.w};
    };
    if (i4 < 4194304) *(f16x4*)(Win16 + i4) = cvt4(winp + i4);
    if (i4 < 2097152) {
        *(f16x4*)(H16 + i4)   = cvt4(hidden + i4);
        *(f16x4*)(Wout16 + i4) = cvt4(woutp + i4);
    }
    if (i4 < 196608) {
        *(f16x4*)(xw16 + i4)          = cvt4(xwf + i4);
        *(f16x4*)(xw16 + 196608 + i4) = cvt4(xwb + i4);
    }
    if (i4 < 131072) {
        *(f16x4*)(dw16 + i4)          = cvt4(dwf + i4);
        *(f16x4*)(dw16 + 131072 + i4) = cvt4(dwb + i4);
    }
    if (i4 < 2048) {
        *(float4*)(bcat + i4)        = *(const float4*)(bf + i4);
        *(float4*)(bcat + 2048 + i4) = *(const float4*)(bb + i4);
    }
}

// Depthwise causal conv (k=4) + SiLU -> u16 (fp16), both directions.
__global__ __launch_bounds__(256)
void conv_silu_kernel(const float* __restrict__ xz,
                      const float* __restrict__ wf, const float* __restrict__ bf,
                      const float* __restrict__ wb, const float* __restrict__ bbk,
                      _Float16* __restrict__ u16)
{
    long idx = (long)blockIdx.x * 256 + threadIdx.x;
    int l = (int)(idx & 1023);
    long r = idx >> 10;
    int d = (int)(r & 2047);
    int b = (int)((r >> 11) & 1);
    int dir = (int)(r >> 12);
    const float* x = xz + ((long)b * 4096 + d) * 1024;
    const float* w = dir ? wb : wf;
    float s = dir ? bbk[d] : bf[d];
    if (dir == 0) {
#pragma unroll
        for (int j = 0; j < 4; ++j) {
            int p = l - 3 + j;
            if (p >= 0) s = fmaf(w[d * 4 + j], x[p], s);
        }
    } else {
#pragma unroll
        for (int j = 0; j < 4; ++j) {
            int src = l - 3 + j;
            if (src >= 0) s = fmaf(w[d * 4 + j], x[1023 - src], s);
        }
    }
    u16[idx] = (_Float16)(s / (1.f + __builtin_amdgcn_exp2f(-s * 1.44269504f)));
}

// ---------------------------------------------------------------------------
// scan pass 1 (fp16 inputs): per-chunk local scan. 64 d/blk, SCL=32.
// ---------------------------------------------------------------------------
__global__ __launch_bounds__(256)
void scan_p1_kernel(const _Float16* __restrict__ u16, const _Float16* __restrict__ delta16,
                    const float* __restrict__ xdbl,
                    const float* __restrict__ Alf, const float* __restrict__ Alb,
                    float* __restrict__ hend, float* __restrict__ aprod)
{
    __shared__ _Float16 sD[64][40], sU[64][40];
    __shared__ float sB[32][20];
    const int t = threadIdx.x, wid = t >> 6, lane = t & 63;
    const int nl = lane & 3;
    const int dloc = wid * 16 + (lane >> 2);
    const int dblk = blockIdx.x, chunk = blockIdx.y, dirb = blockIdx.z;
    const int d = dblk * 64 + dloc, dir = dirb >> 1;
    const int T0 = chunk * SCL;
    f32x4 Av = *(const f32x4*)((dir ? Alb : Alf) + d * 16 + nl * 4);
    float An2[4] = {-expf(Av.x) * 1.44269504f, -expf(Av.y) * 1.44269504f,
                    -expf(Av.z) * 1.44269504f, -expf(Av.w) * 1.44269504f};
    const _Float16* dp = delta16 + ((long)dirb * 2048 + dblk * 64) * 1024;
    const _Float16* up = u16    + ((long)dirb * 2048 + dblk * 64) * 1024;
    const float* Bp = xdbl + ((long)dirb * 96 + 64) * 1024;

    {   // stage: 64 d x 32 t fp16, one f16x8 per thread per buffer
        int dd = t >> 2, q = t & 3;
        *(f16x8*)&sD[dd][q * 8] = *(const f16x8*)&dp[(long)dd * 1024 + T0 + q * 8];
        *(f16x8*)&sU[dd][q * 8] = *(const f16x8*)&up[(long)dd * 1024 + T0 + q * 8];
    }
#pragma unroll
    for (int rep = 0; rep < 2; ++rep) {
        int ii = rep * 256 + t;
        int n = ii >> 5, tt = ii & 31;
        sB[tt][n] = Bp[(long)n * 1024 + T0 + tt];
    }
    __syncthreads();

    float h[4] = {0.f, 0.f, 0.f, 0.f};
    float S = 0.f;
#pragma unroll 4
    for (int g = 0; g < 8; ++g) {
        f16x4 dlh = *(const f16x4*)&sD[dloc][g * 4];
        f16x4 uuh = *(const f16x4*)&sU[dloc][g * 4];
        float dls[4] = {(float)dlh[0], (float)dlh[1], (float)dlh[2], (float)dlh[3]};
        float uus[4] = {(float)uuh[0], (float)uuh[1], (float)uuh[2], (float)uuh[3]};
#pragma unroll
        for (int r4 = 0; r4 < 4; ++r4) {
            f32x4 Bv = *(const f32x4*)&sB[g * 4 + r4][nl * 4];
            float Bs[4] = {Bv.x, Bv.y, Bv.z, Bv.w};
            float dl = dls[r4], t1 = dl * uus[r4];
            S += dl;
#pragma unroll
            for (int r = 0; r < 4; ++r)
                h[r] = fmaf(__builtin_amdgcn_exp2f(dl * An2[r]), h[r], t1 * Bs[r]);
        }
    }
    long cb = (((long)dirb * SCH + chunk) * 2048 + d) * 16 + nl * 4;
    *(f32x4*)&hend[cb]  = (f32x4){h[0], h[1], h[2], h[3]};
    *(f32x4*)&aprod[cb] = (f32x4){__builtin_amdgcn_exp2f(S * An2[0]),
                                  __builtin_amdgcn_exp2f(S * An2[1]),
                                  __builtin_amdgcn_exp2f(S * An2[2]),
                                  __builtin_amdgcn_exp2f(S * An2[3])};
}

// scan pass 2: sequential carry combine. hinit in xz x-halves.
__global__ __launch_bounds__(256)
void scan_carry_kernel(const float* __restrict__ hend, const float* __restrict__ aprod,
                       float* __restrict__ hinit)
{
    int f = blockIdx.x * 256 + threadIdx.x;
    int dn = f & 32767;
    int dirb = f >> 15;
    long src = (long)dirb * SCH * 32768 + dn;
    long dst = (long)(dirb >> 1) * 4194304 + (long)(dirb & 1) * 1048576 + dn;
    float hcur = 0.f;
#pragma unroll
    for (int c = 0; c < SCH; ++c) {
        hinit[dst + (long)c * 32768] = hcur;
        hcur = hend[src + (long)c * 32768]
             + aprod[src + (long)c * 32768] * hcur;
    }
}

// scan pass 3: rescan chunk from hinit, emit y16 (fp16).
__global__ __launch_bounds__(256)
void scan_p3_kernel(const _Float16* __restrict__ u16, const _Float16* __restrict__ delta16,
                    const float* __restrict__ xdbl,
                    const float* __restrict__ Alf, const float* __restrict__ Alb,
                    const float* __restrict__ Df, const float* __restrict__ Db,
                    const float* __restrict__ hinit, _Float16* __restrict__ y16)
{
    __shared__ _Float16 sD[64][40], sU[64][40];
    __shared__ float sB[32][20], sC[32][20];
    const int t = threadIdx.x, wid = t >> 6, lane = t & 63;
    const int nl = lane & 3;
    const int dloc = wid * 16 + (lane >> 2);
    const int dblk = blockIdx.x, chunk = blockIdx.y, dirb = blockIdx.z;
    const int d = dblk * 64 + dloc, dir = dirb >> 1;
    const int T0 = chunk * SCL;
    f32x4 Av = *(const f32x4*)((dir ? Alb : Alf) + d * 16 + nl * 4);
    float An2[4] = {-expf(Av.x) * 1.44269504f, -expf(Av.y) * 1.44269504f,
                    -expf(Av.z) * 1.44269504f, -expf(Av.w) * 1.44269504f};
    const float Dd = (dir ? Db : Df)[d];
    const _Float16* dp = delta16 + ((long)dirb * 2048 + dblk * 64) * 1024;
    const _Float16* up = u16    + ((long)dirb * 2048 + dblk * 64) * 1024;
    const float* Bp = xdbl + ((long)dirb * 96 + 64) * 1024;
    const float* Cp = xdbl + ((long)dirb * 96 + 80) * 1024;
    _Float16* yrow = y16 + ((long)dirb * 2048 + d) * 1024;

    {
        int dd = t >> 2, q = t & 3;
        *(f16x8*)&sD[dd][q * 8] = *(const f16x8*)&dp[(long)dd * 1024 + T0 + q * 8];
        *(f16x8*)&sU[dd][q * 8] = *(const f16x8*)&up[(long)dd * 1024 + T0 + q * 8];
    }
#pragma unroll
    for (int rep = 0; rep < 2; ++rep) {
        int ii = rep * 256 + t;
        int n = ii >> 5, tt = ii & 31;
        sB[tt][n] = Bp[(long)n * 1024 + T0 + tt];
        sC[tt][n] = Cp[(long)n * 1024 + T0 + tt];
    }
    long cb = (long)(dirb >> 1) * 4194304 + (long)(dirb & 1) * 1048576
            + (long)chunk * 32768 + (long)d * 16 + nl * 4;
    f32x4 h0v = *(const f32x4*)&hinit[cb];
    float h[4] = {h0v.x, h0v.y, h0v.z, h0v.w};
    const bool m[4] = {nl == 0, nl == 1, nl == 2, nl == 3};
    __syncthreads();

#pragma unroll 4
    for (int g = 0; g < 8; ++g) {
        f16x4 dlh = *(const f16x4*)&sD[dloc][g * 4];
        f16x4 uuh = *(const f16x4*)&sU[dloc][g * 4];
        float dls[4] = {(float)dlh[0], (float)dlh[1], (float)dlh[2], (float)dlh[3]};
        float uus[4] = {(float)uuh[0], (float)uuh[1], (float)uuh[2], (float)uuh[3]};
        float keep = 0.f;
#pragma unroll
        for (int r4 = 0; r4 < 4; ++r4) {
            f32x4 Bv = *(const f32x4*)&sB[g * 4 + r4][nl * 4];
            f32x4 Cv = *(const f32x4*)&sC[g * 4 + r4][nl * 4];
            float Bs[4] = {Bv.x, Bv.y, Bv.z, Bv.w};
            float Cs[4] = {Cv.x, Cv.y, Cv.z, Cv.w};
            float dl = dls[r4], uu = uus[r4];
            float t1 = dl * uu;
#pragma unroll
            for (int r = 0; r < 4; ++r)
                h[r] = fmaf(__builtin_amdgcn_exp2f(dl * An2[r]), h[r], t1 * Bs[r]);
            float p = h[0] * Cs[0];
            p = fmaf(h[1], Cs[1], p);
            p = fmaf(h[2], Cs[2], p);
            p = fmaf(h[3], Cs[3], p);
            p = dpp_add<0xB1>(p);
            p = dpp_add<0x4E>(p);
            float fy = fmaf(Dd, uu, p);
            keep = m[r4] ? fy : keep;
        }
        yrow[T0 + g * 4 + nl] = (_Float16)keep;
    }
}

// G = silu(z) * (y16_f + rev y16_b), written TRANSPOSED as fp16 GT[b][l][d].
__global__ __launch_bounds__(256)
void combine_T_kernel(const float* __restrict__ xz, const _Float16* __restrict__ y16,
                      _Float16* __restrict__ GT)
{
    __shared__ float Ls[64][65];
    const int d0 = blockIdx.x * 64, l0 = blockIdx.y * 64, b = blockIdx.z;
    const int t = threadIdx.x;
#pragma unroll
    for (int rep = 0; rep < 4; ++rep) {
        int i = rep * 256 + t;
        int dl = i >> 4;
        int lq = (i & 15) * 4;
        const float* zp = xz + ((long)b * 4096 + 2048 + d0 + dl) * 1024 + l0 + lq;
        const _Float16* yfp = y16 + ((long)(b)     * 2048 + d0 + dl) * 1024 + l0 + lq;
        const _Float16* ybp = y16 + ((long)(2 + b) * 2048 + d0 + dl) * 1024 + (1020 - l0 - lq);
        float4 vz = *(const float4*)zp;
        f16x4 vf = *(const f16x4*)yfp;
        f16x4 vb = *(const f16x4*)ybp;
        float zz[4]  = {vz.x, vz.y, vz.z, vz.w};
        float ff[4]  = {(float)vf[0], (float)vf[1], (float)vf[2], (float)vf[3]};
        float bbv[4] = {(float)vb[3], (float)vb[2], (float)vb[1], (float)vb[0]};
#pragma unroll
        for (int qq = 0; qq < 4; ++qq) {
            float z = zz[qq];
            float sz = z / (1.f + __builtin_amdgcn_exp2f(-z * 1.44269504f));
            Ls[dl][lq + qq] = sz * (ff[qq] + bbv[qq]);
        }
    }
    __syncthreads();
#pragma unroll
    for (int rep = 0; rep < 4; ++rep) {
        int i = rep * 256 + t;
        int ll = i >> 4;
        int dq = (i & 15) * 4;
        f16x4 h = {(_Float16)Ls[dq][ll], (_Float16)Ls[dq + 1][ll],
                   (_Float16)Ls[dq + 2][ll], (_Float16)Ls[dq + 3][ll]};
        *(f16x4*)(GT + ((long)(b * 1024 + l0 + ll)) * 2048 + d0 + dq) = h;
    }
}

extern "C" void kernel_launch(void* const* d_in, const int* in_sizes, int n_in,
                              void* d_out, int out_size, void* d_ws, size_t ws_size,
                              hipStream_t stream)
{
    const float* hidden   = (const float*)d_in[0];
    const float* inproj_w = (const float*)d_in[1];
    const float* conv_w   = (const float*)d_in[2];
    const float* conv_b   = (const float*)d_in[3];
    const float* xproj_w  = (const float*)d_in[4];
    const float* dtproj_w = (const float*)d_in[5];
    const float* dt_bias  = (const float*)d_in[6];
    const float* A_log    = (const float*)d_in[7];
    const float* D_skip   = (const float*)d_in[8];
    const float* convb_w  = (const float*)d_in[9];
    const float* convb_b  = (const float*)d_in[10];
    const float* xprojb_w = (const float*)d_in[11];
    const float* dtprojb_w= (const float*)d_in[12];
    const float* dtb_bias = (const float*)d_in[13];
    const float* Ab_log   = (const float*)d_in[14];
    const float* Db_skip  = (const float*)d_in[15];
    const float* outproj_w= (const float*)d_in[16];
    float* out = (float*)d_out;

    float* ws    = (float*)d_ws;
    float* xz    = ws;
    float* u     = ws + 8388608;
    float* xdbl  = ws + 16777216;
    float* delta = ws + 17170432;
    float* y     = ws + 25559040;
    // u region: H16 | Win16 | u16 | Wout16
    _Float16* H16    = (_Float16*)u;                   // [0, 1M) f32
    _Float16* Win16  = (_Float16*)(u + 1048576);       // [1M, 3M)
    _Float16* u16    = (_Float16*)(u + 3145728);       // [3M, 7M)
    _Float16* Wout16 = (_Float16*)(u + 7340032);       // [7M, 8M)
    // delta region: delta16 (later GT) | xpb partials
    _Float16* delta16 = (_Float16*)delta;              // [0, 4.2M)
    float*    xpb     = delta + 4194304;               // [4.2M, 7.3M)
    _Float16* GT      = (_Float16*)delta;              // after scan
    // y region: scratch -> hend/aprod -> y16
    _Float16* dw16  = (_Float16*)y;                    // pre-scan scratch
    float*    bcat  = y + 131072;
    _Float16* xw16  = (_Float16*)(y + 135168);
    float* hend  = y;                                  // [0, 4.2M)
    float* aprod = y + 4194304;                        // [4.2M, 8.4M)
    _Float16* y16 = (_Float16*)y;                      // p3 output over dead hend
    float* hinit = xz;                                 // xz x-halves post-conv

    // 0) merged setup
    hipLaunchKernelGGL(setup_kernel, dim3(4096), dim3(256), 0, stream,
        hidden, inproj_w, outproj_w, xproj_w, xprojb_w, dtproj_w, dtprojb_w,
        dt_bias, dtb_bias, H16, Win16, Wout16, xw16, dw16, bcat);

    // 1) in_proj MFMA
    hipLaunchKernelGGL((gemm_nt_f16<2, 2, 4, 4>),
        dim3(32, 8, 2), dim3(256), 0, stream,
        H16, Win16, xz, 1024, 1024, 1048576L, 4194304L);

    // 2) conv + silu -> u16
    hipLaunchKernelGGL(conv_silu_kernel, dim3(32768), dim3(256), 0, stream,
        xz, conv_w, conv_b, convb_w, convb_b, u16);

    // 3) x_proj MFMA split-K + reduce
    hipLaunchKernelGGL(xproj_f16_kernel, dim3(8, XP_SK, 4), dim3(256), 0, stream,
        u16, xw16, xpb);
    hipLaunchKernelGGL(xreduce_kernel, dim3(384), dim3(256), 0, stream,
        xpb, xdbl);

    // 4) dt_proj fp16 MFMA + softplus -> delta16
    hipLaunchKernelGGL(dtproj_f16_kernel, dim3(16, 8, 4), dim3(256), 0, stream,
        xdbl, dw16, bcat, delta16);

    // 5) scan: p1 -> carry -> p3 (y16)
    hipLaunchKernelGGL(scan_p1_kernel, dim3(32, SCH, 4), dim3(256), 0, stream,
        u16, delta16, xdbl, A_log, Ab_log, hend, aprod);
    hipLaunchKernelGGL(scan_carry_kernel, dim3(512), dim3(256), 0, stream,
        hend, aprod, hinit);
    hipLaunchKernelGGL(scan_p3_kernel, dim3(32, SCH, 4), dim3(256), 0, stream,
        u16, delta16, xdbl, A_log, Ab_log, D_skip, Db_skip, hinit, y16);

    // 6) combine -> GT fp16
    hipLaunchKernelGGL(combine_T_kernel, dim3(32, 16, 2), dim3(256), 0, stream,
        xz, y16, GT);

    // 7) out_proj MFMA
    hipLaunchKernelGGL((gemm_nt_f16<4, 1, 2, 4>),
        dim3(32, 8, 1), dim3(256), 0, stream,
        Wout16, GT, out, 2048, 1024, 0L, 0L);
}

// Round 16
// 175.701 us; speedup vs baseline: 1.3018x; 1.0291x over previous
//
#include <hip/hip_runtime.h>
#include <math.h>

// ---------------------------------------------------------------------------
// Bidirectional Mamba block, MI355X. Round 16 (= round 15 resubmit; infra fail):
//  - xz -> fp16 (in_proj C-store casts; conv & combine read fp16): -25MB traffic.
//  - carry chain fp16 (hend/aprod/hinit): carry pass 50->25MB. f32 in-register.
//  - hinit in dead H16/Win16 region; y region = hend16|aprod16 -> y16.
//  - scan geometry (SCH=32, SCL=32, 64 d/blk), all MFMA kernels: verified r14.
// ws layout (f32 elements):
//   xz    region: xz16 [b][4096][1024] fp16 (= 4.2M f32)
//   u     region: [0,2.1M) H16+Win16 -> hinit16 after in_proj
//                 | [3M,7M) u16 | [7M,8M) Wout16  (H16 [0,1M), Win16 [1M,3M))
//   xdbl  [dirb][96][1024] f32
//   delta region: [0,4.2M) delta16 (later GT) | [4.2M,7.3M) xpb partials
//   y     region: head scratch (dw16/bcat/xw16, pre-scan) -> hend16 [0,2.1M) +
//                 aprod16 [2.1M,4.2M) -> y16 [0,4.2M) by p3
// ---------------------------------------------------------------------------

typedef _Float16 f16x8 __attribute__((ext_vector_type(8)));
typedef _Float16 f16x4 __attribute__((ext_vector_type(4)));
typedef float    f32x4 __attribute__((ext_vector_type(4)));

#define SCH 32    // scan chunks
#define SCL 32    // chunk length

__device__ __forceinline__ void gload_lds16(const void* g, void* l) {
    __builtin_amdgcn_global_load_lds(
        (const __attribute__((address_space(1))) void*)g,
        (__attribute__((address_space(3))) void*)l, 16, 0, 0);
}

__device__ __forceinline__ float softplus_f(float x) {
    float e = __builtin_amdgcn_exp2f(-fabsf(x) * 1.44269504f);
    return fmaxf(x, 0.f) + __builtin_amdgcn_logf(1.f + e) * 0.69314718f;
}

template<int CTRL>
__device__ __forceinline__ float dpp_add(float x) {
    int s = __builtin_amdgcn_update_dpp(0, __builtin_bit_cast(int, x),
                                        CTRL, 0xF, 0xF, true);
    return x + __builtin_bit_cast(float, s);
}

// ---------------------------------------------------------------------------
// fp16 NT MFMA GEMM; CT = float or _Float16 output.
// ---------------------------------------------------------------------------
template<int WMW, int WNW, int FM, int FN, typename CT>
__global__ __launch_bounds__(256)
void gemm_nt_f16(const _Float16* __restrict__ A, const _Float16* __restrict__ B,
                 CT* __restrict__ C, int K, int ldc, long sA, long sC)
{
    constexpr int BM = WMW * FM * 16, BN = WNW * FN * 16;
    constexpr int ACH = BM / 8, NCH = (BM + BN) / 8;
    __shared__ __align__(16) _Float16 lds[(BM + BN) * 64];
    A += (long)blockIdx.z * sA;
    C += (long)blockIdx.z * sC;
    const int m0 = blockIdx.y * BM, n0 = blockIdx.x * BN;
    const int t = threadIdx.x, wid = t >> 6, lane = t & 63;
    const int wm = wid / WNW, wn = wid % WNW;
    const int srow = lane >> 3;
    const int skk  = ((lane & 7) ^ srow) * 8;

    f32x4 acc[FM][FN];
#pragma unroll
    for (int i = 0; i < FM; ++i)
#pragma unroll
        for (int j = 0; j < FN; ++j) acc[i][j] = (f32x4){0.f, 0.f, 0.f, 0.f};

    for (int k0 = 0; k0 < K; k0 += 64) {
#pragma unroll
        for (int c = wid; c < NCH; c += 4) {
            const _Float16* gp = (c < ACH)
                ? A + (long)(m0 + c * 8 + srow) * K + k0 + skk
                : B + (long)(n0 + (c - ACH) * 8 + srow) * K + k0 + skk;
            gload_lds16(gp, lds + c * 512);
        }
        __syncthreads();
#pragma unroll
        for (int kw = 0; kw < 2; ++kw) {
            f16x8 af[FM], bf[FN];
#pragma unroll
            for (int i = 0; i < FM; ++i) {
                int r = wm * FM * 16 + i * 16 + (lane & 15);
                af[i] = *(const f16x8*)(lds + r * 64 +
                        (((kw * 4 + (lane >> 4)) ^ (r & 7)) * 8));
            }
#pragma unroll
            for (int j = 0; j < FN; ++j) {
                int r = wn * FN * 16 + j * 16 + (lane & 15);
                bf[j] = *(const f16x8*)(lds + BM * 64 + r * 64 +
                        (((kw * 4 + (lane >> 4)) ^ (r & 7)) * 8));
            }
#pragma unroll
            for (int i = 0; i < FM; ++i)
#pragma unroll
                for (int j = 0; j < FN; ++j)
                    acc[i][j] = __builtin_amdgcn_mfma_f32_16x16x32_f16(
                        af[i], bf[j], acc[i][j], 0, 0, 0);
        }
        __syncthreads();
    }
#pragma unroll
    for (int i = 0; i < FM; ++i)
#pragma unroll
        for (int j = 0; j < FN; ++j) {
            int n = n0 + wn * FN * 16 + j * 16 + (lane & 15);
            int m = m0 + wm * FM * 16 + i * 16 + (lane >> 4) * 4;
            f32x4 v = acc[i][j];
            if constexpr (__is_same(CT, float)) {
                *(f32x4*)&C[(long)n * ldc + m] = v;
            } else {
                f16x4 h = {(_Float16)v.x, (_Float16)v.y, (_Float16)v.z, (_Float16)v.w};
                *(f16x4*)&C[(long)n * ldc + m] = h;
            }
        }
}

// ---------------------------------------------------------------------------
// x_proj fp16 MFMA, split-K (verified r8/r14).
// ---------------------------------------------------------------------------
#define XP_SK 8
__global__ __launch_bounds__(256)
void xproj_f16_kernel(const _Float16* __restrict__ u16, const _Float16* __restrict__ xw16,
                      float* __restrict__ pb)
{
    __shared__ __align__(16) _Float16 Asw[128 * 64];
    __shared__ __align__(16) _Float16 Bsw[96 * 64];
    const int t = threadIdx.x, wid = t >> 6, lane = t & 63;
    const int wm = wid >> 1, wn = wid & 1;
    const int m0 = blockIdx.x * 128;
    const int sk = blockIdx.y, dirb = blockIdx.z;
    const _Float16* ub = u16 + (long)dirb * 2048 * 1024;
    const _Float16* Bw = xw16 + (long)(dirb >> 1) * 96 * 2048;
    const int srow = lane >> 3;
    const int skk  = ((lane & 7) ^ srow) * 8;
    const int lloc = (t & 31) * 4;
    const int kslt = t >> 5;

    f32x4 acc[4][3];
#pragma unroll
    for (int i = 0; i < 4; ++i)
#pragma unroll
        for (int j = 0; j < 3; ++j) acc[i][j] = (f32x4){0.f, 0.f, 0.f, 0.f};

    for (int ks = 0; ks < 2048 / XP_SK; ks += 64) {
        const int k0 = sk * (2048 / XP_SK) + ks;
#pragma unroll
        for (int c = wid; c < 12; c += 4)
            gload_lds16(Bw + (long)(c * 8 + srow) * 2048 + k0 + skk, Bsw + c * 512);
        _Float16 av[8][4];
#pragma unroll
        for (int kk = 0; kk < 8; ++kk) {
            f16x4 v = *(const f16x4*)&ub[(long)(k0 + kslt * 8 + kk) * 1024 + m0 + lloc];
            av[kk][0] = v[0]; av[kk][1] = v[1]; av[kk][2] = v[2]; av[kk][3] = v[3];
        }
#pragma unroll
        for (int q = 0; q < 4; ++q) {
            int l = lloc + q;
            f16x8 h = {av[0][q], av[1][q], av[2][q], av[3][q],
                       av[4][q], av[5][q], av[6][q], av[7][q]};
            *(f16x8*)(Asw + l * 64 + ((kslt ^ (l & 7)) * 8)) = h;
        }
        __syncthreads();
#pragma unroll
        for (int kw = 0; kw < 2; ++kw) {
            f16x8 af[4], bf[3];
#pragma unroll
            for (int i = 0; i < 4; ++i) {
                int r = wm * 64 + i * 16 + (lane & 15);
                af[i] = *(const f16x8*)(Asw + r * 64 +
                        (((kw * 4 + (lane >> 4)) ^ (r & 7)) * 8));
            }
#pragma unroll
            for (int j = 0; j < 3; ++j) {
                int r = wn * 48 + j * 16 + (lane & 15);
                bf[j] = *(const f16x8*)(Bsw + r * 64 +
                        (((kw * 4 + (lane >> 4)) ^ (r & 7)) * 8));
            }
#pragma unroll
            for (int i = 0; i < 4; ++i)
#pragma unroll
                for (int j = 0; j < 3; ++j)
                    acc[i][j] = __builtin_amdgcn_mfma_f32_16x16x32_f16(
                        af[i], bf[j], acc[i][j], 0, 0, 0);
        }
        __syncthreads();
    }
    float* Cp = pb + ((long)sk * 4 + dirb) * 96 * 1024;
#pragma unroll
    for (int i = 0; i < 4; ++i)
#pragma unroll
        for (int j = 0; j < 3; ++j) {
            int n = wn * 48 + j * 16 + (lane & 15);
            int m = m0 + wm * 64 + i * 16 + (lane >> 4) * 4;
            *(f32x4*)&Cp[(long)n * 1024 + m] = acc[i][j];
        }
}

__global__ __launch_bounds__(256)
void xreduce_kernel(const float* __restrict__ pb, float* __restrict__ xdbl)
{
    int f = (blockIdx.x * 256 + threadIdx.x) * 4;
    f32x4 s = (f32x4){0.f, 0.f, 0.f, 0.f};
#pragma unroll
    for (int sk = 0; sk < XP_SK; ++sk)
        s += *(const f32x4*)(pb + (long)sk * 393216 + f);
    *(f32x4*)(xdbl + f) = s;
}

// ---------------------------------------------------------------------------
// dt_proj fp16 MFMA + softplus -> delta16 (verified r14)
// ---------------------------------------------------------------------------
__global__ __launch_bounds__(256)
void dtproj_f16_kernel(const float* __restrict__ xdbl, const _Float16* __restrict__ dw16,
                       const float* __restrict__ bcat, _Float16* __restrict__ delta16)
{
    __shared__ __align__(16) _Float16 Asw[128 * 64];
    __shared__ __align__(16) _Float16 Bsw[128 * 64];
    const int t = threadIdx.x, wid = t >> 6, lane = t & 63;
    const int wm = wid >> 1, wn = wid & 1;
    const int n0 = blockIdx.x * 128, m0 = blockIdx.y * 128;
    const int dirb = blockIdx.z, dir = dirb >> 1;
    const float* Xb = xdbl + (long)dirb * 96 * 1024;
    const _Float16* Bw = dw16 + (long)dir * 2048 * 64;
    const int srow = lane >> 3, skk = ((lane & 7) ^ srow) * 8;
    const int lloc = (t & 31) * 4, kslt = t >> 5;

#pragma unroll
    for (int c = wid; c < 16; c += 4)
        gload_lds16(Bw + (long)(n0 + c * 8 + srow) * 64 + skk, Bsw + c * 512);
    float av[8][4];
#pragma unroll
    for (int kk = 0; kk < 8; ++kk) {
        f32x4 v = *(const f32x4*)&Xb[(long)(kslt * 8 + kk) * 1024 + m0 + lloc];
        av[kk][0] = v.x; av[kk][1] = v.y; av[kk][2] = v.z; av[kk][3] = v.w;
    }
#pragma unroll
    for (int q = 0; q < 4; ++q) {
        int l = lloc + q;
        f16x8 h = {(_Float16)av[0][q], (_Float16)av[1][q], (_Float16)av[2][q],
                   (_Float16)av[3][q], (_Float16)av[4][q], (_Float16)av[5][q],
                   (_Float16)av[6][q], (_Float16)av[7][q]};
        *(f16x8*)(Asw + l * 64 + ((kslt ^ (l & 7)) * 8)) = h;
    }
    __syncthreads();

    f32x4 acc[4][4];
#pragma unroll
    for (int i = 0; i < 4; ++i)
#pragma unroll
        for (int j = 0; j < 4; ++j) acc[i][j] = (f32x4){0.f, 0.f, 0.f, 0.f};
#pragma unroll
    for (int kw = 0; kw < 2; ++kw) {
        f16x8 af[4], bf[4];
#pragma unroll
        for (int i = 0; i < 4; ++i) {
            int r = wm * 64 + i * 16 + (lane & 15);
            af[i] = *(const f16x8*)(Asw + r * 64 +
                    (((kw * 4 + (lane >> 4)) ^ (r & 7)) * 8));
        }
#pragma unroll
        for (int j = 0; j < 4; ++j) {
            int r = wn * 64 + j * 16 + (lane & 15);
            bf[j] = *(const f16x8*)(Bsw + r * 64 +
                    (((kw * 4 + (lane >> 4)) ^ (r & 7)) * 8));
        }
#pragma unroll
        for (int i = 0; i < 4; ++i)
#pragma unroll
            for (int j = 0; j < 4; ++j)
                acc[i][j] = __builtin_amdgcn_mfma_f32_16x16x32_f16(
                    af[i], bf[j], acc[i][j], 0, 0, 0);
    }
    _Float16* Dp = delta16 + (long)dirb * 2048 * 1024;
#pragma unroll
    for (int j = 0; j < 4; ++j) {
        int dd = n0 + wn * 64 + j * 16 + (lane & 15);
        float bm = bcat[dir * 2048 + dd];
#pragma unroll
        for (int i = 0; i < 4; ++i) {
            int m = m0 + wm * 64 + i * 16 + (lane >> 4) * 4;
            f32x4 v = acc[i][j];
            f16x4 o = {(_Float16)softplus_f(v.x + bm), (_Float16)softplus_f(v.y + bm),
                       (_Float16)softplus_f(v.z + bm), (_Float16)softplus_f(v.w + bm)};
            *(f16x4*)&Dp[(long)dd * 1024 + m] = o;
        }
    }
}

// Merged setup (verified r14).
__global__ __launch_bounds__(256)
void setup_kernel(const float* __restrict__ hidden, const float* __restrict__ winp,
                  const float* __restrict__ woutp,
                  const float* __restrict__ xwf, const float* __restrict__ xwb,
                  const float* __restrict__ dwf, const float* __restrict__ dwb,
                  const float* __restrict__ bf,  const float* __restrict__ bb,
                  _Float16* __restrict__ H16, _Float16* __restrict__ Win16,
                  _Float16* __restrict__ Wout16,
                  _Float16* __restrict__ xw16, _Float16* __restrict__ dw16,
                  float* __restrict__ bcat)
{
    long i4 = ((long)blockIdx.x * 256 + threadIdx.x) * 4;
    auto cvt4 = [](const float* s) -> f16x4 {
        float4 v = *(const float4*)s;
        return (f16x4){(_Float16)v.x, (_Float16)v.y, (_Float16)v.z, (_Float16)v.w};
    };
    if (i4 < 4194304) *(f16x4*)(Win16 + i4) = cvt4(winp + i4);
    if (i4 < 2097152) {
        *(f16x4*)(H16 + i4)   = cvt4(hidden + i4);
        *(f16x4*)(Wout16 + i4) = cvt4(woutp + i4);
    }
    if (i4 < 196608) {
        *(f16x4*)(xw16 + i4)          = cvt4(xwf + i4);
        *(f16x4*)(xw16 + 196608 + i4) = cvt4(xwb + i4);
    }
    if (i4 < 131072) {
        *(f16x4*)(dw16 + i4)          = cvt4(dwf + i4);
        *(f16x4*)(dw16 + 131072 + i4) = cvt4(dwb + i4);
    }
    if (i4 < 2048) {
        *(float4*)(bcat + i4)        = *(const float4*)(bf + i4);
        *(float4*)(bcat + 2048 + i4) = *(const float4*)(bb + i4);
    }
}

// Depthwise causal conv (k=4) + SiLU -> u16; reads fp16 xz.
__global__ __launch_bounds__(256)
void conv_silu_kernel(const _Float16* __restrict__ xz16,
                      const float* __restrict__ wf, const float* __restrict__ bf,
                      const float* __restrict__ wb, const float* __restrict__ bbk,
                      _Float16* __restrict__ u16)
{
    long idx = (long)blockIdx.x * 256 + threadIdx.x;
    int l = (int)(idx & 1023);
    long r = idx >> 10;
    int d = (int)(r & 2047);
    int b = (int)((r >> 11) & 1);
    int dir = (int)(r >> 12);
    const _Float16* x = xz16 + ((long)b * 4096 + d) * 1024;
    const float* w = dir ? wb : wf;
    float s = dir ? bbk[d] : bf[d];
    if (dir == 0) {
#pragma unroll
        for (int j = 0; j < 4; ++j) {
            int p = l - 3 + j;
            if (p >= 0) s = fmaf(w[d * 4 + j], (float)x[p], s);
        }
    } else {
#pragma unroll
        for (int j = 0; j < 4; ++j) {
            int src = l - 3 + j;
            if (src >= 0) s = fmaf(w[d * 4 + j], (float)x[1023 - src], s);
        }
    }
    u16[idx] = (_Float16)(s / (1.f + __builtin_amdgcn_exp2f(-s * 1.44269504f)));
}

// ---------------------------------------------------------------------------
// scan pass 1: per-chunk local scan -> hend16/aprod16.
// ---------------------------------------------------------------------------
__global__ __launch_bounds__(256)
void scan_p1_kernel(const _Float16* __restrict__ u16, const _Float16* __restrict__ delta16,
                    const float* __restrict__ xdbl,
                    const float* __restrict__ Alf, const float* __restrict__ Alb,
                    _Float16* __restrict__ hend16, _Float16* __restrict__ aprod16)
{
    __shared__ _Float16 sD[64][40], sU[64][40];
    __shared__ float sB[32][20];
    const int t = threadIdx.x, wid = t >> 6, lane = t & 63;
    const int nl = lane & 3;
    const int dloc = wid * 16 + (lane >> 2);
    const int dblk = blockIdx.x, chunk = blockIdx.y, dirb = blockIdx.z;
    const int d = dblk * 64 + dloc, dir = dirb >> 1;
    const int T0 = chunk * SCL;
    f32x4 Av = *(const f32x4*)((dir ? Alb : Alf) + d * 16 + nl * 4);
    float An2[4] = {-expf(Av.x) * 1.44269504f, -expf(Av.y) * 1.44269504f,
                    -expf(Av.z) * 1.44269504f, -expf(Av.w) * 1.44269504f};
    const _Float16* dp = delta16 + ((long)dirb * 2048 + dblk * 64) * 1024;
    const _Float16* up = u16    + ((long)dirb * 2048 + dblk * 64) * 1024;
    const float* Bp = xdbl + ((long)dirb * 96 + 64) * 1024;

    {
        int dd = t >> 2, q = t & 3;
        *(f16x8*)&sD[dd][q * 8] = *(const f16x8*)&dp[(long)dd * 1024 + T0 + q * 8];
        *(f16x8*)&sU[dd][q * 8] = *(const f16x8*)&up[(long)dd * 1024 + T0 + q * 8];
    }
#pragma unroll
    for (int rep = 0; rep < 2; ++rep) {
        int ii = rep * 256 + t;
        int n = ii >> 5, tt = ii & 31;
        sB[tt][n] = Bp[(long)n * 1024 + T0 + tt];
    }
    __syncthreads();

    float h[4] = {0.f, 0.f, 0.f, 0.f};
    float S = 0.f;
#pragma unroll 4
    for (int g = 0; g < 8; ++g) {
        f16x4 dlh = *(const f16x4*)&sD[dloc][g * 4];
        f16x4 uuh = *(const f16x4*)&sU[dloc][g * 4];
        float dls[4] = {(float)dlh[0], (float)dlh[1], (float)dlh[2], (float)dlh[3]};
        float uus[4] = {(float)uuh[0], (float)uuh[1], (float)uuh[2], (float)uuh[3]};
#pragma unroll
        for (int r4 = 0; r4 < 4; ++r4) {
            f32x4 Bv = *(const f32x4*)&sB[g * 4 + r4][nl * 4];
            float Bs[4] = {Bv.x, Bv.y, Bv.z, Bv.w};
            float dl = dls[r4], t1 = dl * uus[r4];
            S += dl;
#pragma unroll
            for (int r = 0; r < 4; ++r)
                h[r] = fmaf(__builtin_amdgcn_exp2f(dl * An2[r]), h[r], t1 * Bs[r]);
        }
    }
    long cb = (((long)dirb * SCH + chunk) * 2048 + d) * 16 + nl * 4;
    f16x4 he = {(_Float16)h[0], (_Float16)h[1], (_Float16)h[2], (_Float16)h[3]};
    f16x4 ap = {(_Float16)__builtin_amdgcn_exp2f(S * An2[0]),
                (_Float16)__builtin_amdgcn_exp2f(S * An2[1]),
                (_Float16)__builtin_amdgcn_exp2f(S * An2[2]),
                (_Float16)__builtin_amdgcn_exp2f(S * An2[3])};
    *(f16x4*)&hend16[cb]  = he;
    *(f16x4*)&aprod16[cb] = ap;
}

// scan pass 2: sequential carry combine (f32 in-register, fp16 storage).
__global__ __launch_bounds__(256)
void scan_carry_kernel(const _Float16* __restrict__ hend16,
                       const _Float16* __restrict__ aprod16,
                       _Float16* __restrict__ hinit16)
{
    int f = blockIdx.x * 256 + threadIdx.x;   // (dirb, d*16+n)
    int dn = f & 32767;
    int dirb = f >> 15;
    long base = (long)dirb * SCH * 32768 + dn;
    float hcur = 0.f;
#pragma unroll
    for (int c = 0; c < SCH; ++c) {
        hinit16[base + (long)c * 32768] = (_Float16)hcur;
        hcur = (float)hend16[base + (long)c * 32768]
             + (float)aprod16[base + (long)c * 32768] * hcur;
    }
}

// scan pass 3: rescan chunk from hinit16, emit y16.
__global__ __launch_bounds__(256)
void scan_p3_kernel(const _Float16* __restrict__ u16, const _Float16* __restrict__ delta16,
                    const float* __restrict__ xdbl,
                    const float* __restrict__ Alf, const float* __restrict__ Alb,
                    const float* __restrict__ Df, const float* __restrict__ Db,
                    const _Float16* __restrict__ hinit16, _Float16* __restrict__ y16)
{
    __shared__ _Float16 sD[64][40], sU[64][40];
    __shared__ float sB[32][20], sC[32][20];
    const int t = threadIdx.x, wid = t >> 6, lane = t & 63;
    const int nl = lane & 3;
    const int dloc = wid * 16 + (lane >> 2);
    const int dblk = blockIdx.x, chunk = blockIdx.y, dirb = blockIdx.z;
    const int d = dblk * 64 + dloc, dir = dirb >> 1;
    const int T0 = chunk * SCL;
    f32x4 Av = *(const f32x4*)((dir ? Alb : Alf) + d * 16 + nl * 4);
    float An2[4] = {-expf(Av.x) * 1.44269504f, -expf(Av.y) * 1.44269504f,
                    -expf(Av.z) * 1.44269504f, -expf(Av.w) * 1.44269504f};
    const float Dd = (dir ? Db : Df)[d];
    const _Float16* dp = delta16 + ((long)dirb * 2048 + dblk * 64) * 1024;
    const _Float16* up = u16    + ((long)dirb * 2048 + dblk * 64) * 1024;
    const float* Bp = xdbl + ((long)dirb * 96 + 64) * 1024;
    const float* Cp = xdbl + ((long)dirb * 96 + 80) * 1024;
    _Float16* yrow = y16 + ((long)dirb * 2048 + d) * 1024;

    {
        int dd = t >> 2, q = t & 3;
        *(f16x8*)&sD[dd][q * 8] = *(const f16x8*)&dp[(long)dd * 1024 + T0 + q * 8];
        *(f16x8*)&sU[dd][q * 8] = *(const f16x8*)&up[(long)dd * 1024 + T0 + q * 8];
    }
#pragma unroll
    for (int rep = 0; rep < 2; ++rep) {
        int ii = rep * 256 + t;
        int n = ii >> 5, tt = ii & 31;
        sB[tt][n] = Bp[(long)n * 1024 + T0 + tt];
        sC[tt][n] = Cp[(long)n * 1024 + T0 + tt];
    }
    long cb = (((long)dirb * SCH + chunk) * 2048 + d) * 16 + nl * 4;
    f16x4 h0v = *(const f16x4*)&hinit16[cb];
    float h[4] = {(float)h0v[0], (float)h0v[1], (float)h0v[2], (float)h0v[3]};
    const bool m[4] = {nl == 0, nl == 1, nl == 2, nl == 3};
    __syncthreads();

#pragma unroll 4
    for (int g = 0; g < 8; ++g) {
        f16x4 dlh = *(const f16x4*)&sD[dloc][g * 4];
        f16x4 uuh = *(const f16x4*)&sU[dloc][g * 4];
        float dls[4] = {(float)dlh[0], (float)dlh[1], (float)dlh[2], (float)dlh[3]};
        float uus[4] = {(float)uuh[0], (float)uuh[1], (float)uuh[2], (float)uuh[3]};
        float keep = 0.f;
#pragma unroll
        for (int r4 = 0; r4 < 4; ++r4) {
            f32x4 Bv = *(const f32x4*)&sB[g * 4 + r4][nl * 4];
            f32x4 Cv = *(const f32x4*)&sC[g * 4 + r4][nl * 4];
            float Bs[4] = {Bv.x, Bv.y, Bv.z, Bv.w};
            float Cs[4] = {Cv.x, Cv.y, Cv.z, Cv.w};
            float dl = dls[r4], uu = uus[r4];
            float t1 = dl * uu;
#pragma unroll
            for (int r = 0; r < 4; ++r)
                h[r] = fmaf(__builtin_amdgcn_exp2f(dl * An2[r]), h[r], t1 * Bs[r]);
            float p = h[0] * Cs[0];
            p = fmaf(h[1], Cs[1], p);
            p = fmaf(h[2], Cs[2], p);
            p = fmaf(h[3], Cs[3], p);
            p = dpp_add<0xB1>(p);
            p = dpp_add<0x4E>(p);
            float fy = fmaf(Dd, uu, p);
            keep = m[r4] ? fy : keep;
        }
        yrow[T0 + g * 4 + nl] = (_Float16)keep;
    }
}

// G = silu(z16) * (y16_f + rev y16_b) -> fp16 GT[b][l][d] (transposed).
__global__ __launch_bounds__(256)
void combine_T_kernel(const _Float16* __restrict__ xz16, const _Float16* __restrict__ y16,
                      _Float16* __restrict__ GT)
{
    __shared__ float Ls[64][65];
    const int d0 = blockIdx.x * 64, l0 = blockIdx.y * 64, b = blockIdx.z;
    const int t = threadIdx.x;
#pragma unroll
    for (int rep = 0; rep < 4; ++rep) {
        int i = rep * 256 + t;
        int dl = i >> 4;
        int lq = (i & 15) * 4;
        const _Float16* zp  = xz16 + ((long)b * 4096 + 2048 + d0 + dl) * 1024 + l0 + lq;
        const _Float16* yfp = y16 + ((long)(b)     * 2048 + d0 + dl) * 1024 + l0 + lq;
        const _Float16* ybp = y16 + ((long)(2 + b) * 2048 + d0 + dl) * 1024 + (1020 - l0 - lq);
        f16x4 vz = *(const f16x4*)zp;
        f16x4 vf = *(const f16x4*)yfp;
        f16x4 vb = *(const f16x4*)ybp;
        float zz[4]  = {(float)vz[0], (float)vz[1], (float)vz[2], (float)vz[3]};
        float ff[4]  = {(float)vf[0], (float)vf[1], (float)vf[2], (float)vf[3]};
        float bbv[4] = {(float)vb[3], (float)vb[2], (float)vb[1], (float)vb[0]};
#pragma unroll
        for (int qq = 0; qq < 4; ++qq) {
            float z = zz[qq];
            float sz = z / (1.f + __builtin_amdgcn_exp2f(-z * 1.44269504f));
            Ls[dl][lq + qq] = sz * (ff[qq] + bbv[qq]);
        }
    }
    __syncthreads();
#pragma unroll
    for (int rep = 0; rep < 4; ++rep) {
        int i = rep * 256 + t;
        int ll = i >> 4;
        int dq = (i & 15) * 4;
        f16x4 h = {(_Float16)Ls[dq][ll], (_Float16)Ls[dq + 1][ll],
                   (_Float16)Ls[dq + 2][ll], (_Float16)Ls[dq + 3][ll]};
        *(f16x4*)(GT + ((long)(b * 1024 + l0 + ll)) * 2048 + d0 + dq) = h;
    }
}

extern "C" void kernel_launch(void* const* d_in, const int* in_sizes, int n_in,
                              void* d_out, int out_size, void* d_ws, size_t ws_size,
                              hipStream_t stream)
{
    const float* hidden   = (const float*)d_in[0];
    const float* inproj_w = (const float*)d_in[1];
    const float* conv_w   = (const float*)d_in[2];
    const float* conv_b   = (const float*)d_in[3];
    const float* xproj_w  = (const float*)d_in[4];
    const float* dtproj_w = (const float*)d_in[5];
    const float* dt_bias  = (const float*)d_in[6];
    const float* A_log    = (const float*)d_in[7];
    const float* D_skip   = (const float*)d_in[8];
    const float* convb_w  = (const float*)d_in[9];
    const float* convb_b  = (const float*)d_in[10];
    const float* xprojb_w = (const float*)d_in[11];
    const float* dtprojb_w= (const float*)d_in[12];
    const float* dtb_bias = (const float*)d_in[13];
    const float* Ab_log   = (const float*)d_in[14];
    const float* Db_skip  = (const float*)d_in[15];
    const float* outproj_w= (const float*)d_in[16];
    float* out = (float*)d_out;

    float* ws    = (float*)d_ws;
    float* xz    = ws;
    float* u     = ws + 8388608;
    float* xdbl  = ws + 16777216;
    float* delta = ws + 17170432;
    float* y     = ws + 25559040;
    // xz region: fp16 xz
    _Float16* xz16 = (_Float16*)xz;                    // [b][4096][1024] fp16
    // u region: H16 | Win16 | u16 | Wout16; hinit16 overlays H16/Win16 later
    _Float16* H16     = (_Float16*)u;                  // [0, 1M f32)
    _Float16* Win16   = (_Float16*)(u + 1048576);      // [1M, 3M)
    _Float16* u16     = (_Float16*)(u + 3145728);      // [3M, 7M)
    _Float16* Wout16  = (_Float16*)(u + 7340032);      // [7M, 8M)
    _Float16* hinit16 = (_Float16*)u;                  // [0, 2.1M) after in_proj
    // delta region: delta16 (later GT) | xpb partials
    _Float16* delta16 = (_Float16*)delta;              // [0, 4.2M)
    float*    xpb     = delta + 4194304;               // [4.2M, 7.3M)
    _Float16* GT      = (_Float16*)delta;              // after scan
    // y region: scratch -> hend16|aprod16 -> y16
    _Float16* dw16  = (_Float16*)y;
    float*    bcat  = y + 131072;
    _Float16* xw16  = (_Float16*)(y + 135168);
    _Float16* hend16  = (_Float16*)y;                  // [0, 2.1M f32)
    _Float16* aprod16 = (_Float16*)(y + 2097152);      // [2.1M, 4.2M)
    _Float16* y16     = (_Float16*)y;                  // [0, 4.2M) by p3

    // 0) merged setup
    hipLaunchKernelGGL(setup_kernel, dim3(4096), dim3(256), 0, stream,
        hidden, inproj_w, outproj_w, xproj_w, xprojb_w, dtproj_w, dtprojb_w,
        dt_bias, dtb_bias, H16, Win16, Wout16, xw16, dw16, bcat);

    // 1) in_proj MFMA -> fp16 xz
    hipLaunchKernelGGL((gemm_nt_f16<2, 2, 4, 4, _Float16>),
        dim3(32, 8, 2), dim3(256), 0, stream,
        H16, Win16, xz16, 1024, 1024, 1048576L, 4194304L);

    // 2) conv + silu -> u16
    hipLaunchKernelGGL(conv_silu_kernel, dim3(32768), dim3(256), 0, stream,
        xz16, conv_w, conv_b, convb_w, convb_b, u16);

    // 3) x_proj MFMA split-K + reduce
    hipLaunchKernelGGL(xproj_f16_kernel, dim3(8, XP_SK, 4), dim3(256), 0, stream,
        u16, xw16, xpb);
    hipLaunchKernelGGL(xreduce_kernel, dim3(384), dim3(256), 0, stream,
        xpb, xdbl);

    // 4) dt_proj fp16 MFMA + softplus -> delta16
    hipLaunchKernelGGL(dtproj_f16_kernel, dim3(16, 8, 4), dim3(256), 0, stream,
        xdbl, dw16, bcat, delta16);

    // 5) scan: p1 -> carry -> p3
    hipLaunchKernelGGL(scan_p1_kernel, dim3(32, SCH, 4), dim3(256), 0, stream,
        u16, delta16, xdbl, A_log, Ab_log, hend16, aprod16);
    hipLaunchKernelGGL(scan_carry_kernel, dim3(512), dim3(256), 0, stream,
        hend16, aprod16, hinit16);
    hipLaunchKernelGGL(scan_p3_kernel, dim3(32, SCH, 4), dim3(256), 0, stream,
        u16, delta16, xdbl, A_log, Ab_log, D_skip, Db_skip, hinit16, y16);

    // 6) combine -> GT fp16
    hipLaunchKernelGGL(combine_T_kernel, dim3(32, 16, 2), dim3(256), 0, stream,
        xz16, y16, GT);

    // 7) out_proj MFMA -> f32 out
    hipLaunchKernelGGL((gemm_nt_f16<4, 1, 2, 4, float>),
        dim3(32, 8, 1), dim3(256), 0, stream,
        Wout16, GT, out, 2048, 1024, 0L, 0L);
}

// Round 17
// 175.151 us; speedup vs baseline: 1.3059x; 1.0031x over previous
//
#include <hip/hip_runtime.h>
#include <math.h>

// ---------------------------------------------------------------------------
// Bidirectional Mamba block, MI355X. Round 17:
//  - out_proj split-K=2 via z-dim (was 256 blocks = 1 blk/CU, 32 serial
//    K-steps): 512 blocks, f32 partials in dead xz region + oreduce.
//  - in_proj tile 128x128 -> 64x128: 1024 blocks = 4/CU.
//  - gemm template: explicit lda (A/B stride) + sB (B z-offset).
//  - everything else byte-identical to r16 (verified, 175.7us).
// ws layout (f32 elements):
//   xz    region: xz16 fp16 [b][4096][1024] -> opart f32 [2][2048][1024]
//                 (xz16 dead after combine)
//   u     region: [0,2.1M) H16+Win16 -> hinit16 | [3M,7M) u16 | [7M,8M) Wout16
//   xdbl  [dirb][96][1024] f32
//   delta region: [0,4.2M) delta16 (later GT) | [4.2M,7.3M) xpb partials
//   y     region: scratch -> hend16|aprod16 -> y16
// ---------------------------------------------------------------------------

typedef _Float16 f16x8 __attribute__((ext_vector_type(8)));
typedef _Float16 f16x4 __attribute__((ext_vector_type(4)));
typedef float    f32x4 __attribute__((ext_vector_type(4)));

#define SCH 32    // scan chunks
#define SCL 32    // chunk length

__device__ __forceinline__ void gload_lds16(const void* g, void* l) {
    __builtin_amdgcn_global_load_lds(
        (const __attribute__((address_space(1))) void*)g,
        (__attribute__((address_space(3))) void*)l, 16, 0, 0);
}

__device__ __forceinline__ float softplus_f(float x) {
    float e = __builtin_amdgcn_exp2f(-fabsf(x) * 1.44269504f);
    return fmaxf(x, 0.f) + __builtin_amdgcn_logf(1.f + e) * 0.69314718f;
}

template<int CTRL>
__device__ __forceinline__ float dpp_add(float x) {
    int s = __builtin_amdgcn_update_dpp(0, __builtin_bit_cast(int, x),
                                        CTRL, 0xF, 0xF, true);
    return x + __builtin_bit_cast(float, s);
}

// ---------------------------------------------------------------------------
// fp16 NT MFMA GEMM. A MxK', B NxK' (both lda-strided, K'-loop), C[n*ldc+m].
// z-dim offsets: A += z*sA, B += z*sB, C += z*sC (enables batch OR split-K).
// ---------------------------------------------------------------------------
template<int WMW, int WNW, int FM, int FN, typename CT>
__global__ __launch_bounds__(256)
void gemm_nt_f16(const _Float16* __restrict__ A, const _Float16* __restrict__ B,
                 CT* __restrict__ C, int K, int lda, int ldc,
                 long sA, long sB, long sC)
{
    constexpr int BM = WMW * FM * 16, BN = WNW * FN * 16;
    constexpr int ACH = BM / 8, NCH = (BM + BN) / 8;
    __shared__ __align__(16) _Float16 lds[(BM + BN) * 64];
    A += (long)blockIdx.z * sA;
    B += (long)blockIdx.z * sB;
    C += (long)blockIdx.z * sC;
    const int m0 = blockIdx.y * BM, n0 = blockIdx.x * BN;
    const int t = threadIdx.x, wid = t >> 6, lane = t & 63;
    const int wm = wid / WNW, wn = wid % WNW;
    const int srow = lane >> 3;
    const int skk  = ((lane & 7) ^ srow) * 8;

    f32x4 acc[FM][FN];
#pragma unroll
    for (int i = 0; i < FM; ++i)
#pragma unroll
        for (int j = 0; j < FN; ++j) acc[i][j] = (f32x4){0.f, 0.f, 0.f, 0.f};

    for (int k0 = 0; k0 < K; k0 += 64) {
#pragma unroll
        for (int c = wid; c < NCH; c += 4) {
            const _Float16* gp = (c < ACH)
                ? A + (long)(m0 + c * 8 + srow) * lda + k0 + skk
                : B + (long)(n0 + (c - ACH) * 8 + srow) * lda + k0 + skk;
            gload_lds16(gp, lds + c * 512);
        }
        __syncthreads();
#pragma unroll
        for (int kw = 0; kw < 2; ++kw) {
            f16x8 af[FM], bf[FN];
#pragma unroll
            for (int i = 0; i < FM; ++i) {
                int r = wm * FM * 16 + i * 16 + (lane & 15);
                af[i] = *(const f16x8*)(lds + r * 64 +
                        (((kw * 4 + (lane >> 4)) ^ (r & 7)) * 8));
            }
#pragma unroll
            for (int j = 0; j < FN; ++j) {
                int r = wn * FN * 16 + j * 16 + (lane & 15);
                bf[j] = *(const f16x8*)(lds + BM * 64 + r * 64 +
                        (((kw * 4 + (lane >> 4)) ^ (r & 7)) * 8));
            }
#pragma unroll
            for (int i = 0; i < FM; ++i)
#pragma unroll
                for (int j = 0; j < FN; ++j)
                    acc[i][j] = __builtin_amdgcn_mfma_f32_16x16x32_f16(
                        af[i], bf[j], acc[i][j], 0, 0, 0);
        }
        __syncthreads();
    }
#pragma unroll
    for (int i = 0; i < FM; ++i)
#pragma unroll
        for (int j = 0; j < FN; ++j) {
            int n = n0 + wn * FN * 16 + j * 16 + (lane & 15);
            int m = m0 + wm * FM * 16 + i * 16 + (lane >> 4) * 4;
            f32x4 v = acc[i][j];
            if constexpr (__is_same(CT, float)) {
                *(f32x4*)&C[(long)n * ldc + m] = v;
            } else {
                f16x4 h = {(_Float16)v.x, (_Float16)v.y, (_Float16)v.z, (_Float16)v.w};
                *(f16x4*)&C[(long)n * ldc + m] = h;
            }
        }
}

// out = p0 + p1 (out_proj split-K reduce)
__global__ __launch_bounds__(256)
void oreduce_kernel(const float* __restrict__ p, float* __restrict__ out)
{
    int f = (blockIdx.x * 256 + threadIdx.x) * 4;
    f32x4 a = *(const f32x4*)(p + f);
    f32x4 b = *(const f32x4*)(p + 2097152 + f);
    *(f32x4*)(out + f) = a + b;
}

// ---------------------------------------------------------------------------
// x_proj fp16 MFMA, split-K (verified r8/r14).
// ---------------------------------------------------------------------------
#define XP_SK 8
__global__ __launch_bounds__(256)
void xproj_f16_kernel(const _Float16* __restrict__ u16, const _Float16* __restrict__ xw16,
                      float* __restrict__ pb)
{
    __shared__ __align__(16) _Float16 Asw[128 * 64];
    __shared__ __align__(16) _Float16 Bsw[96 * 64];
    const int t = threadIdx.x, wid = t >> 6, lane = t & 63;
    const int wm = wid >> 1, wn = wid & 1;
    const int m0 = blockIdx.x * 128;
    const int sk = blockIdx.y, dirb = blockIdx.z;
    const _Float16* ub = u16 + (long)dirb * 2048 * 1024;
    const _Float16* Bw = xw16 + (long)(dirb >> 1) * 96 * 2048;
    const int srow = lane >> 3;
    const int skk  = ((lane & 7) ^ srow) * 8;
    const int lloc = (t & 31) * 4;
    const int kslt = t >> 5;

    f32x4 acc[4][3];
#pragma unroll
    for (int i = 0; i < 4; ++i)
#pragma unroll
        for (int j = 0; j < 3; ++j) acc[i][j] = (f32x4){0.f, 0.f, 0.f, 0.f};

    for (int ks = 0; ks < 2048 / XP_SK; ks += 64) {
        const int k0 = sk * (2048 / XP_SK) + ks;
#pragma unroll
        for (int c = wid; c < 12; c += 4)
            gload_lds16(Bw + (long)(c * 8 + srow) * 2048 + k0 + skk, Bsw + c * 512);
        _Float16 av[8][4];
#pragma unroll
        for (int kk = 0; kk < 8; ++kk) {
            f16x4 v = *(const f16x4*)&ub[(long)(k0 + kslt * 8 + kk) * 1024 + m0 + lloc];
            av[kk][0] = v[0]; av[kk][1] = v[1]; av[kk][2] = v[2]; av[kk][3] = v[3];
        }
#pragma unroll
        for (int q = 0; q < 4; ++q) {
            int l = lloc + q;
            f16x8 h = {av[0][q], av[1][q], av[2][q], av[3][q],
                       av[4][q], av[5][q], av[6][q], av[7][q]};
            *(f16x8*)(Asw + l * 64 + ((kslt ^ (l & 7)) * 8)) = h;
        }
        __syncthreads();
#pragma unroll
        for (int kw = 0; kw < 2; ++kw) {
            f16x8 af[4], bf[3];
#pragma unroll
            for (int i = 0; i < 4; ++i) {
                int r = wm * 64 + i * 16 + (lane & 15);
                af[i] = *(const f16x8*)(Asw + r * 64 +
                        (((kw * 4 + (lane >> 4)) ^ (r & 7)) * 8));
            }
#pragma unroll
            for (int j = 0; j < 3; ++j) {
                int r = wn * 48 + j * 16 + (lane & 15);
                bf[j] = *(const f16x8*)(Bsw + r * 64 +
                        (((kw * 4 + (lane >> 4)) ^ (r & 7)) * 8));
            }
#pragma unroll
            for (int i = 0; i < 4; ++i)
#pragma unroll
                for (int j = 0; j < 3; ++j)
                    acc[i][j] = __builtin_amdgcn_mfma_f32_16x16x32_f16(
                        af[i], bf[j], acc[i][j], 0, 0, 0);
        }
        __syncthreads();
    }
    float* Cp = pb + ((long)sk * 4 + dirb) * 96 * 1024;
#pragma unroll
    for (int i = 0; i < 4; ++i)
#pragma unroll
        for (int j = 0; j < 3; ++j) {
            int n = wn * 48 + j * 16 + (lane & 15);
            int m = m0 + wm * 64 + i * 16 + (lane >> 4) * 4;
            *(f32x4*)&Cp[(long)n * 1024 + m] = acc[i][j];
        }
}

__global__ __launch_bounds__(256)
void xreduce_kernel(const float* __restrict__ pb, float* __restrict__ xdbl)
{
    int f = (blockIdx.x * 256 + threadIdx.x) * 4;
    f32x4 s = (f32x4){0.f, 0.f, 0.f, 0.f};
#pragma unroll
    for (int sk = 0; sk < XP_SK; ++sk)
        s += *(const f32x4*)(pb + (long)sk * 393216 + f);
    *(f32x4*)(xdbl + f) = s;
}

// ---------------------------------------------------------------------------
// dt_proj fp16 MFMA + softplus -> delta16 (verified r14)
// ---------------------------------------------------------------------------
__global__ __launch_bounds__(256)
void dtproj_f16_kernel(const float* __restrict__ xdbl, const _Float16* __restrict__ dw16,
                       const float* __restrict__ bcat, _Float16* __restrict__ delta16)
{
    __shared__ __align__(16) _Float16 Asw[128 * 64];
    __shared__ __align__(16) _Float16 Bsw[128 * 64];
    const int t = threadIdx.x, wid = t >> 6, lane = t & 63;
    const int wm = wid >> 1, wn = wid & 1;
    const int n0 = blockIdx.x * 128, m0 = blockIdx.y * 128;
    const int dirb = blockIdx.z, dir = dirb >> 1;
    const float* Xb = xdbl + (long)dirb * 96 * 1024;
    const _Float16* Bw = dw16 + (long)dir * 2048 * 64;
    const int srow = lane >> 3, skk = ((lane & 7) ^ srow) * 8;
    const int lloc = (t & 31) * 4, kslt = t >> 5;

#pragma unroll
    for (int c = wid; c < 16; c += 4)
        gload_lds16(Bw + (long)(n0 + c * 8 + srow) * 64 + skk, Bsw + c * 512);
    float av[8][4];
#pragma unroll
    for (int kk = 0; kk < 8; ++kk) {
        f32x4 v = *(const f32x4*)&Xb[(long)(kslt * 8 + kk) * 1024 + m0 + lloc];
        av[kk][0] = v.x; av[kk][1] = v.y; av[kk][2] = v.z; av[kk][3] = v.w;
    }
#pragma unroll
    for (int q = 0; q < 4; ++q) {
        int l = lloc + q;
        f16x8 h = {(_Float16)av[0][q], (_Float16)av[1][q], (_Float16)av[2][q],
                   (_Float16)av[3][q], (_Float16)av[4][q], (_Float16)av[5][q],
                   (_Float16)av[6][q], (_Float16)av[7][q]};
        *(f16x8*)(Asw + l * 64 + ((kslt ^ (l & 7)) * 8)) = h;
    }
    __syncthreads();

    f32x4 acc[4][4];
#pragma unroll
    for (int i = 0; i < 4; ++i)
#pragma unroll
        for (int j = 0; j < 4; ++j) acc[i][j] = (f32x4){0.f, 0.f, 0.f, 0.f};
#pragma unroll
    for (int kw = 0; kw < 2; ++kw) {
        f16x8 af[4], bf[4];
#pragma unroll
        for (int i = 0; i < 4; ++i) {
            int r = wm * 64 + i * 16 + (lane & 15);
            af[i] = *(const f16x8*)(Asw + r * 64 +
                    (((kw * 4 + (lane >> 4)) ^ (r & 7)) * 8));
        }
#pragma unroll
        for (int j = 0; j < 4; ++j) {
            int r = wn * 64 + j * 16 + (lane & 15);
            bf[j] = *(const f16x8*)(Bsw + r * 64 +
                    (((kw * 4 + (lane >> 4)) ^ (r & 7)) * 8));
        }
#pragma unroll
        for (int i = 0; i < 4; ++i)
#pragma unroll
            for (int j = 0; j < 4; ++j)
                acc[i][j] = __builtin_amdgcn_mfma_f32_16x16x32_f16(
                    af[i], bf[j], acc[i][j], 0, 0, 0);
    }
    _Float16* Dp = delta16 + (long)dirb * 2048 * 1024;
#pragma unroll
    for (int j = 0; j < 4; ++j) {
        int dd = n0 + wn * 64 + j * 16 + (lane & 15);
        float bm = bcat[dir * 2048 + dd];
#pragma unroll
        for (int i = 0; i < 4; ++i) {
            int m = m0 + wm * 64 + i * 16 + (lane >> 4) * 4;
            f32x4 v = acc[i][j];
            f16x4 o = {(_Float16)softplus_f(v.x + bm), (_Float16)softplus_f(v.y + bm),
                       (_Float16)softplus_f(v.z + bm), (_Float16)softplus_f(v.w + bm)};
            *(f16x4*)&Dp[(long)dd * 1024 + m] = o;
        }
    }
}

// Merged setup (verified r14).
__global__ __launch_bounds__(256)
void setup_kernel(const float* __restrict__ hidden, const float* __restrict__ winp,
                  const float* __restrict__ woutp,
                  const float* __restrict__ xwf, const float* __restrict__ xwb,
                  const float* __restrict__ dwf, const float* __restrict__ dwb,
                  const float* __restrict__ bf,  const float* __restrict__ bb,
                  _Float16* __restrict__ H16, _Float16* __restrict__ Win16,
                  _Float16* __restrict__ Wout16,
                  _Float16* __restrict__ xw16, _Float16* __restrict__ dw16,
                  float* __restrict__ bcat)
{
    long i4 = ((long)blockIdx.x * 256 + threadIdx.x) * 4;
    auto cvt4 = [](const float* s) -> f16x4 {
        float4 v = *(const float4*)s;
        return (f16x4){(_Float16)v.x, (_Float16)v.y, (_Float16)v.z, (_Float16)v.w};
    };
    if (i4 < 4194304) *(f16x4*)(Win16 + i4) = cvt4(winp + i4);
    if (i4 < 2097152) {
        *(f16x4*)(H16 + i4)   = cvt4(hidden + i4);
        *(f16x4*)(Wout16 + i4) = cvt4(woutp + i4);
    }
    if (i4 < 196608) {
        *(f16x4*)(xw16 + i4)          = cvt4(xwf + i4);
        *(f16x4*)(xw16 + 196608 + i4) = cvt4(xwb + i4);
    }
    if (i4 < 131072) {
        *(f16x4*)(dw16 + i4)          = cvt4(dwf + i4);
        *(f16x4*)(dw16 + 131072 + i4) = cvt4(dwb + i4);
    }
    if (i4 < 2048) {
        *(float4*)(bcat + i4)        = *(const float4*)(bf + i4);
        *(float4*)(bcat + 2048 + i4) = *(const float4*)(bb + i4);
    }
}

// Depthwise causal conv (k=4) + SiLU -> u16; reads fp16 xz.
__global__ __launch_bounds__(256)
void conv_silu_kernel(const _Float16* __restrict__ xz16,
                      const float* __restrict__ wf, const float* __restrict__ bf,
                      const float* __restrict__ wb, const float* __restrict__ bbk,
                      _Float16* __restrict__ u16)
{
    long idx = (long)blockIdx.x * 256 + threadIdx.x;
    int l = (int)(idx & 1023);
    long r = idx >> 10;
    int d = (int)(r & 2047);
    int b = (int)((r >> 11) & 1);
    int dir = (int)(r >> 12);
    const _Float16* x = xz16 + ((long)b * 4096 + d) * 1024;
    const float* w = dir ? wb : wf;
    float s = dir ? bbk[d] : bf[d];
    if (dir == 0) {
#pragma unroll
        for (int j = 0; j < 4; ++j) {
            int p = l - 3 + j;
            if (p >= 0) s = fmaf(w[d * 4 + j], (float)x[p], s);
        }
    } else {
#pragma unroll
        for (int j = 0; j < 4; ++j) {
            int src = l - 3 + j;
            if (src >= 0) s = fmaf(w[d * 4 + j], (float)x[1023 - src], s);
        }
    }
    u16[idx] = (_Float16)(s / (1.f + __builtin_amdgcn_exp2f(-s * 1.44269504f)));
}

// ---------------------------------------------------------------------------
// scan pass 1: per-chunk local scan -> hend16/aprod16 (verified r16).
// ---------------------------------------------------------------------------
__global__ __launch_bounds__(256)
void scan_p1_kernel(const _Float16* __restrict__ u16, const _Float16* __restrict__ delta16,
                    const float* __restrict__ xdbl,
                    const float* __restrict__ Alf, const float* __restrict__ Alb,
                    _Float16* __restrict__ hend16, _Float16* __restrict__ aprod16)
{
    __shared__ _Float16 sD[64][40], sU[64][40];
    __shared__ float sB[32][20];
    const int t = threadIdx.x, wid = t >> 6, lane = t & 63;
    const int nl = lane & 3;
    const int dloc = wid * 16 + (lane >> 2);
    const int dblk = blockIdx.x, chunk = blockIdx.y, dirb = blockIdx.z;
    const int d = dblk * 64 + dloc, dir = dirb >> 1;
    const int T0 = chunk * SCL;
    f32x4 Av = *(const f32x4*)((dir ? Alb : Alf) + d * 16 + nl * 4);
    float An2[4] = {-expf(Av.x) * 1.44269504f, -expf(Av.y) * 1.44269504f,
                    -expf(Av.z) * 1.44269504f, -expf(Av.w) * 1.44269504f};
    const _Float16* dp = delta16 + ((long)dirb * 2048 + dblk * 64) * 1024;
    const _Float16* up = u16    + ((long)dirb * 2048 + dblk * 64) * 1024;
    const float* Bp = xdbl + ((long)dirb * 96 + 64) * 1024;

    {
        int dd = t >> 2, q = t & 3;
        *(f16x8*)&sD[dd][q * 8] = *(const f16x8*)&dp[(long)dd * 1024 + T0 + q * 8];
        *(f16x8*)&sU[dd][q * 8] = *(const f16x8*)&up[(long)dd * 1024 + T0 + q * 8];
    }
#pragma unroll
    for (int rep = 0; rep < 2; ++rep) {
        int ii = rep * 256 + t;
        int n = ii >> 5, tt = ii & 31;
        sB[tt][n] = Bp[(long)n * 1024 + T0 + tt];
    }
    __syncthreads();

    float h[4] = {0.f, 0.f, 0.f, 0.f};
    float S = 0.f;
#pragma unroll 4
    for (int g = 0; g < 8; ++g) {
        f16x4 dlh = *(const f16x4*)&sD[dloc][g * 4];
        f16x4 uuh = *(const f16x4*)&sU[dloc][g * 4];
        float dls[4] = {(float)dlh[0], (float)dlh[1], (float)dlh[2], (float)dlh[3]};
        float uus[4] = {(float)uuh[0], (float)uuh[1], (float)uuh[2], (float)uuh[3]};
#pragma unroll
        for (int r4 = 0; r4 < 4; ++r4) {
            f32x4 Bv = *(const f32x4*)&sB[g * 4 + r4][nl * 4];
            float Bs[4] = {Bv.x, Bv.y, Bv.z, Bv.w};
            float dl = dls[r4], t1 = dl * uus[r4];
            S += dl;
#pragma unroll
            for (int r = 0; r < 4; ++r)
                h[r] = fmaf(__builtin_amdgcn_exp2f(dl * An2[r]), h[r], t1 * Bs[r]);
        }
    }
    long cb = (((long)dirb * SCH + chunk) * 2048 + d) * 16 + nl * 4;
    f16x4 he = {(_Float16)h[0], (_Float16)h[1], (_Float16)h[2], (_Float16)h[3]};
    f16x4 ap = {(_Float16)__builtin_amdgcn_exp2f(S * An2[0]),
                (_Float16)__builtin_amdgcn_exp2f(S * An2[1]),
                (_Float16)__builtin_amdgcn_exp2f(S * An2[2]),
                (_Float16)__builtin_amdgcn_exp2f(S * An2[3])};
    *(f16x4*)&hend16[cb]  = he;
    *(f16x4*)&aprod16[cb] = ap;
}

// scan pass 2: sequential carry combine (f32 in-register, fp16 storage).
__global__ __launch_bounds__(256)
void scan_carry_kernel(const _Float16* __restrict__ hend16,
                       const _Float16* __restrict__ aprod16,
                       _Float16* __restrict__ hinit16)
{
    int f = blockIdx.x * 256 + threadIdx.x;   // (dirb, d*16+n)
    int dn = f & 32767;
    int dirb = f >> 15;
    long base = (long)dirb * SCH * 32768 + dn;
    float hcur = 0.f;
#pragma unroll
    for (int c = 0; c < SCH; ++c) {
        hinit16[base + (long)c * 32768] = (_Float16)hcur;
        hcur = (float)hend16[base + (long)c * 32768]
             + (float)aprod16[base + (long)c * 32768] * hcur;
    }
}

// scan pass 3: rescan chunk from hinit16, emit y16 (verified r16).
__global__ __launch_bounds__(256)
void scan_p3_kernel(const _Float16* __restrict__ u16, const _Float16* __restrict__ delta16,
                    const float* __restrict__ xdbl,
                    const float* __restrict__ Alf, const float* __restrict__ Alb,
                    const float* __restrict__ Df, const float* __restrict__ Db,
                    const _Float16* __restrict__ hinit16, _Float16* __restrict__ y16)
{
    __shared__ _Float16 sD[64][40], sU[64][40];
    __shared__ float sB[32][20], sC[32][20];
    const int t = threadIdx.x, wid = t >> 6, lane = t & 63;
    const int nl = lane & 3;
    const int dloc = wid * 16 + (lane >> 2);
    const int dblk = blockIdx.x, chunk = blockIdx.y, dirb = blockIdx.z;
    const int d = dblk * 64 + dloc, dir = dirb >> 1;
    const int T0 = chunk * SCL;
    f32x4 Av = *(const f32x4*)((dir ? Alb : Alf) + d * 16 + nl * 4);
    float An2[4] = {-expf(Av.x) * 1.44269504f, -expf(Av.y) * 1.44269504f,
                    -expf(Av.z) * 1.44269504f, -expf(Av.w) * 1.44269504f};
    const float Dd = (dir ? Db : Df)[d];
    const _Float16* dp = delta16 + ((long)dirb * 2048 + dblk * 64) * 1024;
    const _Float16* up = u16    + ((long)dirb * 2048 + dblk * 64) * 1024;
    const float* Bp = xdbl + ((long)dirb * 96 + 64) * 1024;
    const float* Cp = xdbl + ((long)dirb * 96 + 80) * 1024;
    _Float16* yrow = y16 + ((long)dirb * 2048 + d) * 1024;

    {
        int dd = t >> 2, q = t & 3;
        *(f16x8*)&sD[dd][q * 8] = *(const f16x8*)&dp[(long)dd * 1024 + T0 + q * 8];
        *(f16x8*)&sU[dd][q * 8] = *(const f16x8*)&up[(long)dd * 1024 + T0 + q * 8];
    }
#pragma unroll
    for (int rep = 0; rep < 2; ++rep) {
        int ii = rep * 256 + t;
        int n = ii >> 5, tt = ii & 31;
        sB[tt][n] = Bp[(long)n * 1024 + T0 + tt];
        sC[tt][n] = Cp[(long)n * 1024 + T0 + tt];
    }
    long cb = (((long)dirb * SCH + chunk) * 2048 + d) * 16 + nl * 4;
    f16x4 h0v = *(const f16x4*)&hinit16[cb];
    float h[4] = {(float)h0v[0], (float)h0v[1], (float)h0v[2], (float)h0v[3]};
    const bool m[4] = {nl == 0, nl == 1, nl == 2, nl == 3};
    __syncthreads();

#pragma unroll 4
    for (int g = 0; g < 8; ++g) {
        f16x4 dlh = *(const f16x4*)&sD[dloc][g * 4];
        f16x4 uuh = *(const f16x4*)&sU[dloc][g * 4];
        float dls[4] = {(float)dlh[0], (float)dlh[1], (float)dlh[2], (float)dlh[3]};
        float uus[4] = {(float)uuh[0], (float)uuh[1], (float)uuh[2], (float)uuh[3]};
        float keep = 0.f;
#pragma unroll
        for (int r4 = 0; r4 < 4; ++r4) {
            f32x4 Bv = *(const f32x4*)&sB[g * 4 + r4][nl * 4];
            f32x4 Cv = *(const f32x4*)&sC[g * 4 + r4][nl * 4];
            float Bs[4] = {Bv.x, Bv.y, Bv.z, Bv.w};
            float Cs[4] = {Cv.x, Cv.y, Cv.z, Cv.w};
            float dl = dls[r4], uu = uus[r4];
            float t1 = dl * uu;
#pragma unroll
            for (int r = 0; r < 4; ++r)
                h[r] = fmaf(__builtin_amdgcn_exp2f(dl * An2[r]), h[r], t1 * Bs[r]);
            float p = h[0] * Cs[0];
            p = fmaf(h[1], Cs[1], p);
            p = fmaf(h[2], Cs[2], p);
            p = fmaf(h[3], Cs[3], p);
            p = dpp_add<0xB1>(p);
            p = dpp_add<0x4E>(p);
            float fy = fmaf(Dd, uu, p);
            keep = m[r4] ? fy : keep;
        }
        yrow[T0 + g * 4 + nl] = (_Float16)keep;
    }
}

// G = silu(z16) * (y16_f + rev y16_b) -> fp16 GT[b][l][d] (transposed).
__global__ __launch_bounds__(256)
void combine_T_kernel(const _Float16* __restrict__ xz16, const _Float16* __restrict__ y16,
                      _Float16* __restrict__ GT)
{
    __shared__ float Ls[64][65];
    const int d0 = blockIdx.x * 64, l0 = blockIdx.y * 64, b = blockIdx.z;
    const int t = threadIdx.x;
#pragma unroll
    for (int rep = 0; rep < 4; ++rep) {
        int i = rep * 256 + t;
        int dl = i >> 4;
        int lq = (i & 15) * 4;
        const _Float16* zp  = xz16 + ((long)b * 4096 + 2048 + d0 + dl) * 1024 + l0 + lq;
        const _Float16* yfp = y16 + ((long)(b)     * 2048 + d0 + dl) * 1024 + l0 + lq;
        const _Float16* ybp = y16 + ((long)(2 + b) * 2048 + d0 + dl) * 1024 + (1020 - l0 - lq);
        f16x4 vz = *(const f16x4*)zp;
        f16x4 vf = *(const f16x4*)yfp;
        f16x4 vb = *(const f16x4*)ybp;
        float zz[4]  = {(float)vz[0], (float)vz[1], (float)vz[2], (float)vz[3]};
        float ff[4]  = {(float)vf[0], (float)vf[1], (float)vf[2], (float)vf[3]};
        float bbv[4] = {(float)vb[3], (float)vb[2], (float)vb[1], (float)vb[0]};
#pragma unroll
        for (int qq = 0; qq < 4; ++qq) {
            float z = zz[qq];
            float sz = z / (1.f + __builtin_amdgcn_exp2f(-z * 1.44269504f));
            Ls[dl][lq + qq] = sz * (ff[qq] + bbv[qq]);
        }
    }
    __syncthreads();
#pragma unroll
    for (int rep = 0; rep < 4; ++rep) {
        int i = rep * 256 + t;
        int ll = i >> 4;
        int dq = (i & 15) * 4;
        f16x4 h = {(_Float16)Ls[dq][ll], (_Float16)Ls[dq + 1][ll],
                   (_Float16)Ls[dq + 2][ll], (_Float16)Ls[dq + 3][ll]};
        *(f16x4*)(GT + ((long)(b * 1024 + l0 + ll)) * 2048 + d0 + dq) = h;
    }
}

extern "C" void kernel_launch(void* const* d_in, const int* in_sizes, int n_in,
                              void* d_out, int out_size, void* d_ws, size_t ws_size,
                              hipStream_t stream)
{
    const float* hidden   = (const float*)d_in[0];
    const float* inproj_w = (const float*)d_in[1];
    const float* conv_w   = (const float*)d_in[2];
    const float* conv_b   = (const float*)d_in[3];
    const float* xproj_w  = (const float*)d_in[4];
    const float* dtproj_w = (const float*)d_in[5];
    const float* dt_bias  = (const float*)d_in[6];
    const float* A_log    = (const float*)d_in[7];
    const float* D_skip   = (const float*)d_in[8];
    const float* convb_w  = (const float*)d_in[9];
    const float* convb_b  = (const float*)d_in[10];
    const float* xprojb_w = (const float*)d_in[11];
    const float* dtprojb_w= (const float*)d_in[12];
    const float* dtb_bias = (const float*)d_in[13];
    const float* Ab_log   = (const float*)d_in[14];
    const float* Db_skip  = (const float*)d_in[15];
    const float* outproj_w= (const float*)d_in[16];
    float* out = (float*)d_out;

    float* ws    = (float*)d_ws;
    float* xz    = ws;
    float* u     = ws + 8388608;
    float* xdbl  = ws + 16777216;
    float* delta = ws + 17170432;
    float* y     = ws + 25559040;
    // xz region: fp16 xz, then out_proj f32 partials (xz16 dead after combine)
    _Float16* xz16  = (_Float16*)xz;                   // [b][4096][1024] fp16
    float*    opart = xz;                              // [2][2048][1024] f32
    // u region: H16 | Win16 | u16 | Wout16; hinit16 overlays H16/Win16 later
    _Float16* H16     = (_Float16*)u;
    _Float16* Win16   = (_Float16*)(u + 1048576);
    _Float16* u16     = (_Float16*)(u + 3145728);
    _Float16* Wout16  = (_Float16*)(u + 7340032);
    _Float16* hinit16 = (_Float16*)u;
    // delta region: delta16 (later GT) | xpb partials
    _Float16* delta16 = (_Float16*)delta;
    float*    xpb     = delta + 4194304;
    _Float16* GT      = (_Float16*)delta;
    // y region: scratch -> hend16|aprod16 -> y16
    _Float16* dw16  = (_Float16*)y;
    float*    bcat  = y + 131072;
    _Float16* xw16  = (_Float16*)(y + 135168);
    _Float16* hend16  = (_Float16*)y;
    _Float16* aprod16 = (_Float16*)(y + 2097152);
    _Float16* y16     = (_Float16*)y;

    // 0) merged setup
    hipLaunchKernelGGL(setup_kernel, dim3(4096), dim3(256), 0, stream,
        hidden, inproj_w, outproj_w, xproj_w, xprojb_w, dtproj_w, dtprojb_w,
        dt_bias, dtb_bias, H16, Win16, Wout16, xw16, dw16, bcat);

    // 1) in_proj MFMA -> fp16 xz (64x128 tiles, 1024 blocks)
    hipLaunchKernelGGL((gemm_nt_f16<2, 2, 2, 4, _Float16>),
        dim3(32, 16, 2), dim3(256), 0, stream,
        H16, Win16, xz16, 1024, 1024, 1024, 1048576L, 0L, 4194304L);

    // 2) conv + silu -> u16
    hipLaunchKernelGGL(conv_silu_kernel, dim3(32768), dim3(256), 0, stream,
        xz16, conv_w, conv_b, convb_w, convb_b, u16);

    // 3) x_proj MFMA split-K + reduce
    hipLaunchKernelGGL(xproj_f16_kernel, dim3(8, XP_SK, 4), dim3(256), 0, stream,
        u16, xw16, xpb);
    hipLaunchKernelGGL(xreduce_kernel, dim3(384), dim3(256), 0, stream,
        xpb, xdbl);

    // 4) dt_proj fp16 MFMA + softplus -> delta16
    hipLaunchKernelGGL(dtproj_f16_kernel, dim3(16, 8, 4), dim3(256), 0, stream,
        xdbl, dw16, bcat, delta16);

    // 5) scan: p1 -> carry -> p3
    hipLaunchKernelGGL(scan_p1_kernel, dim3(32, SCH, 4), dim3(256), 0, stream,
        u16, delta16, xdbl, A_log, Ab_log, hend16, aprod16);
    hipLaunchKernelGGL(scan_carry_kernel, dim3(512), dim3(256), 0, stream,
        hend16, aprod16, hinit16);
    hipLaunchKernelGGL(scan_p3_kernel, dim3(32, SCH, 4), dim3(256), 0, stream,
        u16, delta16, xdbl, A_log, Ab_log, D_skip, Db_skip, hinit16, y16);

    // 6) combine -> GT fp16 (xz16 dead afterwards)
    hipLaunchKernelGGL(combine_T_kernel, dim3(32, 16, 2), dim3(256), 0, stream,
        xz16, y16, GT);

    // 7) out_proj MFMA split-K=2 -> f32 partials in dead xz region
    hipLaunchKernelGGL((gemm_nt_f16<4, 1, 2, 4, float>),
        dim3(32, 8, 2), dim3(256), 0, stream,
        Wout16, GT, opart, 1024, 2048, 1024, 1024L, 1024L, 2097152L);

    // 8) out = p0 + p1
    hipLaunchKernelGGL(oreduce_kernel, dim3(2048), dim3(256), 0, stream,
        opart, out);
}

// Round 18
// 173.445 us; speedup vs baseline: 1.3188x; 1.0098x over previous
//
#include <hip/hip_runtime.h>
#include <math.h>

// ---------------------------------------------------------------------------
// Bidirectional Mamba block, MI355X. Round 18:
//  - FUSED p3+combine (scan_p3c): each block pairs (dir0,chunk c) with
//    (dir1,chunk 31-c) for the same 64 d's: y_f and reversed y_b co-resident
//    in LDS -> combine + GT transpose in-block. Removes y16 round-trip
//    (~25MB) and the combine launch. GT relocated to y region (hend/aprod
//    dead after carry) to avoid aliasing delta16 which p3c reads.
//  - all other kernels byte-identical to r17 (verified, 175.2us).
// ws layout (f32 elements):
//   xz    region: xz16 fp16 -> opart f32 [2][2048][1024] (xz16 dead after p3c)
//   u     region: [0,2.1M) H16+Win16 -> hinit16 | [3M,7M) u16 | [7M,8M) Wout16
//   xdbl  [dirb][96][1024] f32
//   delta region: [0,4.2M) delta16 | [4.2M,7.3M) xpb partials
//   y     region: scratch -> hend16|aprod16 (dead after carry) -> GT [0,2.1M)
// ---------------------------------------------------------------------------

typedef _Float16 f16x8 __attribute__((ext_vector_type(8)));
typedef _Float16 f16x4 __attribute__((ext_vector_type(4)));
typedef float    f32x4 __attribute__((ext_vector_type(4)));

#define SCH 32    // scan chunks
#define SCL 32    // chunk length

__device__ __forceinline__ void gload_lds16(const void* g, void* l) {
    __builtin_amdgcn_global_load_lds(
        (const __attribute__((address_space(1))) void*)g,
        (__attribute__((address_space(3))) void*)l, 16, 0, 0);
}

__device__ __forceinline__ float softplus_f(float x) {
    float e = __builtin_amdgcn_exp2f(-fabsf(x) * 1.44269504f);
    return fmaxf(x, 0.f) + __builtin_amdgcn_logf(1.f + e) * 0.69314718f;
}

template<int CTRL>
__device__ __forceinline__ float dpp_add(float x) {
    int s = __builtin_amdgcn_update_dpp(0, __builtin_bit_cast(int, x),
                                        CTRL, 0xF, 0xF, true);
    return x + __builtin_bit_cast(float, s);
}

// ---------------------------------------------------------------------------
// fp16 NT MFMA GEMM (verified r17). z-dim: A += z*sA, B += z*sB, C += z*sC.
// ---------------------------------------------------------------------------
template<int WMW, int WNW, int FM, int FN, typename CT>
__global__ __launch_bounds__(256)
void gemm_nt_f16(const _Float16* __restrict__ A, const _Float16* __restrict__ B,
                 CT* __restrict__ C, int K, int lda, int ldc,
                 long sA, long sB, long sC)
{
    constexpr int BM = WMW * FM * 16, BN = WNW * FN * 16;
    constexpr int ACH = BM / 8, NCH = (BM + BN) / 8;
    __shared__ __align__(16) _Float16 lds[(BM + BN) * 64];
    A += (long)blockIdx.z * sA;
    B += (long)blockIdx.z * sB;
    C += (long)blockIdx.z * sC;
    const int m0 = blockIdx.y * BM, n0 = blockIdx.x * BN;
    const int t = threadIdx.x, wid = t >> 6, lane = t & 63;
    const int wm = wid / WNW, wn = wid % WNW;
    const int srow = lane >> 3;
    const int skk  = ((lane & 7) ^ srow) * 8;

    f32x4 acc[FM][FN];
#pragma unroll
    for (int i = 0; i < FM; ++i)
#pragma unroll
        for (int j = 0; j < FN; ++j) acc[i][j] = (f32x4){0.f, 0.f, 0.f, 0.f};

    for (int k0 = 0; k0 < K; k0 += 64) {
#pragma unroll
        for (int c = wid; c < NCH; c += 4) {
            const _Float16* gp = (c < ACH)
                ? A + (long)(m0 + c * 8 + srow) * lda + k0 + skk
                : B + (long)(n0 + (c - ACH) * 8 + srow) * lda + k0 + skk;
            gload_lds16(gp, lds + c * 512);
        }
        __syncthreads();
#pragma unroll
        for (int kw = 0; kw < 2; ++kw) {
            f16x8 af[FM], bf[FN];
#pragma unroll
            for (int i = 0; i < FM; ++i) {
                int r = wm * FM * 16 + i * 16 + (lane & 15);
                af[i] = *(const f16x8*)(lds + r * 64 +
                        (((kw * 4 + (lane >> 4)) ^ (r & 7)) * 8));
            }
#pragma unroll
            for (int j = 0; j < FN; ++j) {
                int r = wn * FN * 16 + j * 16 + (lane & 15);
                bf[j] = *(const f16x8*)(lds + BM * 64 + r * 64 +
                        (((kw * 4 + (lane >> 4)) ^ (r & 7)) * 8));
            }
#pragma unroll
            for (int i = 0; i < FM; ++i)
#pragma unroll
                for (int j = 0; j < FN; ++j)
                    acc[i][j] = __builtin_amdgcn_mfma_f32_16x16x32_f16(
                        af[i], bf[j], acc[i][j], 0, 0, 0);
        }
        __syncthreads();
    }
#pragma unroll
    for (int i = 0; i < FM; ++i)
#pragma unroll
        for (int j = 0; j < FN; ++j) {
            int n = n0 + wn * FN * 16 + j * 16 + (lane & 15);
            int m = m0 + wm * FM * 16 + i * 16 + (lane >> 4) * 4;
            f32x4 v = acc[i][j];
            if constexpr (__is_same(CT, float)) {
                *(f32x4*)&C[(long)n * ldc + m] = v;
            } else {
                f16x4 h = {(_Float16)v.x, (_Float16)v.y, (_Float16)v.z, (_Float16)v.w};
                *(f16x4*)&C[(long)n * ldc + m] = h;
            }
        }
}

// out = p0 + p1 (out_proj split-K reduce)
__global__ __launch_bounds__(256)
void oreduce_kernel(const float* __restrict__ p, float* __restrict__ out)
{
    int f = (blockIdx.x * 256 + threadIdx.x) * 4;
    f32x4 a = *(const f32x4*)(p + f);
    f32x4 b = *(const f32x4*)(p + 2097152 + f);
    *(f32x4*)(out + f) = a + b;
}

// ---------------------------------------------------------------------------
// x_proj fp16 MFMA, split-K (verified r8/r14).
// ---------------------------------------------------------------------------
#define XP_SK 8
__global__ __launch_bounds__(256)
void xproj_f16_kernel(const _Float16* __restrict__ u16, const _Float16* __restrict__ xw16,
                      float* __restrict__ pb)
{
    __shared__ __align__(16) _Float16 Asw[128 * 64];
    __shared__ __align__(16) _Float16 Bsw[96 * 64];
    const int t = threadIdx.x, wid = t >> 6, lane = t & 63;
    const int wm = wid >> 1, wn = wid & 1;
    const int m0 = blockIdx.x * 128;
    const int sk = blockIdx.y, dirb = blockIdx.z;
    const _Float16* ub = u16 + (long)dirb * 2048 * 1024;
    const _Float16* Bw = xw16 + (long)(dirb >> 1) * 96 * 2048;
    const int srow = lane >> 3;
    const int skk  = ((lane & 7) ^ srow) * 8;
    const int lloc = (t & 31) * 4;
    const int kslt = t >> 5;

    f32x4 acc[4][3];
#pragma unroll
    for (int i = 0; i < 4; ++i)
#pragma unroll
        for (int j = 0; j < 3; ++j) acc[i][j] = (f32x4){0.f, 0.f, 0.f, 0.f};

    for (int ks = 0; ks < 2048 / XP_SK; ks += 64) {
        const int k0 = sk * (2048 / XP_SK) + ks;
#pragma unroll
        for (int c = wid; c < 12; c += 4)
            gload_lds16(Bw + (long)(c * 8 + srow) * 2048 + k0 + skk, Bsw + c * 512);
        _Float16 av[8][4];
#pragma unroll
        for (int kk = 0; kk < 8; ++kk) {
            f16x4 v = *(const f16x4*)&ub[(long)(k0 + kslt * 8 + kk) * 1024 + m0 + lloc];
            av[kk][0] = v[0]; av[kk][1] = v[1]; av[kk][2] = v[2]; av[kk][3] = v[3];
        }
#pragma unroll
        for (int q = 0; q < 4; ++q) {
            int l = lloc + q;
            f16x8 h = {av[0][q], av[1][q], av[2][q], av[3][q],
                       av[4][q], av[5][q], av[6][q], av[7][q]};
            *(f16x8*)(Asw + l * 64 + ((kslt ^ (l & 7)) * 8)) = h;
        }
        __syncthreads();
#pragma unroll
        for (int kw = 0; kw < 2; ++kw) {
            f16x8 af[4], bf[3];
#pragma unroll
            for (int i = 0; i < 4; ++i) {
                int r = wm * 64 + i * 16 + (lane & 15);
                af[i] = *(const f16x8*)(Asw + r * 64 +
                        (((kw * 4 + (lane >> 4)) ^ (r & 7)) * 8));
            }
#pragma unroll
            for (int j = 0; j < 3; ++j) {
                int r = wn * 48 + j * 16 + (lane & 15);
                bf[j] = *(const f16x8*)(Bsw + r * 64 +
                        (((kw * 4 + (lane >> 4)) ^ (r & 7)) * 8));
            }
#pragma unroll
            for (int i = 0; i < 4; ++i)
#pragma unroll
                for (int j = 0; j < 3; ++j)
                    acc[i][j] = __builtin_amdgcn_mfma_f32_16x16x32_f16(
                        af[i], bf[j], acc[i][j], 0, 0, 0);
        }
        __syncthreads();
    }
    float* Cp = pb + ((long)sk * 4 + dirb) * 96 * 1024;
#pragma unroll
    for (int i = 0; i < 4; ++i)
#pragma unroll
        for (int j = 0; j < 3; ++j) {
            int n = wn * 48 + j * 16 + (lane & 15);
            int m = m0 + wm * 64 + i * 16 + (lane >> 4) * 4;
            *(f32x4*)&Cp[(long)n * 1024 + m] = acc[i][j];
        }
}

__global__ __launch_bounds__(256)
void xreduce_kernel(const float* __restrict__ pb, float* __restrict__ xdbl)
{
    int f = (blockIdx.x * 256 + threadIdx.x) * 4;
    f32x4 s = (f32x4){0.f, 0.f, 0.f, 0.f};
#pragma unroll
    for (int sk = 0; sk < XP_SK; ++sk)
        s += *(const f32x4*)(pb + (long)sk * 393216 + f);
    *(f32x4*)(xdbl + f) = s;
}

// ---------------------------------------------------------------------------
// dt_proj fp16 MFMA + softplus -> delta16 (verified r14)
// ---------------------------------------------------------------------------
__global__ __launch_bounds__(256)
void dtproj_f16_kernel(const float* __restrict__ xdbl, const _Float16* __restrict__ dw16,
                       const float* __restrict__ bcat, _Float16* __restrict__ delta16)
{
    __shared__ __align__(16) _Float16 Asw[128 * 64];
    __shared__ __align__(16) _Float16 Bsw[128 * 64];
    const int t = threadIdx.x, wid = t >> 6, lane = t & 63;
    const int wm = wid >> 1, wn = wid & 1;
    const int n0 = blockIdx.x * 128, m0 = blockIdx.y * 128;
    const int dirb = blockIdx.z, dir = dirb >> 1;
    const float* Xb = xdbl + (long)dirb * 96 * 1024;
    const _Float16* Bw = dw16 + (long)dir * 2048 * 64;
    const int srow = lane >> 3, skk = ((lane & 7) ^ srow) * 8;
    const int lloc = (t & 31) * 4, kslt = t >> 5;

#pragma unroll
    for (int c = wid; c < 16; c += 4)
        gload_lds16(Bw + (long)(n0 + c * 8 + srow) * 64 + skk, Bsw + c * 512);
    float av[8][4];
#pragma unroll
    for (int kk = 0; kk < 8; ++kk) {
        f32x4 v = *(const f32x4*)&Xb[(long)(kslt * 8 + kk) * 1024 + m0 + lloc];
        av[kk][0] = v.x; av[kk][1] = v.y; av[kk][2] = v.z; av[kk][3] = v.w;
    }
#pragma unroll
    for (int q = 0; q < 4; ++q) {
        int l = lloc + q;
        f16x8 h = {(_Float16)av[0][q], (_Float16)av[1][q], (_Float16)av[2][q],
                   (_Float16)av[3][q], (_Float16)av[4][q], (_Float16)av[5][q],
                   (_Float16)av[6][q], (_Float16)av[7][q]};
        *(f16x8*)(Asw + l * 64 + ((kslt ^ (l & 7)) * 8)) = h;
    }
    __syncthreads();

    f32x4 acc[4][4];
#pragma unroll
    for (int i = 0; i < 4; ++i)
#pragma unroll
        for (int j = 0; j < 4; ++j) acc[i][j] = (f32x4){0.f, 0.f, 0.f, 0.f};
#pragma unroll
    for (int kw = 0; kw < 2; ++kw) {
        f16x8 af[4], bf[4];
#pragma unroll
        for (int i = 0; i < 4; ++i) {
            int r = wm * 64 + i * 16 + (lane & 15);
            af[i] = *(const f16x8*)(Asw + r * 64 +
                    (((kw * 4 + (lane >> 4)) ^ (r & 7)) * 8));
        }
#pragma unroll
        for (int j = 0; j < 4; ++j) {
            int r = wn * 64 + j * 16 + (lane & 15);
            bf[j] = *(const f16x8*)(Bsw + r * 64 +
                    (((kw * 4 + (lane >> 4)) ^ (r & 7)) * 8));
        }
#pragma unroll
        for (int i = 0; i < 4; ++i)
#pragma unroll
            for (int j = 0; j < 4; ++j)
                acc[i][j] = __builtin_amdgcn_mfma_f32_16x16x32_f16(
                    af[i], bf[j], acc[i][j], 0, 0, 0);
    }
    _Float16* Dp = delta16 + (long)dirb * 2048 * 1024;
#pragma unroll
    for (int j = 0; j < 4; ++j) {
        int dd = n0 + wn * 64 + j * 16 + (lane & 15);
        float bm = bcat[dir * 2048 + dd];
#pragma unroll
        for (int i = 0; i < 4; ++i) {
            int m = m0 + wm * 64 + i * 16 + (lane >> 4) * 4;
            f32x4 v = acc[i][j];
            f16x4 o = {(_Float16)softplus_f(v.x + bm), (_Float16)softplus_f(v.y + bm),
                       (_Float16)softplus_f(v.z + bm), (_Float16)softplus_f(v.w + bm)};
            *(f16x4*)&Dp[(long)dd * 1024 + m] = o;
        }
    }
}

// Merged setup (verified r14).
__global__ __launch_bounds__(256)
void setup_kernel(const float* __restrict__ hidden, const float* __restrict__ winp,
                  const float* __restrict__ woutp,
                  const float* __restrict__ xwf, const float* __restrict__ xwb,
                  const float* __restrict__ dwf, const float* __restrict__ dwb,
                  const float* __restrict__ bf,  const float* __restrict__ bb,
                  _Float16* __restrict__ H16, _Float16* __restrict__ Win16,
                  _Float16* __restrict__ Wout16,
                  _Float16* __restrict__ xw16, _Float16* __restrict__ dw16,
                  float* __restrict__ bcat)
{
    long i4 = ((long)blockIdx.x * 256 + threadIdx.x) * 4;
    auto cvt4 = [](const float* s) -> f16x4 {
        float4 v = *(const float4*)s;
        return (f16x4){(_Float16)v.x, (_Float16)v.y, (_Float16)v.z, (_Float16)v.w};
    };
    if (i4 < 4194304) *(f16x4*)(Win16 + i4) = cvt4(winp + i4);
    if (i4 < 2097152) {
        *(f16x4*)(H16 + i4)   = cvt4(hidden + i4);
        *(f16x4*)(Wout16 + i4) = cvt4(woutp + i4);
    }
    if (i4 < 196608) {
        *(f16x4*)(xw16 + i4)          = cvt4(xwf + i4);
        *(f16x4*)(xw16 + 196608 + i4) = cvt4(xwb + i4);
    }
    if (i4 < 131072) {
        *(f16x4*)(dw16 + i4)          = cvt4(dwf + i4);
        *(f16x4*)(dw16 + 131072 + i4) = cvt4(dwb + i4);
    }
    if (i4 < 2048) {
        *(float4*)(bcat + i4)        = *(const float4*)(bf + i4);
        *(float4*)(bcat + 2048 + i4) = *(const float4*)(bb + i4);
    }
}

// Depthwise causal conv (k=4) + SiLU -> u16; reads fp16 xz.
__global__ __launch_bounds__(256)
void conv_silu_kernel(const _Float16* __restrict__ xz16,
                      const float* __restrict__ wf, const float* __restrict__ bf,
                      const float* __restrict__ wb, const float* __restrict__ bbk,
                      _Float16* __restrict__ u16)
{
    long idx = (long)blockIdx.x * 256 + threadIdx.x;
    int l = (int)(idx & 1023);
    long r = idx >> 10;
    int d = (int)(r & 2047);
    int b = (int)((r >> 11) & 1);
    int dir = (int)(r >> 12);
    const _Float16* x = xz16 + ((long)b * 4096 + d) * 1024;
    const float* w = dir ? wb : wf;
    float s = dir ? bbk[d] : bf[d];
    if (dir == 0) {
#pragma unroll
        for (int j = 0; j < 4; ++j) {
            int p = l - 3 + j;
            if (p >= 0) s = fmaf(w[d * 4 + j], (float)x[p], s);
        }
    } else {
#pragma unroll
        for (int j = 0; j < 4; ++j) {
            int src = l - 3 + j;
            if (src >= 0) s = fmaf(w[d * 4 + j], (float)x[1023 - src], s);
        }
    }
    u16[idx] = (_Float16)(s / (1.f + __builtin_amdgcn_exp2f(-s * 1.44269504f)));
}

// ---------------------------------------------------------------------------
// scan pass 1: per-chunk local scan -> hend16/aprod16 (verified r16).
// ---------------------------------------------------------------------------
__global__ __launch_bounds__(256)
void scan_p1_kernel(const _Float16* __restrict__ u16, const _Float16* __restrict__ delta16,
                    const float* __restrict__ xdbl,
                    const float* __restrict__ Alf, const float* __restrict__ Alb,
                    _Float16* __restrict__ hend16, _Float16* __restrict__ aprod16)
{
    __shared__ _Float16 sD[64][40], sU[64][40];
    __shared__ float sB[32][20];
    const int t = threadIdx.x, wid = t >> 6, lane = t & 63;
    const int nl = lane & 3;
    const int dloc = wid * 16 + (lane >> 2);
    const int dblk = blockIdx.x, chunk = blockIdx.y, dirb = blockIdx.z;
    const int d = dblk * 64 + dloc, dir = dirb >> 1;
    const int T0 = chunk * SCL;
    f32x4 Av = *(const f32x4*)((dir ? Alb : Alf) + d * 16 + nl * 4);
    float An2[4] = {-expf(Av.x) * 1.44269504f, -expf(Av.y) * 1.44269504f,
                    -expf(Av.z) * 1.44269504f, -expf(Av.w) * 1.44269504f};
    const _Float16* dp = delta16 + ((long)dirb * 2048 + dblk * 64) * 1024;
    const _Float16* up = u16    + ((long)dirb * 2048 + dblk * 64) * 1024;
    const float* Bp = xdbl + ((long)dirb * 96 + 64) * 1024;

    {
        int dd = t >> 2, q = t & 3;
        *(f16x8*)&sD[dd][q * 8] = *(const f16x8*)&dp[(long)dd * 1024 + T0 + q * 8];
        *(f16x8*)&sU[dd][q * 8] = *(const f16x8*)&up[(long)dd * 1024 + T0 + q * 8];
    }
#pragma unroll
    for (int rep = 0; rep < 2; ++rep) {
        int ii = rep * 256 + t;
        int n = ii >> 5, tt = ii & 31;
        sB[tt][n] = Bp[(long)n * 1024 + T0 + tt];
    }
    __syncthreads();

    float h[4] = {0.f, 0.f, 0.f, 0.f};
    float S = 0.f;
#pragma unroll 4
    for (int g = 0; g < 8; ++g) {
        f16x4 dlh = *(const f16x4*)&sD[dloc][g * 4];
        f16x4 uuh = *(const f16x4*)&sU[dloc][g * 4];
        float dls[4] = {(float)dlh[0], (float)dlh[1], (float)dlh[2], (float)dlh[3]};
        float uus[4] = {(float)uuh[0], (float)uuh[1], (float)uuh[2], (float)uuh[3]};
#pragma unroll
        for (int r4 = 0; r4 < 4; ++r4) {
            f32x4 Bv = *(const f32x4*)&sB[g * 4 + r4][nl * 4];
            float Bs[4] = {Bv.x, Bv.y, Bv.z, Bv.w};
            float dl = dls[r4], t1 = dl * uus[r4];
            S += dl;
#pragma unroll
            for (int r = 0; r < 4; ++r)
                h[r] = fmaf(__builtin_amdgcn_exp2f(dl * An2[r]), h[r], t1 * Bs[r]);
        }
    }
    long cb = (((long)dirb * SCH + chunk) * 2048 + d) * 16 + nl * 4;
    f16x4 he = {(_Float16)h[0], (_Float16)h[1], (_Float16)h[2], (_Float16)h[3]};
    f16x4 ap = {(_Float16)__builtin_amdgcn_exp2f(S * An2[0]),
                (_Float16)__builtin_amdgcn_exp2f(S * An2[1]),
                (_Float16)__builtin_amdgcn_exp2f(S * An2[2]),
                (_Float16)__builtin_amdgcn_exp2f(S * An2[3])};
    *(f16x4*)&hend16[cb]  = he;
    *(f16x4*)&aprod16[cb] = ap;
}

// scan pass 2: sequential carry combine (f32 in-register, fp16 storage).
__global__ __launch_bounds__(256)
void scan_carry_kernel(const _Float16* __restrict__ hend16,
                       const _Float16* __restrict__ aprod16,
                       _Float16* __restrict__ hinit16)
{
    int f = blockIdx.x * 256 + threadIdx.x;   // (dirb, d*16+n)
    int dn = f & 32767;
    int dirb = f >> 15;
    long base = (long)dirb * SCH * 32768 + dn;
    float hcur = 0.f;
#pragma unroll
    for (int c = 0; c < SCH; ++c) {
        hinit16[base + (long)c * 32768] = (_Float16)hcur;
        hcur = (float)hend16[base + (long)c * 32768]
             + (float)aprod16[base + (long)c * 32768] * hcur;
    }
}

// ---------------------------------------------------------------------------
// scan pass 3 FUSED with combine: block = (dblk, c, b) handles dir0 chunk c
// and dir1 chunk 31-c for 64 d's. Emits GT[b][l][d] fp16 directly.
// ---------------------------------------------------------------------------
__global__ __launch_bounds__(256)
void scan_p3c_kernel(const _Float16* __restrict__ u16, const _Float16* __restrict__ delta16,
                     const float* __restrict__ xdbl,
                     const float* __restrict__ Alf, const float* __restrict__ Alb,
                     const float* __restrict__ Df, const float* __restrict__ Db,
                     const _Float16* __restrict__ hinit16,
                     const _Float16* __restrict__ xz16,
                     _Float16* __restrict__ GT)
{
    __shared__ _Float16 sDf[64][40], sUf[64][40], sDb[64][40], sUb[64][40];
    __shared__ float sBf[32][20], sCf[32][20], sBb[32][20], sCb[32][20];
    __shared__ _Float16 sYf[64][40], sYb[64][40];
    const int t = threadIdx.x, wid = t >> 6, lane = t & 63;
    const int nl = lane & 3;
    const int dloc = wid * 16 + (lane >> 2);
    const int dblk = blockIdx.x, c = blockIdx.y, b = blockIdx.z;
    const int d = dblk * 64 + dloc;
    const int cB = SCH - 1 - c;
    const int T0f = c * SCL, T0b = cB * SCL;
    const int dirbF = b, dirbB = 2 + b;

    f32x4 AvF = *(const f32x4*)(Alf + d * 16 + nl * 4);
    f32x4 AvB = *(const f32x4*)(Alb + d * 16 + nl * 4);
    float AnF[4] = {-expf(AvF.x) * 1.44269504f, -expf(AvF.y) * 1.44269504f,
                    -expf(AvF.z) * 1.44269504f, -expf(AvF.w) * 1.44269504f};
    float AnB[4] = {-expf(AvB.x) * 1.44269504f, -expf(AvB.y) * 1.44269504f,
                    -expf(AvB.z) * 1.44269504f, -expf(AvB.w) * 1.44269504f};
    const float DdF = Df[d], DdB = Db[d];
    const _Float16* dpF = delta16 + ((long)dirbF * 2048 + dblk * 64) * 1024;
    const _Float16* upF = u16    + ((long)dirbF * 2048 + dblk * 64) * 1024;
    const _Float16* dpB = delta16 + ((long)dirbB * 2048 + dblk * 64) * 1024;
    const _Float16* upB = u16    + ((long)dirbB * 2048 + dblk * 64) * 1024;
    const float* BpF = xdbl + ((long)dirbF * 96 + 64) * 1024;
    const float* CpF = xdbl + ((long)dirbF * 96 + 80) * 1024;
    const float* BpB = xdbl + ((long)dirbB * 96 + 64) * 1024;
    const float* CpB = xdbl + ((long)dirbB * 96 + 80) * 1024;

    {   // stage D/U for both dirs
        int dd = t >> 2, q = t & 3;
        *(f16x8*)&sDf[dd][q * 8] = *(const f16x8*)&dpF[(long)dd * 1024 + T0f + q * 8];
        *(f16x8*)&sUf[dd][q * 8] = *(const f16x8*)&upF[(long)dd * 1024 + T0f + q * 8];
        *(f16x8*)&sDb[dd][q * 8] = *(const f16x8*)&dpB[(long)dd * 1024 + T0b + q * 8];
        *(f16x8*)&sUb[dd][q * 8] = *(const f16x8*)&upB[(long)dd * 1024 + T0b + q * 8];
    }
#pragma unroll
    for (int rep = 0; rep < 2; ++rep) {
        int ii = rep * 256 + t;
        int n = ii >> 5, tt = ii & 31;
        sBf[tt][n] = BpF[(long)n * 1024 + T0f + tt];
        sCf[tt][n] = CpF[(long)n * 1024 + T0f + tt];
        sBb[tt][n] = BpB[(long)n * 1024 + T0b + tt];
        sCb[tt][n] = CpB[(long)n * 1024 + T0b + tt];
    }
    long cbF = (((long)dirbF * SCH + c)  * 2048 + d) * 16 + nl * 4;
    long cbB = (((long)dirbB * SCH + cB) * 2048 + d) * 16 + nl * 4;
    f16x4 h0F = *(const f16x4*)&hinit16[cbF];
    f16x4 h0B = *(const f16x4*)&hinit16[cbB];
    const bool m[4] = {nl == 0, nl == 1, nl == 2, nl == 3};
    __syncthreads();

    // dir0 recurrence -> sYf[dloc][li]
    {
        float h[4] = {(float)h0F[0], (float)h0F[1], (float)h0F[2], (float)h0F[3]};
#pragma unroll 4
        for (int g = 0; g < 8; ++g) {
            f16x4 dlh = *(const f16x4*)&sDf[dloc][g * 4];
            f16x4 uuh = *(const f16x4*)&sUf[dloc][g * 4];
            float dls[4] = {(float)dlh[0], (float)dlh[1], (float)dlh[2], (float)dlh[3]};
            float uus[4] = {(float)uuh[0], (float)uuh[1], (float)uuh[2], (float)uuh[3]};
            float keep = 0.f;
#pragma unroll
            for (int r4 = 0; r4 < 4; ++r4) {
                f32x4 Bv = *(const f32x4*)&sBf[g * 4 + r4][nl * 4];
                f32x4 Cv = *(const f32x4*)&sCf[g * 4 + r4][nl * 4];
                float dl = dls[r4], uu = uus[r4], t1 = dl * uu;
#pragma unroll
                for (int r = 0; r < 4; ++r)
                    h[r] = fmaf(__builtin_amdgcn_exp2f(dl * AnF[r]), h[r],
                                t1 * ((const float*)&Bv)[r]);
                float p = h[0] * Cv.x;
                p = fmaf(h[1], Cv.y, p);
                p = fmaf(h[2], Cv.z, p);
                p = fmaf(h[3], Cv.w, p);
                p = dpp_add<0xB1>(p);
                p = dpp_add<0x4E>(p);
                float fy = fmaf(DdF, uu, p);
                keep = m[r4] ? fy : keep;
            }
            sYf[dloc][g * 4 + nl] = (_Float16)keep;
        }
    }
    // dir1 recurrence -> sYb[dloc][31 - li] (store at forward-l position)
    {
        float h[4] = {(float)h0B[0], (float)h0B[1], (float)h0B[2], (float)h0B[3]};
#pragma unroll 4
        for (int g = 0; g < 8; ++g) {
            f16x4 dlh = *(const f16x4*)&sDb[dloc][g * 4];
            f16x4 uuh = *(const f16x4*)&sUb[dloc][g * 4];
            float dls[4] = {(float)dlh[0], (float)dlh[1], (float)dlh[2], (float)dlh[3]};
            float uus[4] = {(float)uuh[0], (float)uuh[1], (float)uuh[2], (float)uuh[3]};
            float keep = 0.f;
#pragma unroll
            for (int r4 = 0; r4 < 4; ++r4) {
                f32x4 Bv = *(const f32x4*)&sBb[g * 4 + r4][nl * 4];
                f32x4 Cv = *(const f32x4*)&sCb[g * 4 + r4][nl * 4];
                float dl = dls[r4], uu = uus[r4], t1 = dl * uu;
#pragma unroll
                for (int r = 0; r < 4; ++r)
                    h[r] = fmaf(__builtin_amdgcn_exp2f(dl * AnB[r]), h[r],
                                t1 * ((const float*)&Bv)[r]);
                float p = h[0] * Cv.x;
                p = fmaf(h[1], Cv.y, p);
                p = fmaf(h[2], Cv.z, p);
                p = fmaf(h[3], Cv.w, p);
                p = dpp_add<0xB1>(p);
                p = dpp_add<0x4E>(p);
                float fy = fmaf(DdB, uu, p);
                keep = m[r4] ? fy : keep;
            }
            sYb[dloc][31 - (g * 4 + nl)] = (_Float16)keep;
        }
    }
    __syncthreads();

    // combine: sG (reuse sDf) = silu(z) * (yf + yb_rev); z read coalesced
    {
        int dd = t >> 2, lq = (t & 3) * 8;
        f16x8 vz = *(const f16x8*)&xz16[((long)b * 4096 + 2048 + dblk * 64 + dd) * 1024
                                        + T0f + lq];
#pragma unroll
        for (int j = 0; j < 8; ++j) {
            float z = (float)vz[j];
            float sz = z / (1.f + __builtin_amdgcn_exp2f(-z * 1.44269504f));
            float g = sz * ((float)sYf[dd][lq + j] + (float)sYb[dd][lq + j]);
            sDf[dd][lq + j] = (_Float16)g;
        }
    }
    __syncthreads();

    // transpose-write GT[b][T0f+ll][dblk*64 + dq..dq+3]
#pragma unroll
    for (int rep = 0; rep < 2; ++rep) {
        int ii = rep * 256 + t;
        int ll = ii >> 4;
        int dq = (ii & 15) * 4;
        f16x4 h = {sDf[dq][ll], sDf[dq + 1][ll], sDf[dq + 2][ll], sDf[dq + 3][ll]};
        *(f16x4*)(GT + ((long)(b * 1024 + T0f + ll)) * 2048 + dblk * 64 + dq) = h;
    }
}

extern "C" void kernel_launch(void* const* d_in, const int* in_sizes, int n_in,
                              void* d_out, int out_size, void* d_ws, size_t ws_size,
                              hipStream_t stream)
{
    const float* hidden   = (const float*)d_in[0];
    const float* inproj_w = (const float*)d_in[1];
    const float* conv_w   = (const float*)d_in[2];
    const float* conv_b   = (const float*)d_in[3];
    const float* xproj_w  = (const float*)d_in[4];
    const float* dtproj_w = (const float*)d_in[5];
    const float* dt_bias  = (const float*)d_in[6];
    const float* A_log    = (const float*)d_in[7];
    const float* D_skip   = (const float*)d_in[8];
    const float* convb_w  = (const float*)d_in[9];
    const float* convb_b  = (const float*)d_in[10];
    const float* xprojb_w = (const float*)d_in[11];
    const float* dtprojb_w= (const float*)d_in[12];
    const float* dtb_bias = (const float*)d_in[13];
    const float* Ab_log   = (const float*)d_in[14];
    const float* Db_skip  = (const float*)d_in[15];
    const float* outproj_w= (const float*)d_in[16];
    float* out = (float*)d_out;

    float* ws    = (float*)d_ws;
    float* xz    = ws;
    float* u     = ws + 8388608;
    float* xdbl  = ws + 16777216;
    float* delta = ws + 17170432;
    float* y     = ws + 25559040;
    // xz region: fp16 xz -> out_proj f32 partials (xz16 dead after p3c)
    _Float16* xz16  = (_Float16*)xz;
    float*    opart = xz;
    // u region: H16 | Win16 | u16 | Wout16; hinit16 overlays H16/Win16 later
    _Float16* H16     = (_Float16*)u;
    _Float16* Win16   = (_Float16*)(u + 1048576);
    _Float16* u16     = (_Float16*)(u + 3145728);
    _Float16* Wout16  = (_Float16*)(u + 7340032);
    _Float16* hinit16 = (_Float16*)u;
    // delta region: delta16 | xpb partials
    _Float16* delta16 = (_Float16*)delta;
    float*    xpb     = delta + 4194304;
    // y region: scratch -> hend16|aprod16 (dead after carry) -> GT
    _Float16* dw16  = (_Float16*)y;
    float*    bcat  = y + 131072;
    _Float16* xw16  = (_Float16*)(y + 135168);
    _Float16* hend16  = (_Float16*)y;
    _Float16* aprod16 = (_Float16*)(y + 2097152);
    _Float16* GT      = (_Float16*)y;              // [0, 2.1M f32) after carry

    // 0) merged setup
    hipLaunchKernelGGL(setup_kernel, dim3(4096), dim3(256), 0, stream,
        hidden, inproj_w, outproj_w, xproj_w, xprojb_w, dtproj_w, dtprojb_w,
        dt_bias, dtb_bias, H16, Win16, Wout16, xw16, dw16, bcat);

    // 1) in_proj MFMA -> fp16 xz
    hipLaunchKernelGGL((gemm_nt_f16<2, 2, 2, 4, _Float16>),
        dim3(32, 16, 2), dim3(256), 0, stream,
        H16, Win16, xz16, 1024, 1024, 1024, 1048576L, 0L, 4194304L);

    // 2) conv + silu -> u16
    hipLaunchKernelGGL(conv_silu_kernel, dim3(32768), dim3(256), 0, stream,
        xz16, conv_w, conv_b, convb_w, convb_b, u16);

    // 3) x_proj MFMA split-K + reduce
    hipLaunchKernelGGL(xproj_f16_kernel, dim3(8, XP_SK, 4), dim3(256), 0, stream,
        u16, xw16, xpb);
    hipLaunchKernelGGL(xreduce_kernel, dim3(384), dim3(256), 0, stream,
        xpb, xdbl);

    // 4) dt_proj fp16 MFMA + softplus -> delta16
    hipLaunchKernelGGL(dtproj_f16_kernel, dim3(16, 8, 4), dim3(256), 0, stream,
        xdbl, dw16, bcat, delta16);

    // 5) scan: p1 -> carry -> fused p3+combine (emits GT)
    hipLaunchKernelGGL(scan_p1_kernel, dim3(32, SCH, 4), dim3(256), 0, stream,
        u16, delta16, xdbl, A_log, Ab_log, hend16, aprod16);
    hipLaunchKernelGGL(scan_carry_kernel, dim3(512), dim3(256), 0, stream,
        hend16, aprod16, hinit16);
    hipLaunchKernelGGL(scan_p3c_kernel, dim3(32, SCH, 2), dim3(256), 0, stream,
        u16, delta16, xdbl, A_log, Ab_log, D_skip, Db_skip, hinit16, xz16, GT);

    // 6) out_proj MFMA split-K=2 -> f32 partials in dead xz region
    hipLaunchKernelGGL((gemm_nt_f16<4, 1, 2, 4, float>),
        dim3(32, 8, 2), dim3(256), 0, stream,
        Wout16, GT, opart, 1024, 2048, 1024, 1024L, 1024L, 2097152L);

    // 7) out = p0 + p1
    hipLaunchKernelGGL(oreduce_kernel, dim3(2048), dim3(256), 0, stream,
        opart, out);
}